// Round 4
// baseline (32005.927 us; speedup 1.0000x reference)
//
#include <hip/hip_runtime.h>
#include <hip/hip_bf16.h>
#include <cstddef>

// ---------------- problem constants ----------------
constexpr int B_ = 64, T_ = 512, E_ = 768, H_ = 512, G_ = 1536, NF_ = 256;

typedef float f32x4 __attribute__((ext_vector_type(4)));
typedef __bf16 bf16x8 __attribute__((ext_vector_type(8)));

// ---------------- workspace layout (bytes) ----------------
constexpr size_t SZ_GIC   = (size_t)B_ * T_ * G_ * 4;       // 201326592
constexpr size_t OFF_GI   = 0;
constexpr size_t OFF_OUT  = (size_t)B_ * T_ * G_ * 2;       // out f32 after bf16 gi
constexpr size_t OFF_WBF0 = 170u * 1024 * 1024;             // in dead giC tail (>160MB)
constexpr size_t OFF_WBF1 = OFF_WBF0 + (size_t)G_ * H_ * 2;
constexpr size_t OFF_MISC = SZ_GIC;
constexpr size_t OFF_H0   = OFF_MISC;
constexpr size_t OFF_H1   = OFF_H0 + (size_t)B_ * H_ * 4;
constexpr size_t OFF_SEL  = OFF_H1 + (size_t)B_ * H_ * 4;
constexpr size_t OFF_ORD  = OFF_SEL + (size_t)B_ * T_ * 4;
constexpr size_t OFF_NSEL = OFF_ORD + (size_t)B_ * T_ * 4;
constexpr size_t OFF_MAXN = OFF_NSEL + 256;
constexpr size_t OFF_FLG  = OFF_MAXN + 256;
constexpr size_t OFF_POOL = OFF_FLG + 256;
constexpr size_t WS_NEED  = OFF_POOL + (size_t)B_ * 3 * NF_ * 4;

// coherent (fabric-level, L1/L2-bypass) access helpers
#define CLOAD4(dst, ptr) \
    asm volatile("global_load_dwordx4 %0, %1, off sc0 sc1" : "=v"(dst) : "v"(ptr))
#define CWAIT() do { \
    asm volatile("s_waitcnt vmcnt(0)" ::: "memory"); \
    __builtin_amdgcn_sched_barrier(0); } while (0)
#define CSTORE4(ptr, val) \
    asm volatile("global_store_dword %0, %1, off sc0 sc1" :: "v"(ptr), "v"(val) : "memory")
#define CSTORE8(ptr, val) \
    asm volatile("global_store_dwordx2 %0, %1, off sc0 sc1" :: "v"(ptr), "v"(val) : "memory")

__device__ __forceinline__ float sigm(float x) { return 1.f / (1.f + expf(-x)); }
__device__ __forceinline__ float b2f(unsigned short u) {
    return __uint_as_float(((unsigned int)u) << 16);
}
__device__ __forceinline__ unsigned short f2bu(float x) {
    __hip_bfloat16 h = __float2bfloat16(x);
    return *(unsigned short*)&h;
}

template<int NWG>
__device__ __forceinline__ void bar_wait(const int* flags, int t, int tid) {
    if (tid < 64) {
        int v;
        for (;;) {
            asm volatile("global_load_dword %0, %1, off sc0 sc1\n\t"
                         "s_waitcnt vmcnt(0)"
                         : "=v"(v) : "v"(flags + (tid & (NWG - 1))) : "memory");
            if (__all(v >= t)) break;
            __builtin_amdgcn_s_sleep(1);
        }
    }
    __syncthreads();
}

__device__ __forceinline__ void bar_arrive(int* flags, int t, int tid, int bx) {
    asm volatile("s_waitcnt vmcnt(0)" ::: "memory");
    __syncthreads();
    if (tid == 0) { int pv = t + 1; CSTORE4(flags + bx, pv); }
}

// =====================================================================
// Tiled fp32 GEMM (unchanged — MFMA conversion in a later round).
// =====================================================================
template<int AMODE, int OMODE>
__global__ __launch_bounds__(256) void gemm_k(
    const float* __restrict__ A, const float* __restrict__ W,
    const float* __restrict__ bias,
    float* __restrict__ Cf, __hip_bfloat16* __restrict__ Cb,
    unsigned int* __restrict__ pool,
    int N, int K, int ldA, int rowsPerB, int tilesPerB,
    const int* __restrict__ order, const int* __restrict__ nsel, int poolOff)
{
    __shared__ float As[64 * 20];
    __shared__ float Bs[64 * 20];
    __shared__ const float* rowp[64];
    __shared__ float rowsc[64];

    const int tid = threadIdx.x;
    const int tx = tid & 15, ty = tid >> 4;
    const int bx = blockIdx.x;
    const int n0 = blockIdx.y * 64;

    int tileb = 0, tilet0 = 0;
    if (AMODE != 0) { tileb = bx / tilesPerB; tilet0 = (bx % tilesPerB) * 64; }

    if (tid < 64) {
        const float* p = nullptr; float sc = 1.f;
        if (AMODE == 0) {
            p = A + ((size_t)bx * 64 + tid) * (size_t)ldA;
        } else if (AMODE == 1) {
            int t = tilet0 + tid;
            int src = order[tileb * T_ + t];
            p = A + ((size_t)tileb * T_ + src) * (size_t)ldA;
            sc = (t < nsel[tileb]) ? 1.f : 0.f;
        } else {
            int t = tilet0 + tid;
            if (t < rowsPerB) p = A + ((size_t)tileb * T_ + t) * (size_t)H_;
        }
        rowp[tid] = p; rowsc[tid] = sc;
    }
    __syncthreads();

    float acc[4][4] = {};
    const int rl = tid >> 2, kl = (tid & 3) * 4;
    const float* __restrict__ ap = rowp[rl];
    const float  asc = rowsc[rl];
    const float* __restrict__ wrow = W + (size_t)(n0 + rl) * (size_t)K + kl;

    for (int k0 = 0; k0 < K; k0 += 16) {
        float4 av = make_float4(0.f, 0.f, 0.f, 0.f);
        if (ap) av = *(const float4*)(ap + k0 + kl);
        float4 wv = *(const float4*)(wrow + k0);
        __syncthreads();
        As[rl*20+kl+0] = av.x * asc; As[rl*20+kl+1] = av.y * asc;
        As[rl*20+kl+2] = av.z * asc; As[rl*20+kl+3] = av.w * asc;
        Bs[rl*20+kl+0] = wv.x; Bs[rl*20+kl+1] = wv.y;
        Bs[rl*20+kl+2] = wv.z; Bs[rl*20+kl+3] = wv.w;
        __syncthreads();
        #pragma unroll
        for (int kk = 0; kk < 16; ++kk) {
            float a0 = As[(ty*4+0)*20+kk], a1 = As[(ty*4+1)*20+kk];
            float a2 = As[(ty*4+2)*20+kk], a3 = As[(ty*4+3)*20+kk];
            float w0 = Bs[(tx*4+0)*20+kk], w1 = Bs[(tx*4+1)*20+kk];
            float w2 = Bs[(tx*4+2)*20+kk], w3 = Bs[(tx*4+3)*20+kk];
            acc[0][0]=fmaf(a0,w0,acc[0][0]); acc[0][1]=fmaf(a0,w1,acc[0][1]);
            acc[0][2]=fmaf(a0,w2,acc[0][2]); acc[0][3]=fmaf(a0,w3,acc[0][3]);
            acc[1][0]=fmaf(a1,w0,acc[1][0]); acc[1][1]=fmaf(a1,w1,acc[1][1]);
            acc[1][2]=fmaf(a1,w2,acc[1][2]); acc[1][3]=fmaf(a1,w3,acc[1][3]);
            acc[2][0]=fmaf(a2,w0,acc[2][0]); acc[2][1]=fmaf(a2,w1,acc[2][1]);
            acc[2][2]=fmaf(a2,w2,acc[2][2]); acc[2][3]=fmaf(a2,w3,acc[2][3]);
            acc[3][0]=fmaf(a3,w0,acc[3][0]); acc[3][1]=fmaf(a3,w1,acc[3][1]);
            acc[3][2]=fmaf(a3,w2,acc[3][2]); acc[3][3]=fmaf(a3,w3,acc[3][3]);
        }
    }

    if (OMODE == 0 || OMODE == 1) {
        #pragma unroll
        for (int i = 0; i < 4; ++i) {
            int m;
            if (AMODE == 0) m = bx * 64 + ty*4 + i;
            else            m = tileb * T_ + tilet0 + ty*4 + i;
            size_t co = (size_t)m * (size_t)N + n0 + tx*4;
            #pragma unroll
            for (int j = 0; j < 4; ++j) {
                float v = acc[i][j] + bias[n0 + tx*4 + j];
                if (OMODE == 0) Cf[co + j] = v;
                else            Cb[co + j] = __float2bfloat16(v);
            }
        }
    } else {
        float mx[4] = {0.f, 0.f, 0.f, 0.f};
        #pragma unroll
        for (int i = 0; i < 4; ++i) {
            int t = tilet0 + ty*4 + i;
            bool v = t < rowsPerB;
            #pragma unroll
            for (int j = 0; j < 4; ++j) {
                float val = fmaxf(acc[i][j] + bias[n0 + tx*4 + j], 0.f);
                if (v) mx[j] = fmaxf(mx[j], val);
            }
        }
        __syncthreads();
        #pragma unroll
        for (int j = 0; j < 4; ++j) As[(tx*4+j)*17 + ty] = mx[j];
        __syncthreads();
        if (tid < 64) {
            float m = 0.f;
            #pragma unroll
            for (int q = 0; q < 16; ++q) m = fmaxf(m, As[tid*17 + q]);
            atomicMax(&pool[(size_t)tileb * (3*NF_) + poolOff + n0 + tid],
                      __float_as_uint(m));
        }
    }
}

// =====================================================================
// Weight f32 -> bf16 prep.
// =====================================================================
__global__ void wprep_k(const float* __restrict__ W, unsigned short* __restrict__ o, int n)
{
    int i = blockIdx.x * 256 + threadIdx.x;
    if (i < n) o[i] = f2bu(W[i]);
}

// =====================================================================
// Selector GRU (fp32 exact): 64 WGs x 256 thr (4 waves).
// Thread: b = tid&63, g = tid>>6; owns units iu0 = bx*8+2g, iu0+1.
// Weights (24 rows) + dW resident in LDS. h ping-pong f32 [b][k] in
// global, staged per step in 4 chunks of 128 k (2 LDS buffers, [k][b]).
// Selector dot accumulated in-loop on wave g==0 (lane = batch).
// =====================================================================
__global__ __launch_bounds__(256) void rec_sel(
    const float* __restrict__ giF,
    const float* __restrict__ Whh, const float* __restrict__ bhh,
    const float* __restrict__ Ws, const float* __restrict__ bs,
    float* __restrict__ h0, float* __restrict__ h1,
    int* __restrict__ selp, int* __restrict__ flags)
{
    __shared__ float Wl[24 * 512];
    __shared__ float dWl[512];
    __shared__ float hsb[2][128 * 66];

    const int tid = threadIdx.x;
    const int b = tid & 63;
    const int g = tid >> 6;
    const int bx = blockIdx.x;
    const int iu0 = bx * 8 + 2 * g;
    const int u0 = 2 * g, u1 = 2 * g + 1;

    for (int idx = tid; idx < 24 * 512; idx += 256) {
        int r = idx >> 9, k = idx & 511;
        int ul = r / 3, gate = r - ul * 3;
        Wl[idx] = Whh[((size_t)gate * 512 + bx * 8 + ul) * 512 + k];
    }
    for (int k = tid; k < 512; k += 256) dWl[k] = Ws[512 + k] - Ws[k];
    __syncthreads();

    const float bR0 = bhh[iu0],        bR1 = bhh[iu0 + 1];
    const float bZ0 = bhh[512 + iu0],  bZ1 = bhh[512 + iu0 + 1];
    const float bN0 = bhh[1024 + iu0], bN1 = bhh[1024 + iu0 + 1];
    const float db  = bs[1] - bs[0];
    const float* __restrict__ wR0 = Wl + (u0 * 3 + 0) * 512;
    const float* __restrict__ wZ0 = Wl + (u0 * 3 + 1) * 512;
    const float* __restrict__ wN0 = Wl + (u0 * 3 + 2) * 512;
    const float* __restrict__ wR1 = Wl + (u1 * 3 + 0) * 512;
    const float* __restrict__ wZ1 = Wl + (u1 * 3 + 1) * 512;
    const float* __restrict__ wN1 = Wl + (u1 * 3 + 2) * 512;
    const int hpc = iu0 >> 7;   // chunk holding this thread's own units

    for (int t = 0; t <= T_; ++t) {
        const bool comp = (t < T_);
        const float* hcur = (t & 1) ? h1 : h0;
        float* hnxt = (t & 1) ? h0 : h1;

        if (t > 0) bar_wait<64>(flags, t, tid);

        float ir0 = 0, iz0 = 0, in0 = 0, ir1 = 0, iz1 = 0, in1 = 0;
        if (comp) {
            const float* gp = giF + ((size_t)b * T_ + t) * G_;
            ir0 = gp[iu0];        ir1 = gp[iu0 + 1];
            iz0 = gp[512 + iu0];  iz1 = gp[512 + iu0 + 1];
            in0 = gp[1024 + iu0]; in1 = gp[1024 + iu0 + 1];
        }

        const float* hrow = hcur + (size_t)b * 512 + g * 32;
        float4 a0, a1, a2, a3, a4, a5, a6, a7;
        CLOAD4(a0, hrow + 0);  CLOAD4(a1, hrow + 4);
        CLOAD4(a2, hrow + 8);  CLOAD4(a3, hrow + 12);
        CLOAD4(a4, hrow + 16); CLOAD4(a5, hrow + 20);
        CLOAD4(a6, hrow + 24); CLOAD4(a7, hrow + 28);

        float aR0 = bR0, aR1 = bR1, aZ0 = bZ0, aZ1 = bZ1, aN0 = bN0, aN1 = bN1;
        float dot = 0.f, hp0 = 0.f, hp1 = 0.f;

        for (int c = 0; c < 4; ++c) {
            float* hb = hsb[c & 1];
            CWAIT();
            #define WRCH(A, J) \
                hb[(g*32+(J)*4+0)*66+b]=A.x; hb[(g*32+(J)*4+1)*66+b]=A.y; \
                hb[(g*32+(J)*4+2)*66+b]=A.z; hb[(g*32+(J)*4+3)*66+b]=A.w;
            WRCH(a0,0) WRCH(a1,1) WRCH(a2,2) WRCH(a3,3)
            WRCH(a4,4) WRCH(a5,5) WRCH(a6,6) WRCH(a7,7)
            #undef WRCH
            __syncthreads();
            if (c < 3) {
                const float* hn2 = hrow + (c + 1) * 128;
                CLOAD4(a0, hn2 + 0);  CLOAD4(a1, hn2 + 4);
                CLOAD4(a2, hn2 + 8);  CLOAD4(a3, hn2 + 12);
                CLOAD4(a4, hn2 + 16); CLOAD4(a5, hn2 + 20);
                CLOAD4(a6, hn2 + 24); CLOAD4(a7, hn2 + 28);
            }
            const int k0 = c * 128;
            if (comp) {
                if (g == 0) {
                    #pragma unroll 4
                    for (int kk = 0; kk < 128; ++kk) {
                        const float hv = hb[kk * 66 + b];
                        const int k = k0 + kk;
                        aR0 = fmaf(hv, wR0[k], aR0); aR1 = fmaf(hv, wR1[k], aR1);
                        aZ0 = fmaf(hv, wZ0[k], aZ0); aZ1 = fmaf(hv, wZ1[k], aZ1);
                        aN0 = fmaf(hv, wN0[k], aN0); aN1 = fmaf(hv, wN1[k], aN1);
                        dot = fmaf(hv, dWl[k], dot);
                    }
                } else {
                    #pragma unroll 4
                    for (int kk = 0; kk < 128; ++kk) {
                        const float hv = hb[kk * 66 + b];
                        const int k = k0 + kk;
                        aR0 = fmaf(hv, wR0[k], aR0); aR1 = fmaf(hv, wR1[k], aR1);
                        aZ0 = fmaf(hv, wZ0[k], aZ0); aZ1 = fmaf(hv, wZ1[k], aZ1);
                        aN0 = fmaf(hv, wN0[k], aN0); aN1 = fmaf(hv, wN1[k], aN1);
                    }
                }
            } else if (g == 0) {
                #pragma unroll 4
                for (int kk = 0; kk < 128; ++kk)
                    dot = fmaf(hb[kk * 66 + b], dWl[k0 + kk], dot);
            }
            if (comp && c == hpc) {
                hp0 = hb[(iu0 & 127) * 66 + b];
                hp1 = hb[((iu0 & 127) + 1) * 66 + b];
            }
        }

        if (comp) {
            const float r0 = sigm(ir0 + aR0), r1 = sigm(ir1 + aR1);
            const float z0 = sigm(iz0 + aZ0), z1 = sigm(iz1 + aZ1);
            const float n0 = tanhf(in0 + r0 * aN0), n1 = tanhf(in1 + r1 * aN1);
            float2 pv;
            pv.x = (1.f - z0) * n0 + z0 * hp0;
            pv.y = (1.f - z1) * n1 + z1 * hp1;
            const float* hdst = hnxt + (size_t)b * 512 + iu0;
            CSTORE8(hdst, pv);
        }
        if (g == 0 && t >= 1)
            selp[b * T_ + (t - 1)] = ((dot + db) > 0.f) ? 1 : 0;

        if (t < T_) bar_arrive(flags, t, tid, bx);
    }
}

// =====================================================================
// Layer GRU via MFMA (bf16): 32 WGs x 256 thr (4 waves); WG owns 16
// units (48 gate rows in LDS, bf16, loaded once). h ping-pong bf16
// [b][512] in global; staged to LDS [b-row][1040B] per step. Wave q =
// m-tile (batches 16q..16q+15), computes 3 n-tiles x 16 k-steps = 48
// MFMA. Gates -> LDS gbuf -> per-thread epilogue (4 units each).
// =====================================================================
__global__ __launch_bounds__(256) void rec_mfma(
    const unsigned short* __restrict__ giB,
    const unsigned short* __restrict__ wbf,
    const float* __restrict__ bhh,
    const int* __restrict__ nselp, const int* __restrict__ maxnp,
    unsigned short* __restrict__ hA, unsigned short* __restrict__ hBp,
    float* __restrict__ outp, int* __restrict__ flags)
{
    __shared__ __align__(16) unsigned char ldsW[48 * 1040];
    __shared__ __align__(16) unsigned char ldsH[64 * 1040];
    __shared__ float gbuf[48 * 66];

    const int tid = threadIdx.x;
    const int l = tid & 63;
    const int q = tid >> 6;
    const int bx = blockIdx.x;
    const int i0 = bx * 16;
    const int b = tid & 63;

    // weights -> LDS (48 rows x 1024B, stride 1040)
    for (int idx = tid; idx < 48 * 64; idx += 256) {
        const int r = idx >> 6, seg = idx & 63;
        const int tier = r >> 4, ul = r & 15;
        const float4 v = *(const float4*)((const char*)wbf
            + ((size_t)(tier * 512 + i0 + ul) * 512) * 2 + seg * 16);
        *(float4*)(ldsW + r * 1040 + seg * 16) = v;
    }
    const float4 bRv = *(const float4*)(bhh + i0 + 4 * q);
    const float4 bZv = *(const float4*)(bhh + 512 + i0 + 4 * q);
    const float4 bNv = *(const float4*)(bhh + 1024 + i0 + 4 * q);
    const int ns = nselp[b];
    const int TOTAL = *maxnp;
    __syncthreads();

    for (int t = 0; t < TOTAL; ++t) {
        const unsigned short* hcur = (t & 1) ? hBp : hA;
        unsigned short* hnxt = (t & 1) ? hA : hBp;

        if (t > 0) bar_wait<32>(flags, t, tid);

        // gi for this step (cached loads, land before epilogue)
        const unsigned short* gp = giB + ((size_t)b * T_ + t) * (size_t)G_ + i0 + 4 * q;
        const uint2 gR = *(const uint2*)gp;
        const uint2 gZ = *(const uint2*)(gp + 512);
        const uint2 gN = *(const uint2*)(gp + 1024);

        // stage h(t): 64KB, 256B/thread, coherent
        {
            const char* src = (const char*)hcur + tid * 256;
            float4 s0, s1, s2, s3, s4, s5, s6, s7, s8, s9, sa, sb_, sc, sd, se, sf;
            CLOAD4(s0, src + 0 * 16);  CLOAD4(s1, src + 1 * 16);
            CLOAD4(s2, src + 2 * 16);  CLOAD4(s3, src + 3 * 16);
            CLOAD4(s4, src + 4 * 16);  CLOAD4(s5, src + 5 * 16);
            CLOAD4(s6, src + 6 * 16);  CLOAD4(s7, src + 7 * 16);
            CLOAD4(s8, src + 8 * 16);  CLOAD4(s9, src + 9 * 16);
            CLOAD4(sa, src + 10 * 16); CLOAD4(sb_, src + 11 * 16);
            CLOAD4(sc, src + 12 * 16); CLOAD4(sd, src + 13 * 16);
            CLOAD4(se, src + 14 * 16); CLOAD4(sf, src + 15 * 16);
            CWAIT();
            char* dst = (char*)ldsH + (tid >> 2) * 1040 + (tid & 3) * 256;
            *(float4*)(dst + 0 * 16) = s0;  *(float4*)(dst + 1 * 16) = s1;
            *(float4*)(dst + 2 * 16) = s2;  *(float4*)(dst + 3 * 16) = s3;
            *(float4*)(dst + 4 * 16) = s4;  *(float4*)(dst + 5 * 16) = s5;
            *(float4*)(dst + 6 * 16) = s6;  *(float4*)(dst + 7 * 16) = s7;
            *(float4*)(dst + 8 * 16) = s8;  *(float4*)(dst + 9 * 16) = s9;
            *(float4*)(dst + 10 * 16) = sa; *(float4*)(dst + 11 * 16) = sb_;
            *(float4*)(dst + 12 * 16) = sc; *(float4*)(dst + 13 * 16) = sd;
            *(float4*)(dst + 14 * 16) = se; *(float4*)(dst + 15 * 16) = sf;
        }
        __syncthreads();

        // MFMA: wave q = m-tile q
        f32x4 ac0 = {0.f, 0.f, 0.f, 0.f};
        f32x4 ac1 = {0.f, 0.f, 0.f, 0.f};
        f32x4 ac2 = {0.f, 0.f, 0.f, 0.f};
        {
            const char* ab = (const char*)ldsH + (q * 16 + (l & 15)) * 1040 + (l >> 4) * 16;
            const char* bb = (const char*)ldsW + (l & 15) * 1040 + (l >> 4) * 16;
            #pragma unroll
            for (int ks = 0; ks < 16; ++ks) {
                const bf16x8 av = *(const bf16x8*)(ab + ks * 64);
                const bf16x8 w0 = *(const bf16x8*)(bb + ks * 64);
                const bf16x8 w1 = *(const bf16x8*)(bb + 16 * 1040 + ks * 64);
                const bf16x8 w2 = *(const bf16x8*)(bb + 32 * 1040 + ks * 64);
                ac0 = __builtin_amdgcn_mfma_f32_16x16x32_bf16(av, w0, ac0, 0, 0, 0);
                ac1 = __builtin_amdgcn_mfma_f32_16x16x32_bf16(av, w1, ac1, 0, 0, 0);
                ac2 = __builtin_amdgcn_mfma_f32_16x16x32_bf16(av, w2, ac2, 0, 0, 0);
            }
        }
        {
            const int gcol = q * 16 + 4 * (l >> 4);
            const int grow = l & 15;
            #pragma unroll
            for (int r = 0; r < 4; ++r) {
                gbuf[grow * 66 + gcol + r]        = ac0[r];
                gbuf[(16 + grow) * 66 + gcol + r] = ac1[r];
                gbuf[(32 + grow) * 66 + gcol + r] = ac2[r];
            }
        }
        __syncthreads();

        // epilogue: thread -> batch b, units u = 4q..4q+3
        {
            const ushort4 hp4 = *(const ushort4*)((const char*)ldsH
                                 + b * 1040 + (i0 + 4 * q) * 2);
            const unsigned short hpb[4] = {hp4.x, hp4.y, hp4.z, hp4.w};
            const float irv[4] = {b2f(gR.x & 0xffff), b2f(gR.x >> 16),
                                  b2f(gR.y & 0xffff), b2f(gR.y >> 16)};
            const float izv[4] = {b2f(gZ.x & 0xffff), b2f(gZ.x >> 16),
                                  b2f(gZ.y & 0xffff), b2f(gZ.y >> 16)};
            const float inv[4] = {b2f(gN.x & 0xffff), b2f(gN.x >> 16),
                                  b2f(gN.y & 0xffff), b2f(gN.y >> 16)};
            float4 o;
            unsigned short ob[4];
            #pragma unroll
            for (int j = 0; j < 4; ++j) {
                const int u = 4 * q + j;
                const float hr = gbuf[u * 66 + b]        + bRv[j];
                const float hz = gbuf[(16 + u) * 66 + b] + bZv[j];
                const float hn = gbuf[(32 + u) * 66 + b] + bNv[j];
                const float rr = sigm(irv[j] + hr);
                const float zz = sigm(izv[j] + hz);
                const float nn = tanhf(inv[j] + rr * hn);
                const float hpf = b2f(hpb[j]);
                float hv = (1.f - zz) * nn + zz * hpf;
                if (t >= ns) hv = hpf;
                ((float*)&o)[j] = hv;
                ob[j] = f2bu(hv);
            }
            if (t < ns)
                *(float4*)(outp + ((size_t)b * T_ + t) * 512 + i0 + 4 * q) = o;
            uint2 hpk;
            hpk.x = (unsigned)ob[0] | ((unsigned)ob[1] << 16);
            hpk.y = (unsigned)ob[2] | ((unsigned)ob[3] << 16);
            const unsigned short* hdst = hnxt + (size_t)b * 512 + i0 + 4 * q;
            CSTORE8(hdst, hpk);
        }

        if (t + 1 < TOTAL) bar_arrive(flags, t, tid, bx);
    }
}

// =====================================================================
// Per-batch selection post-processing (unchanged).
// =====================================================================
__global__ void build_order_k(const int* __restrict__ mask, const int* __restrict__ sel,
                              int* __restrict__ order, int* __restrict__ nsel,
                              int* __restrict__ maxn)
{
    const int b = threadIdx.x;
    int lens = 0;
    for (int t = 0; t < T_; ++t) lens += (mask[b * T_ + t] != 0);
    int cnt = 0;
    for (int t = 0; t < T_; ++t) {
        int s = sel[b * T_ + t];
        if (t == 0) s = 1;
        if (t == lens - 1) s = 1;
        if (t >= lens) s = 0;
        if (s) order[b * T_ + (cnt++)] = t;
    }
    nsel[b] = cnt;
    int c2 = cnt;
    for (int t = 0; t < T_; ++t) {
        int s = sel[b * T_ + t];
        if (t == 0) s = 1;
        if (t == lens - 1) s = 1;
        if (t >= lens) s = 0;
        if (!s) order[b * T_ + (c2++)] = t;
    }
    __shared__ int red[64];
    red[b] = cnt;
    __syncthreads();
    if (b == 0) {
        int m = 0;
        for (int qq = 0; qq < 64; ++qq) m = max(m, red[qq]);
        *maxn = m;
    }
}

// =====================================================================
// Final linear (unchanged).
// =====================================================================
__global__ void final_k(const unsigned int* __restrict__ pool,
                        const float* __restrict__ Wo, const float* __restrict__ bo,
                        float* __restrict__ out)
{
    const int b = threadIdx.x;
    float s = bo[0];
    for (int f = 0; f < 3 * NF_; ++f)
        s = fmaf(__uint_as_float(pool[b * (3*NF_) + f]), Wo[f], s);
    out[b] = s;
}

// =====================================================================
extern "C" void kernel_launch(void* const* d_in, const int* in_sizes, int n_in,
                              void* d_out, int out_size, void* d_ws, size_t ws_size,
                              hipStream_t stream)
{
    (void)in_sizes; (void)n_in; (void)out_size;
    const float* emb   = (const float*)d_in[0];
    const int*   mask  = (const int*)d_in[1];
    const float* Wih_c = (const float*)d_in[2];
    const float* Whh_c = (const float*)d_in[3];
    const float* bih_c = (const float*)d_in[4];
    const float* bhh_c = (const float*)d_in[5];
    const float* Ws    = (const float*)d_in[6];
    const float* bs    = (const float*)d_in[7];
    const float* Wih0  = (const float*)d_in[8];
    const float* Whh0  = (const float*)d_in[9];
    const float* bih0  = (const float*)d_in[10];
    const float* bhh0  = (const float*)d_in[11];
    const float* Wih1  = (const float*)d_in[12];
    const float* Whh1  = (const float*)d_in[13];
    const float* bih1  = (const float*)d_in[14];
    const float* bhh1  = (const float*)d_in[15];
    const float* Wc3   = (const float*)d_in[16];
    const float* bc3   = (const float*)d_in[17];
    const float* Wc4   = (const float*)d_in[18];
    const float* bc4   = (const float*)d_in[19];
    const float* Wc5   = (const float*)d_in[20];
    const float* bc5   = (const float*)d_in[21];
    const float* Wo    = (const float*)d_in[22];
    const float* bo    = (const float*)d_in[23];

    if (ws_size < WS_NEED) return;
    char* ws = (char*)d_ws;
    float*          giC    = (float*)(ws + OFF_GI);
    __hip_bfloat16* giB    = (__hip_bfloat16*)(ws + OFF_GI);
    float*          outbuf = (float*)(ws + OFF_OUT);
    unsigned short* wbf0   = (unsigned short*)(ws + OFF_WBF0);
    unsigned short* wbf1   = (unsigned short*)(ws + OFF_WBF1);
    float*          h0     = (float*)(ws + OFF_H0);
    float*          h1     = (float*)(ws + OFF_H1);
    int*            sel    = (int*)(ws + OFF_SEL);
    int*            order  = (int*)(ws + OFF_ORD);
    int*            nsel   = (int*)(ws + OFF_NSEL);
    int*            maxn   = (int*)(ws + OFF_MAXN);
    int*            flags  = (int*)(ws + OFF_FLG);
    unsigned int*   pool   = (unsigned int*)(ws + OFF_POOL);

    // 1. gi_c = emb @ Wih_c^T + bih_c  (fp32 — argmax precision)
    gemm_k<0,0><<<dim3(512, 24), 256, 0, stream>>>(emb, Wih_c, bih_c, giC, nullptr, nullptr,
                                                   G_, E_, E_, 0, 0, nullptr, nullptr, 0);
    // 2. selector recurrence -> sel
    hipMemsetAsync(flags, 0, 256, stream);
    hipMemsetAsync(h0, 0, (size_t)B_ * H_ * 4, stream);
    rec_sel<<<64, 256, 0, stream>>>(giC, Whh_c, bhh_c, Ws, bs, h0, h1, sel, flags);
    // 3. forcing + stable partition
    build_order_k<<<1, 64, 0, stream>>>(mask, sel, order, nsel, maxn);
    // 3b. bf16 weight prep (into dead giC tail)
    wprep_k<<<(G_ * H_ + 255) / 256, 256, 0, stream>>>(Whh0, wbf0, G_ * H_);
    wprep_k<<<(G_ * H_ + 255) / 256, 256, 0, stream>>>(Whh1, wbf1, G_ * H_);
    // 4. gi0 = new_emb @ Wih0^T + bih0 (gathered rows, bf16 out)
    gemm_k<1,1><<<dim3(512, 24), 256, 0, stream>>>(emb, Wih0, bih0, nullptr, giB, nullptr,
                                                   G_, E_, E_, T_, 8, order, nsel, 0);
    // 5. layer0 recurrence -> out0
    hipMemsetAsync(flags, 0, 256, stream);
    hipMemsetAsync(h0, 0, (size_t)B_ * H_ * 2, stream);
    hipMemsetAsync(outbuf, 0, (size_t)B_ * T_ * H_ * 4, stream);
    rec_mfma<<<32, 256, 0, stream>>>((const unsigned short*)giB, wbf0, bhh0, nsel, maxn,
                                     (unsigned short*)h0, (unsigned short*)h1, outbuf, flags);
    // 6. gi1 = out0 @ Wih1^T + bih1 (bf16 out)
    gemm_k<0,1><<<dim3(512, 24), 256, 0, stream>>>(outbuf, Wih1, bih1, nullptr, giB, nullptr,
                                                   G_, H_, H_, 0, 0, nullptr, nullptr, 0);
    // 7. layer1 recurrence -> out1 (overwrites out0)
    hipMemsetAsync(flags, 0, 256, stream);
    hipMemsetAsync(h0, 0, (size_t)B_ * H_ * 2, stream);
    hipMemsetAsync(outbuf, 0, (size_t)B_ * T_ * H_ * 4, stream);
    rec_mfma<<<32, 256, 0, stream>>>((const unsigned short*)giB, wbf1, bhh1, nsel, maxn,
                                     (unsigned short*)h0, (unsigned short*)h1, outbuf, flags);
    // 8. convs (sliding-window GEMM) + relu + time-max pooling
    hipMemsetAsync(pool, 0, (size_t)B_ * 3 * NF_ * 4, stream);
    gemm_k<2,2><<<dim3(512, 4), 256, 0, stream>>>(outbuf, Wc3, bc3, nullptr, nullptr, pool,
                                                  NF_, 3 * H_, H_, 510, 8, nullptr, nullptr, 0);
    gemm_k<2,2><<<dim3(512, 4), 256, 0, stream>>>(outbuf, Wc4, bc4, nullptr, nullptr, pool,
                                                  NF_, 4 * H_, H_, 509, 8, nullptr, nullptr, 256);
    gemm_k<2,2><<<dim3(512, 4), 256, 0, stream>>>(outbuf, Wc5, bc5, nullptr, nullptr, pool,
                                                  NF_, 5 * H_, H_, 508, 8, nullptr, nullptr, 512);
    // 9. final linear -> d_out (64 f32)
    final_k<<<1, 64, 0, stream>>>(pool, Wo, bo, (float*)d_out);
}

// Round 6
// 16821.335 us; speedup vs baseline: 1.9027x; 1.9027x over previous
//
#include <hip/hip_runtime.h>
#include <hip/hip_bf16.h>
#include <cstddef>

// ---------------- problem constants ----------------
constexpr int B_ = 64, T_ = 512, E_ = 768, H_ = 512, G_ = 1536, NF_ = 256;

typedef float f32x4 __attribute__((ext_vector_type(4)));
typedef __bf16 bf16x8 __attribute__((ext_vector_type(8)));

// ---------------- workspace layout (bytes) ----------------
constexpr size_t SZ_GIC   = (size_t)B_ * T_ * G_ * 4;       // 192 MiB
constexpr size_t OFF_GI   = 0;                              // f32 gi_c / bf16 gi
constexpr size_t OFF_OUT  = (size_t)B_ * T_ * G_ * 2;       // 96MiB: out f32 (64MiB)
// bf16 weight copies live at [170MiB, ~180MiB) — INSIDE gi_c's span!
// gi_c is alive from gemm_f32 until rec_sel completes; wprep_k MUST be
// launched after rec_sel (round-5 lesson: launching it first gets the
// weights clobbered by the gi_c store).
constexpr size_t OFF_WBF0 = 170u * 1024 * 1024;
constexpr size_t OFF_WBF1 = OFF_WBF0 + (size_t)G_ * H_ * 2;
constexpr size_t OFF_WIH0 = OFF_WBF1 + (size_t)G_ * H_ * 2;
constexpr size_t OFF_WIH1 = OFF_WIH0 + (size_t)G_ * E_ * 2;
constexpr size_t OFF_WC3  = OFF_WIH1 + (size_t)G_ * H_ * 2;
constexpr size_t OFF_WC4  = OFF_WC3 + (size_t)NF_ * 3 * H_ * 2;
constexpr size_t OFF_WC5  = OFF_WC4 + (size_t)NF_ * 4 * H_ * 2;
constexpr size_t OFF_MISC = SZ_GIC;
constexpr size_t OFF_H0   = OFF_MISC;
constexpr size_t OFF_H1   = OFF_H0 + (size_t)B_ * H_ * 4;
constexpr size_t OFF_SEL  = OFF_H1 + (size_t)B_ * H_ * 4;
constexpr size_t OFF_ORD  = OFF_SEL + (size_t)B_ * T_ * 4;
constexpr size_t OFF_NSEL = OFF_ORD + (size_t)B_ * T_ * 4;
constexpr size_t OFF_MAXN = OFF_NSEL + 256;
constexpr size_t OFF_FLG  = OFF_MAXN + 256;
constexpr size_t OFF_POOL = OFF_FLG + 256;
constexpr size_t WS_NEED  = OFF_POOL + (size_t)B_ * 3 * NF_ * 4;

// coherent (fabric-level, L1/L2-bypass) access helpers
#define CLOAD4(dst, ptr) \
    asm volatile("global_load_dwordx4 %0, %1, off sc0 sc1" : "=v"(dst) : "v"(ptr))
#define CWAIT() do { \
    asm volatile("s_waitcnt vmcnt(0)" ::: "memory"); \
    __builtin_amdgcn_sched_barrier(0); } while (0)
#define CSTORE4(ptr, val) \
    asm volatile("global_store_dword %0, %1, off sc0 sc1" :: "v"(ptr), "v"(val) : "memory")
#define CSTORE8(ptr, val) \
    asm volatile("global_store_dwordx2 %0, %1, off sc0 sc1" :: "v"(ptr), "v"(val) : "memory")

__device__ __forceinline__ float sigm(float x) { return 1.f / (1.f + expf(-x)); }
__device__ __forceinline__ float b2f(unsigned short u) {
    return __uint_as_float(((unsigned int)u) << 16);
}
__device__ __forceinline__ unsigned short f2bu(float x) {
    __hip_bfloat16 h = __float2bfloat16(x);
    return *(unsigned short*)&h;
}

template<int NWG>
__device__ __forceinline__ void bar_wait(const int* flags, int t, int tid) {
    if (tid < 64) {
        int v;
        for (;;) {
            asm volatile("global_load_dword %0, %1, off sc0 sc1\n\t"
                         "s_waitcnt vmcnt(0)"
                         : "=v"(v) : "v"(flags + (tid & (NWG - 1))) : "memory");
            if (__all(v >= t)) break;
            __builtin_amdgcn_s_sleep(1);
        }
    }
    __syncthreads();
}

__device__ __forceinline__ void bar_arrive(int* flags, int t, int tid, int bx) {
    asm volatile("s_waitcnt vmcnt(0)" ::: "memory");
    __syncthreads();
    if (tid == 0) { int pv = t + 1; CSTORE4(flags + bx, pv); }
}

// =====================================================================
// fp32 tiled GEMM — gi_c only (argmax precision). Stride 21:
// kills the 16-way LDS bank conflict on the Bs reads.
// =====================================================================
__global__ __launch_bounds__(256) void gemm_f32(
    const float* __restrict__ A, const float* __restrict__ W,
    const float* __restrict__ bias, float* __restrict__ Cf,
    int N, int K, int ldA)
{
    __shared__ float As[64 * 21];
    __shared__ float Bs[64 * 21];
    const int tid = threadIdx.x;
    const int tx = tid & 15, ty = tid >> 4;
    const int bx = blockIdx.x;
    const int n0 = blockIdx.y * 64;

    float acc[4][4] = {};
    const int rl = tid >> 2, kl = (tid & 3) * 4;
    const float* __restrict__ ap = A + ((size_t)bx * 64 + rl) * (size_t)ldA + kl;
    const float* __restrict__ wrow = W + (size_t)(n0 + rl) * (size_t)K + kl;

    for (int k0 = 0; k0 < K; k0 += 16) {
        float4 av = *(const float4*)(ap + k0);
        float4 wv = *(const float4*)(wrow + k0);
        __syncthreads();
        As[rl*21+kl+0] = av.x; As[rl*21+kl+1] = av.y;
        As[rl*21+kl+2] = av.z; As[rl*21+kl+3] = av.w;
        Bs[rl*21+kl+0] = wv.x; Bs[rl*21+kl+1] = wv.y;
        Bs[rl*21+kl+2] = wv.z; Bs[rl*21+kl+3] = wv.w;
        __syncthreads();
        #pragma unroll
        for (int kk = 0; kk < 16; ++kk) {
            float a0 = As[(ty*4+0)*21+kk], a1 = As[(ty*4+1)*21+kk];
            float a2 = As[(ty*4+2)*21+kk], a3 = As[(ty*4+3)*21+kk];
            float w0 = Bs[(tx*4+0)*21+kk], w1 = Bs[(tx*4+1)*21+kk];
            float w2 = Bs[(tx*4+2)*21+kk], w3 = Bs[(tx*4+3)*21+kk];
            acc[0][0]=fmaf(a0,w0,acc[0][0]); acc[0][1]=fmaf(a0,w1,acc[0][1]);
            acc[0][2]=fmaf(a0,w2,acc[0][2]); acc[0][3]=fmaf(a0,w3,acc[0][3]);
            acc[1][0]=fmaf(a1,w0,acc[1][0]); acc[1][1]=fmaf(a1,w1,acc[1][1]);
            acc[1][2]=fmaf(a1,w2,acc[1][2]); acc[1][3]=fmaf(a1,w3,acc[1][3]);
            acc[2][0]=fmaf(a2,w0,acc[2][0]); acc[2][1]=fmaf(a2,w1,acc[2][1]);
            acc[2][2]=fmaf(a2,w2,acc[2][2]); acc[2][3]=fmaf(a2,w3,acc[2][3]);
            acc[3][0]=fmaf(a3,w0,acc[3][0]); acc[3][1]=fmaf(a3,w1,acc[3][1]);
            acc[3][2]=fmaf(a3,w2,acc[3][2]); acc[3][3]=fmaf(a3,w3,acc[3][3]);
        }
    }
    #pragma unroll
    for (int i = 0; i < 4; ++i) {
        int m = bx * 64 + ty*4 + i;
        size_t co = (size_t)m * (size_t)N + n0 + tx*4;
        #pragma unroll
        for (int j = 0; j < 4; ++j)
            Cf[co + j] = acc[i][j] + bias[n0 + tx*4 + j];
    }
}

// =====================================================================
// bf16 MFMA GEMM: C[m][n] = sum_k Arow(m)[k] * W[n][k] (+bias).
// A is f32 (cast to bf16 during LDS staging); W pre-cast bf16.
// AMODE: 0 flat rows, 1 gathered rows (order/nsel), 2 conv windows.
// OMODE: 0 bf16 store (+bias), 1 conv relu+bias+time-max -> atomicMax.
// =====================================================================
template<int AMODE, int OMODE>
__global__ __launch_bounds__(256) void gemm_mfma(
    const float* __restrict__ A, const unsigned short* __restrict__ Wb,
    const float* __restrict__ bias,
    unsigned short* __restrict__ Cb, unsigned int* __restrict__ pool,
    int N, int K, int ldA, int rowsPerB, int tilesPerB,
    const int* __restrict__ order, const int* __restrict__ nsel, int poolOff)
{
    __shared__ __align__(16) unsigned short As[64][40];  // pad 40: 2-way-free b128
    __shared__ __align__(16) unsigned short Bs[64][40];
    __shared__ const float* rowp[64];

    const int tid = threadIdx.x;
    const int l = tid & 63;
    const int q = tid >> 6;
    const int bx = blockIdx.x;
    const int n0 = blockIdx.y * 64;

    int tileb = 0, tilet0 = 0;
    if (AMODE != 0) { tileb = bx / tilesPerB; tilet0 = (bx % tilesPerB) * 64; }

    if (tid < 64) {
        const float* p = nullptr;
        if (AMODE == 0) {
            p = A + ((size_t)bx * 64 + tid) * (size_t)ldA;
        } else if (AMODE == 1) {
            int t = tilet0 + tid;
            if (t < nsel[tileb]) {
                int src = order[tileb * T_ + t];
                p = A + ((size_t)tileb * T_ + src) * (size_t)ldA;
            }
        } else {
            int t = tilet0 + tid;
            if (t < rowsPerB) p = A + ((size_t)tileb * T_ + t) * (size_t)ldA;
        }
        rowp[tid] = p;
    }
    __syncthreads();

    f32x4 acc0 = {0.f,0.f,0.f,0.f}, acc1 = {0.f,0.f,0.f,0.f};
    f32x4 acc2 = {0.f,0.f,0.f,0.f}, acc3 = {0.f,0.f,0.f,0.f};

    const int r = tid & 63, seg = tid >> 6;       // staging role
    const float* ap = rowp[r];
    if (ap) ap += seg * 8;
    const unsigned short* wrow = Wb + (size_t)(n0 + r) * (size_t)K + seg * 8;

    for (int k0 = 0; k0 < K; k0 += 32) {
        float4 fa = make_float4(0,0,0,0), fb = make_float4(0,0,0,0);
        if (ap) { fa = *(const float4*)(ap + k0); fb = *(const float4*)(ap + k0 + 4); }
        const uint4 wv = *(const uint4*)(wrow + k0);
        __syncthreads();                 // previous tile fully consumed
        uint4 pk;
        pk.x = (unsigned)f2bu(fa.x) | ((unsigned)f2bu(fa.y) << 16);
        pk.y = (unsigned)f2bu(fa.z) | ((unsigned)f2bu(fa.w) << 16);
        pk.z = (unsigned)f2bu(fb.x) | ((unsigned)f2bu(fb.y) << 16);
        pk.w = (unsigned)f2bu(fb.z) | ((unsigned)f2bu(fb.w) << 16);
        *(uint4*)&As[r][seg * 8] = pk;
        *(uint4*)&Bs[r][seg * 8] = wv;
        __syncthreads();
        const bf16x8 av = *(const bf16x8*)&As[q * 16 + (l & 15)][(l >> 4) * 8];
        const bf16x8 b0 = *(const bf16x8*)&Bs[ 0 + (l & 15)][(l >> 4) * 8];
        const bf16x8 b1 = *(const bf16x8*)&Bs[16 + (l & 15)][(l >> 4) * 8];
        const bf16x8 b2 = *(const bf16x8*)&Bs[32 + (l & 15)][(l >> 4) * 8];
        const bf16x8 b3 = *(const bf16x8*)&Bs[48 + (l & 15)][(l >> 4) * 8];
        acc0 = __builtin_amdgcn_mfma_f32_16x16x32_bf16(av, b0, acc0, 0, 0, 0);
        acc1 = __builtin_amdgcn_mfma_f32_16x16x32_bf16(av, b1, acc1, 0, 0, 0);
        acc2 = __builtin_amdgcn_mfma_f32_16x16x32_bf16(av, b2, acc2, 0, 0, 0);
        acc3 = __builtin_amdgcn_mfma_f32_16x16x32_bf16(av, b3, acc3, 0, 0, 0);
    }

    f32x4 accs[4] = {acc0, acc1, acc2, acc3};
    if (OMODE == 0) {
        const int mbase = (AMODE == 0) ? bx * 64 : tileb * T_ + tilet0;
        #pragma unroll
        for (int s = 0; s < 4; ++s) {
            const int col = n0 + s * 16 + (l & 15);
            const float bv = bias[col];
            #pragma unroll
            for (int reg = 0; reg < 4; ++reg) {
                const int m = mbase + q * 16 + (l >> 4) * 4 + reg;
                Cb[(size_t)m * (size_t)N + col] = f2bu(accs[s][reg] + bv);
            }
        }
    } else {
        #pragma unroll
        for (int s = 0; s < 4; ++s) {
            const int col = n0 + s * 16 + (l & 15);
            const float bv = bias[col];
            float mx = 0.f;
            #pragma unroll
            for (int reg = 0; reg < 4; ++reg) {
                const int t = tilet0 + q * 16 + (l >> 4) * 4 + reg;
                const float val = fmaxf(accs[s][reg] + bv, 0.f);
                if (t < rowsPerB) mx = fmaxf(mx, val);
            }
            mx = fmaxf(mx, __shfl_xor(mx, 16));
            mx = fmaxf(mx, __shfl_xor(mx, 32));
            if (l < 16)
                atomicMax(&pool[(size_t)tileb * (3*NF_) + poolOff + n0 + s*16 + l],
                          __float_as_uint(mx));
        }
    }
}

// =====================================================================
// Weight f32 -> bf16 prep.
// =====================================================================
__global__ void wprep_k(const float* __restrict__ W, unsigned short* __restrict__ o, int n)
{
    int i = blockIdx.x * 256 + threadIdx.x;
    if (i < n) o[i] = f2bu(W[i]);
}

// =====================================================================
// Selector GRU v4 (fp32 exact): 64 WGs x 512 thr (8 waves).
// Wave w = unit i = bx*8+w; lane = batch b. Weights LDS-resident,
// read as wave-uniform float4 (broadcast). h ping-pong f32 [k][b]
// (coalesced loads AND stores), staged in 2x64KB chunks with overlap.
// Selector dot folded into wave 0's loop; extra t=T dot-only step.
// =====================================================================
template<bool GATES, bool DOT>
__device__ __forceinline__ void sel_chunk(
    const float* __restrict__ hs, int b,
    const float* __restrict__ wR, const float* __restrict__ wZ,
    const float* __restrict__ wN, const float* __restrict__ dWl, int cb,
    float& aR, float& aZ, float& aN, float& dot)
{
    #pragma unroll 4
    for (int kq = 0; kq < 64; ++kq) {
        const float hv0 = hs[(kq*4+0)*64 + b];
        const float hv1 = hs[(kq*4+1)*64 + b];
        const float hv2 = hs[(kq*4+2)*64 + b];
        const float hv3 = hs[(kq*4+3)*64 + b];
        if (GATES) {
            const float4 wr = *(const float4*)(wR + cb + kq*4);
            const float4 wz = *(const float4*)(wZ + cb + kq*4);
            const float4 wn = *(const float4*)(wN + cb + kq*4);
            aR = fmaf(hv0, wr.x, aR); aR = fmaf(hv1, wr.y, aR);
            aR = fmaf(hv2, wr.z, aR); aR = fmaf(hv3, wr.w, aR);
            aZ = fmaf(hv0, wz.x, aZ); aZ = fmaf(hv1, wz.y, aZ);
            aZ = fmaf(hv2, wz.z, aZ); aZ = fmaf(hv3, wz.w, aZ);
            aN = fmaf(hv0, wn.x, aN); aN = fmaf(hv1, wn.y, aN);
            aN = fmaf(hv2, wn.z, aN); aN = fmaf(hv3, wn.w, aN);
        }
        if (DOT) {
            const float4 dv = *(const float4*)(dWl + cb + kq*4);
            dot = fmaf(hv0, dv.x, dot); dot = fmaf(hv1, dv.y, dot);
            dot = fmaf(hv2, dv.z, dot); dot = fmaf(hv3, dv.w, dot);
        }
    }
}

__global__ __launch_bounds__(512) void rec_sel(
    const float* __restrict__ giF,
    const float* __restrict__ Whh, const float* __restrict__ bhh,
    const float* __restrict__ Ws, const float* __restrict__ bs,
    float* __restrict__ h0, float* __restrict__ h1,
    int* __restrict__ selp, int* __restrict__ flags)
{
    __shared__ float Wl[24 * 512];    // 48KB: rows u*3+gate
    __shared__ float dWl[512];        // 2KB
    __shared__ float hs[256 * 64];    // 64KB chunk, [k-local][b]

    const int tid = threadIdx.x;
    const int b = tid & 63;
    const int w = __builtin_amdgcn_readfirstlane(tid >> 6);
    const int bx = blockIdx.x;
    const int i = bx * 8 + w;

    for (int idx = tid; idx < 24 * 512; idx += 512) {
        int rr = idx >> 9, k = idx & 511;
        int ul = rr / 3, gate = rr - ul * 3;
        Wl[idx] = Whh[((size_t)gate * 512 + bx * 8 + ul) * 512 + k];
    }
    dWl[tid] = Ws[512 + tid] - Ws[tid];
    __syncthreads();

    const float bR = bhh[i], bZ = bhh[512 + i], bN = bhh[1024 + i];
    const float db = bs[1] - bs[0];
    const float* __restrict__ wR = Wl + (w*3 + 0) * 512;
    const float* __restrict__ wZ = Wl + (w*3 + 1) * 512;
    const float* __restrict__ wN = Wl + (w*3 + 2) * 512;
    const int hchunk = i >> 8;         // which chunk holds unit i

    // gi(t=0) prefetch
    float pgR = giF[(size_t)b * T_ * G_ + i];
    float pgZ = giF[(size_t)b * T_ * G_ + 512 + i];
    float pgN = giF[(size_t)b * T_ * G_ + 1024 + i];

    for (int t = 0; t <= T_; ++t) {
        const bool comp = (t < T_);
        const float* hcur = (t & 1) ? h1 : h0;
        float* hnxt = (t & 1) ? h0 : h1;

        if (t > 0) bar_wait<64>(flags, t, tid);

        const float* hc = hcur + (size_t)tid * 4;
        float* hd = hs + tid * 4;
        float4 a0,a1,a2,a3,a4,a5,a6,a7;
        // ---- chunk 0: load + land ----
        CLOAD4(a0, hc + 0*2048); CLOAD4(a1, hc + 1*2048);
        CLOAD4(a2, hc + 2*2048); CLOAD4(a3, hc + 3*2048);
        CLOAD4(a4, hc + 4*2048); CLOAD4(a5, hc + 5*2048);
        CLOAD4(a6, hc + 6*2048); CLOAD4(a7, hc + 7*2048);
        CWAIT();
        *(float4*)(hd + 0*2048) = a0; *(float4*)(hd + 1*2048) = a1;
        *(float4*)(hd + 2*2048) = a2; *(float4*)(hd + 3*2048) = a3;
        *(float4*)(hd + 4*2048) = a4; *(float4*)(hd + 5*2048) = a5;
        *(float4*)(hd + 6*2048) = a6; *(float4*)(hd + 7*2048) = a7;
        __syncthreads();
        // ---- issue chunk 1 loads (fly during chunk-0 compute) ----
        CLOAD4(a0, hc +  8*2048); CLOAD4(a1, hc +  9*2048);
        CLOAD4(a2, hc + 10*2048); CLOAD4(a3, hc + 11*2048);
        CLOAD4(a4, hc + 12*2048); CLOAD4(a5, hc + 13*2048);
        CLOAD4(a6, hc + 14*2048); CLOAD4(a7, hc + 15*2048);

        float aR = bR, aZ = bZ, aN = bN, dot = 0.f, hp = 0.f;
        if (comp) {
            if (w == 0) sel_chunk<true,true >(hs, b, wR, wZ, wN, dWl, 0, aR, aZ, aN, dot);
            else        sel_chunk<true,false>(hs, b, wR, wZ, wN, dWl, 0, aR, aZ, aN, dot);
            if (hchunk == 0) hp = hs[(i & 255)*64 + b];
        } else if (w == 0) {
            sel_chunk<false,true>(hs, b, wR, wZ, wN, dWl, 0, aR, aZ, aN, dot);
        }
        __syncthreads();            // everyone done reading chunk 0
        CWAIT();
        *(float4*)(hd + 0*2048) = a0; *(float4*)(hd + 1*2048) = a1;
        *(float4*)(hd + 2*2048) = a2; *(float4*)(hd + 3*2048) = a3;
        *(float4*)(hd + 4*2048) = a4; *(float4*)(hd + 5*2048) = a5;
        *(float4*)(hd + 6*2048) = a6; *(float4*)(hd + 7*2048) = a7;
        __syncthreads();
        if (comp) {
            if (w == 0) sel_chunk<true,true >(hs, b, wR, wZ, wN, dWl, 256, aR, aZ, aN, dot);
            else        sel_chunk<true,false>(hs, b, wR, wZ, wN, dWl, 256, aR, aZ, aN, dot);
            if (hchunk == 1) hp = hs[(i & 255)*64 + b];
        } else if (w == 0) {
            sel_chunk<false,true>(hs, b, wR, wZ, wN, dWl, 256, aR, aZ, aN, dot);
        }

        if (comp) {
            const float r = sigm(pgR + aR);
            const float z = sigm(pgZ + aZ);
            const float n = tanhf(pgN + r * aN);
            const float hn = (1.f - z) * n + z * hp;
            // gi(t+1) prefetch (cached; lands during barrier/next stage)
            if (t + 1 < T_) {
                const float* gp = giF + ((size_t)b * T_ + t + 1) * G_;
                pgR = gp[i]; pgZ = gp[512 + i]; pgN = gp[1024 + i];
            }
            const float* hdst = hnxt + (size_t)i * 64 + b;   // coalesced
            CSTORE4(hdst, hn);
        }
        if (w == 0 && bx == 0 && t >= 1)
            selp[b * T_ + (t - 1)] = ((dot + db) > 0.f) ? 1 : 0;

        if (t < T_) bar_arrive(flags, t, tid, bx);
    }
}

// =====================================================================
// Layer GRU via MFMA (verified rounds 4-5 structure).
// =====================================================================
__global__ __launch_bounds__(256) void rec_mfma(
    const unsigned short* __restrict__ giB,
    const unsigned short* __restrict__ wbf,
    const float* __restrict__ bhh,
    const int* __restrict__ nselp, const int* __restrict__ maxnp,
    unsigned short* __restrict__ hA, unsigned short* __restrict__ hBp,
    float* __restrict__ outp, int* __restrict__ flags)
{
    __shared__ __align__(16) unsigned char ldsW[48 * 1040];
    __shared__ __align__(16) unsigned char ldsH[64 * 1040];
    __shared__ float gbuf[48 * 66];

    const int tid = threadIdx.x;
    const int l = tid & 63;
    const int q = tid >> 6;
    const int bx = blockIdx.x;
    const int i0 = bx * 16;
    const int b = tid & 63;

    for (int idx = tid; idx < 48 * 64; idx += 256) {
        const int r = idx >> 6, seg = idx & 63;
        const int tier = r >> 4, ul = r & 15;
        const float4 v = *(const float4*)((const char*)wbf
            + ((size_t)(tier * 512 + i0 + ul) * 512) * 2 + seg * 16);
        *(float4*)(ldsW + r * 1040 + seg * 16) = v;
    }
    const float4 bRv = *(const float4*)(bhh + i0 + 4 * q);
    const float4 bZv = *(const float4*)(bhh + 512 + i0 + 4 * q);
    const float4 bNv = *(const float4*)(bhh + 1024 + i0 + 4 * q);
    const int ns = nselp[b];
    const int TOTAL = *maxnp;
    __syncthreads();

    for (int t = 0; t < TOTAL; ++t) {
        const unsigned short* hcur = (t & 1) ? hBp : hA;
        unsigned short* hnxt = (t & 1) ? hA : hBp;

        if (t > 0) bar_wait<32>(flags, t, tid);

        const unsigned short* gp = giB + ((size_t)b * T_ + t) * (size_t)G_ + i0 + 4 * q;
        const uint2 gR = *(const uint2*)gp;
        const uint2 gZ = *(const uint2*)(gp + 512);
        const uint2 gN = *(const uint2*)(gp + 1024);

        {
            const char* src = (const char*)hcur + tid * 256;
            float4 s0, s1, s2, s3, s4, s5, s6, s7, s8, s9, sa, sb_, sc, sd, se, sf;
            CLOAD4(s0, src + 0 * 16);  CLOAD4(s1, src + 1 * 16);
            CLOAD4(s2, src + 2 * 16);  CLOAD4(s3, src + 3 * 16);
            CLOAD4(s4, src + 4 * 16);  CLOAD4(s5, src + 5 * 16);
            CLOAD4(s6, src + 6 * 16);  CLOAD4(s7, src + 7 * 16);
            CLOAD4(s8, src + 8 * 16);  CLOAD4(s9, src + 9 * 16);
            CLOAD4(sa, src + 10 * 16); CLOAD4(sb_, src + 11 * 16);
            CLOAD4(sc, src + 12 * 16); CLOAD4(sd, src + 13 * 16);
            CLOAD4(se, src + 14 * 16); CLOAD4(sf, src + 15 * 16);
            CWAIT();
            char* dst = (char*)ldsH + (tid >> 2) * 1040 + (tid & 3) * 256;
            *(float4*)(dst + 0 * 16) = s0;  *(float4*)(dst + 1 * 16) = s1;
            *(float4*)(dst + 2 * 16) = s2;  *(float4*)(dst + 3 * 16) = s3;
            *(float4*)(dst + 4 * 16) = s4;  *(float4*)(dst + 5 * 16) = s5;
            *(float4*)(dst + 6 * 16) = s6;  *(float4*)(dst + 7 * 16) = s7;
            *(float4*)(dst + 8 * 16) = s8;  *(float4*)(dst + 9 * 16) = s9;
            *(float4*)(dst + 10 * 16) = sa; *(float4*)(dst + 11 * 16) = sb_;
            *(float4*)(dst + 12 * 16) = sc; *(float4*)(dst + 13 * 16) = sd;
            *(float4*)(dst + 14 * 16) = se; *(float4*)(dst + 15 * 16) = sf;
        }
        __syncthreads();

        f32x4 ac0 = {0.f, 0.f, 0.f, 0.f};
        f32x4 ac1 = {0.f, 0.f, 0.f, 0.f};
        f32x4 ac2 = {0.f, 0.f, 0.f, 0.f};
        {
            const char* ab = (const char*)ldsH + (q * 16 + (l & 15)) * 1040 + (l >> 4) * 16;
            const char* bb = (const char*)ldsW + (l & 15) * 1040 + (l >> 4) * 16;
            #pragma unroll
            for (int ks = 0; ks < 16; ++ks) {
                const bf16x8 av = *(const bf16x8*)(ab + ks * 64);
                const bf16x8 w0 = *(const bf16x8*)(bb + ks * 64);
                const bf16x8 w1 = *(const bf16x8*)(bb + 16 * 1040 + ks * 64);
                const bf16x8 w2 = *(const bf16x8*)(bb + 32 * 1040 + ks * 64);
                ac0 = __builtin_amdgcn_mfma_f32_16x16x32_bf16(av, w0, ac0, 0, 0, 0);
                ac1 = __builtin_amdgcn_mfma_f32_16x16x32_bf16(av, w1, ac1, 0, 0, 0);
                ac2 = __builtin_amdgcn_mfma_f32_16x16x32_bf16(av, w2, ac2, 0, 0, 0);
            }
        }
        {
            const int gcol = q * 16 + 4 * (l >> 4);
            const int grow = l & 15;
            #pragma unroll
            for (int r = 0; r < 4; ++r) {
                gbuf[grow * 66 + gcol + r]        = ac0[r];
                gbuf[(16 + grow) * 66 + gcol + r] = ac1[r];
                gbuf[(32 + grow) * 66 + gcol + r] = ac2[r];
            }
        }
        __syncthreads();

        {
            const ushort4 hp4 = *(const ushort4*)((const char*)ldsH
                                 + b * 1040 + (i0 + 4 * q) * 2);
            const unsigned short hpb[4] = {hp4.x, hp4.y, hp4.z, hp4.w};
            const float irv[4] = {b2f(gR.x & 0xffff), b2f(gR.x >> 16),
                                  b2f(gR.y & 0xffff), b2f(gR.y >> 16)};
            const float izv[4] = {b2f(gZ.x & 0xffff), b2f(gZ.x >> 16),
                                  b2f(gZ.y & 0xffff), b2f(gZ.y >> 16)};
            const float inv[4] = {b2f(gN.x & 0xffff), b2f(gN.x >> 16),
                                  b2f(gN.y & 0xffff), b2f(gN.y >> 16)};
            float4 o;
            unsigned short ob[4];
            #pragma unroll
            for (int j = 0; j < 4; ++j) {
                const int u = 4 * q + j;
                const float hr = gbuf[u * 66 + b]        + bRv[j];
                const float hz = gbuf[(16 + u) * 66 + b] + bZv[j];
                const float hn = gbuf[(32 + u) * 66 + b] + bNv[j];
                const float rr = sigm(irv[j] + hr);
                const float zz = sigm(izv[j] + hz);
                const float nn = tanhf(inv[j] + rr * hn);
                const float hpf = b2f(hpb[j]);
                float hv = (1.f - zz) * nn + zz * hpf;
                if (t >= ns) hv = hpf;
                ((float*)&o)[j] = hv;
                ob[j] = f2bu(hv);
            }
            if (t < ns)
                *(float4*)(outp + ((size_t)b * T_ + t) * 512 + i0 + 4 * q) = o;
            uint2 hpk;
            hpk.x = (unsigned)ob[0] | ((unsigned)ob[1] << 16);
            hpk.y = (unsigned)ob[2] | ((unsigned)ob[3] << 16);
            const unsigned short* hdst = hnxt + (size_t)b * 512 + i0 + 4 * q;
            CSTORE8(hdst, hpk);
        }

        if (t + 1 < TOTAL) bar_arrive(flags, t, tid, bx);
    }
}

// =====================================================================
// Per-batch selection post-processing (unchanged).
// =====================================================================
__global__ void build_order_k(const int* __restrict__ mask, const int* __restrict__ sel,
                              int* __restrict__ order, int* __restrict__ nsel,
                              int* __restrict__ maxn)
{
    const int b = threadIdx.x;
    int lens = 0;
    for (int t = 0; t < T_; ++t) lens += (mask[b * T_ + t] != 0);
    int cnt = 0;
    for (int t = 0; t < T_; ++t) {
        int s = sel[b * T_ + t];
        if (t == 0) s = 1;
        if (t == lens - 1) s = 1;
        if (t >= lens) s = 0;
        if (s) order[b * T_ + (cnt++)] = t;
    }
    nsel[b] = cnt;
    int c2 = cnt;
    for (int t = 0; t < T_; ++t) {
        int s = sel[b * T_ + t];
        if (t == 0) s = 1;
        if (t == lens - 1) s = 1;
        if (t >= lens) s = 0;
        if (!s) order[b * T_ + (c2++)] = t;
    }
    __shared__ int red[64];
    red[b] = cnt;
    __syncthreads();
    if (b == 0) {
        int m = 0;
        for (int qq = 0; qq < 64; ++qq) m = max(m, red[qq]);
        *maxn = m;
    }
}

// =====================================================================
// Final linear (unchanged).
// =====================================================================
__global__ void final_k(const unsigned int* __restrict__ pool,
                        const float* __restrict__ Wo, const float* __restrict__ bo,
                        float* __restrict__ out)
{
    const int b = threadIdx.x;
    float s = bo[0];
    for (int f = 0; f < 3 * NF_; ++f)
        s = fmaf(__uint_as_float(pool[b * (3*NF_) + f]), Wo[f], s);
    out[b] = s;
}

// =====================================================================
extern "C" void kernel_launch(void* const* d_in, const int* in_sizes, int n_in,
                              void* d_out, int out_size, void* d_ws, size_t ws_size,
                              hipStream_t stream)
{
    (void)in_sizes; (void)n_in; (void)out_size;
    const float* emb   = (const float*)d_in[0];
    const int*   mask  = (const int*)d_in[1];
    const float* Wih_c = (const float*)d_in[2];
    const float* Whh_c = (const float*)d_in[3];
    const float* bih_c = (const float*)d_in[4];
    const float* bhh_c = (const float*)d_in[5];
    const float* Ws    = (const float*)d_in[6];
    const float* bs    = (const float*)d_in[7];
    const float* Wih0  = (const float*)d_in[8];
    const float* Whh0  = (const float*)d_in[9];
    const float* bih0  = (const float*)d_in[10];
    const float* bhh0  = (const float*)d_in[11];
    const float* Wih1  = (const float*)d_in[12];
    const float* Whh1  = (const float*)d_in[13];
    const float* bih1  = (const float*)d_in[14];
    const float* bhh1  = (const float*)d_in[15];
    const float* Wc3   = (const float*)d_in[16];
    const float* bc3   = (const float*)d_in[17];
    const float* Wc4   = (const float*)d_in[18];
    const float* bc4   = (const float*)d_in[19];
    const float* Wc5   = (const float*)d_in[20];
    const float* bc5   = (const float*)d_in[21];
    const float* Wo    = (const float*)d_in[22];
    const float* bo    = (const float*)d_in[23];

    if (ws_size < WS_NEED) return;
    char* ws = (char*)d_ws;
    float*          giC    = (float*)(ws + OFF_GI);
    unsigned short* giB    = (unsigned short*)(ws + OFF_GI);
    float*          outbuf = (float*)(ws + OFF_OUT);
    unsigned short* wbf0   = (unsigned short*)(ws + OFF_WBF0);
    unsigned short* wbf1   = (unsigned short*)(ws + OFF_WBF1);
    unsigned short* wih0b  = (unsigned short*)(ws + OFF_WIH0);
    unsigned short* wih1b  = (unsigned short*)(ws + OFF_WIH1);
    unsigned short* wc3b   = (unsigned short*)(ws + OFF_WC3);
    unsigned short* wc4b   = (unsigned short*)(ws + OFF_WC4);
    unsigned short* wc5b   = (unsigned short*)(ws + OFF_WC5);
    float*          h0     = (float*)(ws + OFF_H0);
    float*          h1     = (float*)(ws + OFF_H1);
    int*            sel    = (int*)(ws + OFF_SEL);
    int*            order  = (int*)(ws + OFF_ORD);
    int*            nsel   = (int*)(ws + OFF_NSEL);
    int*            maxn   = (int*)(ws + OFF_MAXN);
    int*            flags  = (int*)(ws + OFF_FLG);
    unsigned int*   pool   = (unsigned int*)(ws + OFF_POOL);

    // 1. gi_c = emb @ Wih_c^T + bih_c  (fp32 — argmax precision)
    gemm_f32<<<dim3(512, 24), 256, 0, stream>>>(emb, Wih_c, bih_c, giC, G_, E_, E_);
    // 2. selector recurrence -> sel
    hipMemsetAsync(flags, 0, 256, stream);
    hipMemsetAsync(h0, 0, (size_t)B_ * H_ * 4, stream);
    rec_sel<<<64, 512, 0, stream>>>(giC, Whh_c, bhh_c, Ws, bs, h0, h1, sel, flags);
    // 3. forcing + stable partition
    build_order_k<<<1, 64, 0, stream>>>(mask, sel, order, nsel, maxn);
    // 3b. bf16 weight prep — MUST run after rec_sel: the weight region
    //     aliases gi_c's tail, which is live until rec_sel completes.
    wprep_k<<<(G_*H_ + 255)/256, 256, 0, stream>>>(Whh0, wbf0, G_*H_);
    wprep_k<<<(G_*H_ + 255)/256, 256, 0, stream>>>(Whh1, wbf1, G_*H_);
    wprep_k<<<(G_*E_ + 255)/256, 256, 0, stream>>>(Wih0, wih0b, G_*E_);
    wprep_k<<<(G_*H_ + 255)/256, 256, 0, stream>>>(Wih1, wih1b, G_*H_);
    wprep_k<<<(NF_*3*H_ + 255)/256, 256, 0, stream>>>(Wc3, wc3b, NF_*3*H_);
    wprep_k<<<(NF_*4*H_ + 255)/256, 256, 0, stream>>>(Wc4, wc4b, NF_*4*H_);
    wprep_k<<<(NF_*5*H_ + 255)/256, 256, 0, stream>>>(Wc5, wc5b, NF_*5*H_);
    // 4. gi0 = new_emb @ Wih0^T + bih0 (gathered rows, bf16 MFMA)
    gemm_mfma<1,0><<<dim3(512, 24), 256, 0, stream>>>(emb, wih0b, bih0, giB, nullptr,
                                                      G_, E_, E_, T_, 8, order, nsel, 0);
    // 5. layer0 recurrence -> out0
    hipMemsetAsync(flags, 0, 256, stream);
    hipMemsetAsync(h0, 0, (size_t)B_ * H_ * 2, stream);
    hipMemsetAsync(outbuf, 0, (size_t)B_ * T_ * H_ * 4, stream);
    rec_mfma<<<32, 256, 0, stream>>>(giB, wbf0, bhh0, nsel, maxn,
                                     (unsigned short*)h0, (unsigned short*)h1, outbuf, flags);
    // 6. gi1 = out0 @ Wih1^T + bih1 (bf16 MFMA)
    gemm_mfma<0,0><<<dim3(512, 24), 256, 0, stream>>>(outbuf, wih1b, bih1, giB, nullptr,
                                                      G_, H_, H_, 0, 0, nullptr, nullptr, 0);
    // 7. layer1 recurrence -> out1
    hipMemsetAsync(flags, 0, 256, stream);
    hipMemsetAsync(h0, 0, (size_t)B_ * H_ * 2, stream);
    hipMemsetAsync(outbuf, 0, (size_t)B_ * T_ * H_ * 4, stream);
    rec_mfma<<<32, 256, 0, stream>>>(giB, wbf1, bhh1, nsel, maxn,
                                     (unsigned short*)h0, (unsigned short*)h1, outbuf, flags);
    // 8. convs (bf16 MFMA sliding-window) + relu + time-max pooling
    hipMemsetAsync(pool, 0, (size_t)B_ * 3 * NF_ * 4, stream);
    gemm_mfma<2,1><<<dim3(512, 4), 256, 0, stream>>>(outbuf, wc3b, bc3, nullptr, pool,
                                                     NF_, 3*H_, H_, 510, 8, nullptr, nullptr, 0);
    gemm_mfma<2,1><<<dim3(512, 4), 256, 0, stream>>>(outbuf, wc4b, bc4, nullptr, pool,
                                                     NF_, 4*H_, H_, 509, 8, nullptr, nullptr, 256);
    gemm_mfma<2,1><<<dim3(512, 4), 256, 0, stream>>>(outbuf, wc5b, bc5, nullptr, pool,
                                                     NF_, 5*H_, H_, 508, 8, nullptr, nullptr, 512);
    // 9. final linear -> d_out (64 f32)
    final_k<<<1, 64, 0, stream>>>(pool, Wo, bo, (float*)d_out);
}

// Round 8
// 15679.893 us; speedup vs baseline: 2.0412x; 1.0728x over previous
//
#include <hip/hip_runtime.h>
#include <hip/hip_bf16.h>
#include <cstddef>

// ---------------- problem constants ----------------
constexpr int B_ = 64, T_ = 512, E_ = 768, H_ = 512, G_ = 1536, NF_ = 256;

typedef float f32x4 __attribute__((ext_vector_type(4)));
typedef __bf16 bf16x8 __attribute__((ext_vector_type(8)));

// ---------------- workspace layout (bytes) ----------------
constexpr size_t SZ_GIC   = (size_t)B_ * T_ * G_ * 4;       // 192 MiB
constexpr size_t OFF_GI   = 0;                              // f32 gi_c / later bf16 gi
constexpr size_t OFF_OUT  = (size_t)B_ * T_ * G_ * 2;       // 96MiB: out f32 (64MiB)
// bf16 weight copies alias gi_c's tail -> wprep_k must run AFTER rec_sel.
constexpr size_t OFF_WBF0 = 170u * 1024 * 1024;
constexpr size_t OFF_WBF1 = OFF_WBF0 + (size_t)G_ * H_ * 2;
constexpr size_t OFF_WIH0 = OFF_WBF1 + (size_t)G_ * H_ * 2;
constexpr size_t OFF_WIH1 = OFF_WIH0 + (size_t)G_ * E_ * 2;
constexpr size_t OFF_WC3  = OFF_WIH1 + (size_t)G_ * H_ * 2;
constexpr size_t OFF_WC4  = OFF_WC3 + (size_t)NF_ * 3 * H_ * 2;
constexpr size_t OFF_WC5  = OFF_WC4 + (size_t)NF_ * 4 * H_ * 2;
constexpr size_t OFF_MISC = SZ_GIC;
constexpr size_t OFF_H0   = OFF_MISC;
constexpr size_t OFF_H1   = OFF_H0 + (size_t)B_ * H_ * 4;
constexpr size_t OFF_SEL  = OFF_H1 + (size_t)B_ * H_ * 4;
constexpr size_t OFF_ORD  = OFF_SEL + (size_t)B_ * T_ * 4;
constexpr size_t OFF_NSEL = OFF_ORD + (size_t)B_ * T_ * 4;
constexpr size_t OFF_MAXN = OFF_NSEL + 256;
constexpr size_t OFF_FLG  = OFF_MAXN + 256;
constexpr size_t OFF_POOL = OFF_FLG + 256;
constexpr size_t WS_NEED  = OFF_POOL + (size_t)B_ * 3 * NF_ * 4;

// coherent (fabric-level, L1/L2-bypass) access helpers
#define CLOAD4(dst, ptr) \
    asm volatile("global_load_dwordx4 %0, %1, off sc0 sc1" : "=v"(dst) : "v"(ptr))
#define CWAIT() do { \
    asm volatile("s_waitcnt vmcnt(0)" ::: "memory"); \
    __builtin_amdgcn_sched_barrier(0); } while (0)
#define CSTORE4(ptr, val) \
    asm volatile("global_store_dword %0, %1, off sc0 sc1" :: "v"(ptr), "v"(val) : "memory")
#define CSTORE8(ptr, val) \
    asm volatile("global_store_dwordx2 %0, %1, off sc0 sc1" :: "v"(ptr), "v"(val) : "memory")

__device__ __forceinline__ float sigm(float x) { return 1.f / (1.f + expf(-x)); }
__device__ __forceinline__ float b2f(unsigned short u) {
    return __uint_as_float(((unsigned int)u) << 16);
}
__device__ __forceinline__ unsigned short f2bu(float x) {
    __hip_bfloat16 h = __float2bfloat16(x);
    return *(unsigned short*)&h;
}

template<int NWG>
__device__ __forceinline__ void bar_wait(const int* flags, int t, int tid) {
    if (tid < 64) {
        int v;
        for (;;) {
            asm volatile("global_load_dword %0, %1, off sc0 sc1\n\t"
                         "s_waitcnt vmcnt(0)"
                         : "=v"(v) : "v"(flags + (tid & (NWG - 1))) : "memory");
            if (__all(v >= t)) break;
            __builtin_amdgcn_s_sleep(1);
        }
    }
    __syncthreads();
}

__device__ __forceinline__ void bar_arrive(int* flags, int t, int tid, int bx) {
    asm volatile("s_waitcnt vmcnt(0)" ::: "memory");
    __syncthreads();
    if (tid == 0) { int pv = t + 1; CSTORE4(flags + bx, pv); }
}

// =====================================================================
// fp32 tiled GEMM — gi_c only (argmax precision). Stride 21.
// =====================================================================
__global__ __launch_bounds__(256) void gemm_f32(
    const float* __restrict__ A, const float* __restrict__ W,
    const float* __restrict__ bias, float* __restrict__ Cf,
    int N, int K, int ldA)
{
    __shared__ float As[64 * 21];
    __shared__ float Bs[64 * 21];
    const int tid = threadIdx.x;
    const int tx = tid & 15, ty = tid >> 4;
    const int bx = blockIdx.x;
    const int n0 = blockIdx.y * 64;

    float acc[4][4] = {};
    const int rl = tid >> 2, kl = (tid & 3) * 4;
    const float* __restrict__ ap = A + ((size_t)bx * 64 + rl) * (size_t)ldA + kl;
    const float* __restrict__ wrow = W + (size_t)(n0 + rl) * (size_t)K + kl;

    for (int k0 = 0; k0 < K; k0 += 16) {
        float4 av = *(const float4*)(ap + k0);
        float4 wv = *(const float4*)(wrow + k0);
        __syncthreads();
        As[rl*21+kl+0] = av.x; As[rl*21+kl+1] = av.y;
        As[rl*21+kl+2] = av.z; As[rl*21+kl+3] = av.w;
        Bs[rl*21+kl+0] = wv.x; Bs[rl*21+kl+1] = wv.y;
        Bs[rl*21+kl+2] = wv.z; Bs[rl*21+kl+3] = wv.w;
        __syncthreads();
        #pragma unroll
        for (int kk = 0; kk < 16; ++kk) {
            float a0 = As[(ty*4+0)*21+kk], a1 = As[(ty*4+1)*21+kk];
            float a2 = As[(ty*4+2)*21+kk], a3 = As[(ty*4+3)*21+kk];
            float w0 = Bs[(tx*4+0)*21+kk], w1 = Bs[(tx*4+1)*21+kk];
            float w2 = Bs[(tx*4+2)*21+kk], w3 = Bs[(tx*4+3)*21+kk];
            acc[0][0]=fmaf(a0,w0,acc[0][0]); acc[0][1]=fmaf(a0,w1,acc[0][1]);
            acc[0][2]=fmaf(a0,w2,acc[0][2]); acc[0][3]=fmaf(a0,w3,acc[0][3]);
            acc[1][0]=fmaf(a1,w0,acc[1][0]); acc[1][1]=fmaf(a1,w1,acc[1][1]);
            acc[1][2]=fmaf(a1,w2,acc[1][2]); acc[1][3]=fmaf(a1,w3,acc[1][3]);
            acc[2][0]=fmaf(a2,w0,acc[2][0]); acc[2][1]=fmaf(a2,w1,acc[2][1]);
            acc[2][2]=fmaf(a2,w2,acc[2][2]); acc[2][3]=fmaf(a2,w3,acc[2][3]);
            acc[3][0]=fmaf(a3,w0,acc[3][0]); acc[3][1]=fmaf(a3,w1,acc[3][1]);
            acc[3][2]=fmaf(a3,w2,acc[3][2]); acc[3][3]=fmaf(a3,w3,acc[3][3]);
        }
    }
    #pragma unroll
    for (int i = 0; i < 4; ++i) {
        int m = bx * 64 + ty*4 + i;
        size_t co = (size_t)m * (size_t)N + n0 + tx*4;
        #pragma unroll
        for (int j = 0; j < 4; ++j)
            Cf[co + j] = acc[i][j] + bias[n0 + tx*4 + j];
    }
}

// =====================================================================
// bf16 MFMA GEMM (unchanged, verified round 6).
// =====================================================================
template<int AMODE, int OMODE>
__global__ __launch_bounds__(256) void gemm_mfma(
    const float* __restrict__ A, const unsigned short* __restrict__ Wb,
    const float* __restrict__ bias,
    unsigned short* __restrict__ Cb, unsigned int* __restrict__ pool,
    int N, int K, int ldA, int rowsPerB, int tilesPerB,
    const int* __restrict__ order, const int* __restrict__ nsel, int poolOff)
{
    __shared__ __align__(16) unsigned short As[64][40];
    __shared__ __align__(16) unsigned short Bs[64][40];
    __shared__ const float* rowp[64];

    const int tid = threadIdx.x;
    const int l = tid & 63;
    const int q = tid >> 6;
    const int bx = blockIdx.x;
    const int n0 = blockIdx.y * 64;

    int tileb = 0, tilet0 = 0;
    if (AMODE != 0) { tileb = bx / tilesPerB; tilet0 = (bx % tilesPerB) * 64; }

    if (tid < 64) {
        const float* p = nullptr;
        if (AMODE == 0) {
            p = A + ((size_t)bx * 64 + tid) * (size_t)ldA;
        } else if (AMODE == 1) {
            int t = tilet0 + tid;
            if (t < nsel[tileb]) {
                int src = order[tileb * T_ + t];
                p = A + ((size_t)tileb * T_ + src) * (size_t)ldA;
            }
        } else {
            int t = tilet0 + tid;
            if (t < rowsPerB) p = A + ((size_t)tileb * T_ + t) * (size_t)ldA;
        }
        rowp[tid] = p;
    }
    __syncthreads();

    f32x4 acc0 = {0.f,0.f,0.f,0.f}, acc1 = {0.f,0.f,0.f,0.f};
    f32x4 acc2 = {0.f,0.f,0.f,0.f}, acc3 = {0.f,0.f,0.f,0.f};

    const int r = tid & 63, seg = tid >> 6;
    const float* ap = rowp[r];
    if (ap) ap += seg * 8;
    const unsigned short* wrow = Wb + (size_t)(n0 + r) * (size_t)K + seg * 8;

    for (int k0 = 0; k0 < K; k0 += 32) {
        float4 fa = make_float4(0,0,0,0), fb = make_float4(0,0,0,0);
        if (ap) { fa = *(const float4*)(ap + k0); fb = *(const float4*)(ap + k0 + 4); }
        const uint4 wv = *(const uint4*)(wrow + k0);
        __syncthreads();
        uint4 pk;
        pk.x = (unsigned)f2bu(fa.x) | ((unsigned)f2bu(fa.y) << 16);
        pk.y = (unsigned)f2bu(fa.z) | ((unsigned)f2bu(fa.w) << 16);
        pk.z = (unsigned)f2bu(fb.x) | ((unsigned)f2bu(fb.y) << 16);
        pk.w = (unsigned)f2bu(fb.z) | ((unsigned)f2bu(fb.w) << 16);
        *(uint4*)&As[r][seg * 8] = pk;
        *(uint4*)&Bs[r][seg * 8] = wv;
        __syncthreads();
        const bf16x8 av = *(const bf16x8*)&As[q * 16 + (l & 15)][(l >> 4) * 8];
        const bf16x8 b0 = *(const bf16x8*)&Bs[ 0 + (l & 15)][(l >> 4) * 8];
        const bf16x8 b1 = *(const bf16x8*)&Bs[16 + (l & 15)][(l >> 4) * 8];
        const bf16x8 b2 = *(const bf16x8*)&Bs[32 + (l & 15)][(l >> 4) * 8];
        const bf16x8 b3 = *(const bf16x8*)&Bs[48 + (l & 15)][(l >> 4) * 8];
        acc0 = __builtin_amdgcn_mfma_f32_16x16x32_bf16(av, b0, acc0, 0, 0, 0);
        acc1 = __builtin_amdgcn_mfma_f32_16x16x32_bf16(av, b1, acc1, 0, 0, 0);
        acc2 = __builtin_amdgcn_mfma_f32_16x16x32_bf16(av, b2, acc2, 0, 0, 0);
        acc3 = __builtin_amdgcn_mfma_f32_16x16x32_bf16(av, b3, acc3, 0, 0, 0);
    }

    f32x4 accs[4] = {acc0, acc1, acc2, acc3};
    if (OMODE == 0) {
        const int mbase = (AMODE == 0) ? bx * 64 : tileb * T_ + tilet0;
        #pragma unroll
        for (int s = 0; s < 4; ++s) {
            const int col = n0 + s * 16 + (l & 15);
            const float bv = bias[col];
            #pragma unroll
            for (int reg = 0; reg < 4; ++reg) {
                const int m = mbase + q * 16 + (l >> 4) * 4 + reg;
                Cb[(size_t)m * (size_t)N + col] = f2bu(accs[s][reg] + bv);
            }
        }
    } else {
        #pragma unroll
        for (int s = 0; s < 4; ++s) {
            const int col = n0 + s * 16 + (l & 15);
            const float bv = bias[col];
            float mx = 0.f;
            #pragma unroll
            for (int reg = 0; reg < 4; ++reg) {
                const int t = tilet0 + q * 16 + (l >> 4) * 4 + reg;
                const float val = fmaxf(accs[s][reg] + bv, 0.f);
                if (t < rowsPerB) mx = fmaxf(mx, val);
            }
            mx = fmaxf(mx, __shfl_xor(mx, 16));
            mx = fmaxf(mx, __shfl_xor(mx, 32));
            if (l < 16)
                atomicMax(&pool[(size_t)tileb * (3*NF_) + poolOff + n0 + s*16 + l],
                          __float_as_uint(mx));
        }
    }
}

// =====================================================================
// Weight f32 -> bf16 prep.
// =====================================================================
__global__ void wprep_k(const float* __restrict__ W, unsigned short* __restrict__ o, int n)
{
    int i = blockIdx.x * 256 + threadIdx.x;
    if (i < n) o[i] = f2bu(W[i]);
}

// =====================================================================
// Selector GRU (round-6 proven structure + two latency fixes):
// 64 WGs x 512 thr (8 waves); wave w = unit i = bx*8+w; lane = batch b.
// Weights LDS-resident (wave-uniform float4 broadcast reads). h ping-pong
// f32 [k][b] via coherent loads/stores; flag barrier.
// FIX 1 (r8): gi(t+1) prefetch issued AFTER bar_arrive's flag store —
//   round-6 issued it before the vmcnt(0) drain, putting the scattered
//   gi gather latency inside the barrier on every step.
// FIX 2 (r8): sel bits collected per-step via __ballot into LDS; selp
//   written once after the loop (removes WG0's per-step scattered-store
//   burst from the barrier drain).
// FP sequence bit-identical to round 6.
// =====================================================================
template<bool GATES, bool DOT>
__device__ __forceinline__ void sel_chunk(
    const float* __restrict__ hs, int b,
    const float* __restrict__ wR, const float* __restrict__ wZ,
    const float* __restrict__ wN, const float* __restrict__ dWl, int cb,
    float& aR, float& aZ, float& aN, float& dot)
{
    #pragma unroll 4
    for (int kq = 0; kq < 64; ++kq) {
        const float hv0 = hs[(kq*4+0)*64 + b];
        const float hv1 = hs[(kq*4+1)*64 + b];
        const float hv2 = hs[(kq*4+2)*64 + b];
        const float hv3 = hs[(kq*4+3)*64 + b];
        if (GATES) {
            const float4 wr = *(const float4*)(wR + cb + kq*4);
            const float4 wz = *(const float4*)(wZ + cb + kq*4);
            const float4 wn = *(const float4*)(wN + cb + kq*4);
            aR = fmaf(hv0, wr.x, aR); aR = fmaf(hv1, wr.y, aR);
            aR = fmaf(hv2, wr.z, aR); aR = fmaf(hv3, wr.w, aR);
            aZ = fmaf(hv0, wz.x, aZ); aZ = fmaf(hv1, wz.y, aZ);
            aZ = fmaf(hv2, wz.z, aZ); aZ = fmaf(hv3, wz.w, aZ);
            aN = fmaf(hv0, wn.x, aN); aN = fmaf(hv1, wn.y, aN);
            aN = fmaf(hv2, wn.z, aN); aN = fmaf(hv3, wn.w, aN);
        }
        if (DOT) {
            const float4 dv = *(const float4*)(dWl + cb + kq*4);
            dot = fmaf(hv0, dv.x, dot); dot = fmaf(hv1, dv.y, dot);
            dot = fmaf(hv2, dv.z, dot); dot = fmaf(hv3, dv.w, dot);
        }
    }
}

__global__ __launch_bounds__(512) void rec_sel(
    const float* __restrict__ giF,
    const float* __restrict__ Whh, const float* __restrict__ bhh,
    const float* __restrict__ Ws, const float* __restrict__ bs,
    float* __restrict__ h0, float* __restrict__ h1,
    int* __restrict__ selp, int* __restrict__ flags)
{
    __shared__ float Wl[24 * 512];              // 48KB
    __shared__ float dWl[512];                  // 2KB
    __shared__ float hs[256 * 64];              // 64KB chunk, [k-local][b]
    __shared__ unsigned long long selmask[T_];  // 4KB (used by WG0)

    const int tid = threadIdx.x;
    const int b = tid & 63;
    const int w = __builtin_amdgcn_readfirstlane(tid >> 6);
    const int bx = blockIdx.x;
    const int i = bx * 8 + w;

    for (int idx = tid; idx < 24 * 512; idx += 512) {
        int rr = idx >> 9, k = idx & 511;
        int ul = rr / 3, gate = rr - ul * 3;
        Wl[idx] = Whh[((size_t)gate * 512 + bx * 8 + ul) * 512 + k];
    }
    dWl[tid] = Ws[512 + tid] - Ws[tid];
    __syncthreads();

    const float bR = bhh[i], bZ = bhh[512 + i], bN = bhh[1024 + i];
    const float db = bs[1] - bs[0];
    const float* __restrict__ wR = Wl + (w*3 + 0) * 512;
    const float* __restrict__ wZ = Wl + (w*3 + 1) * 512;
    const float* __restrict__ wN = Wl + (w*3 + 2) * 512;
    const int hchunk = i >> 8;

    // gi(t=0) prefetch
    float pgR = giF[(size_t)b * T_ * G_ + i];
    float pgZ = giF[(size_t)b * T_ * G_ + 512 + i];
    float pgN = giF[(size_t)b * T_ * G_ + 1024 + i];

    for (int t = 0; t <= T_; ++t) {
        const bool comp = (t < T_);
        const float* hcur = (t & 1) ? h1 : h0;
        float* hnxt = (t & 1) ? h0 : h1;

        if (t > 0) bar_wait<64>(flags, t, tid);

        const float* hc = hcur + (size_t)tid * 4;
        float* hd = hs + tid * 4;
        float4 a0,a1,a2,a3,a4,a5,a6,a7;
        // ---- chunk 0: load + land ----
        CLOAD4(a0, hc + 0*2048); CLOAD4(a1, hc + 1*2048);
        CLOAD4(a2, hc + 2*2048); CLOAD4(a3, hc + 3*2048);
        CLOAD4(a4, hc + 4*2048); CLOAD4(a5, hc + 5*2048);
        CLOAD4(a6, hc + 6*2048); CLOAD4(a7, hc + 7*2048);
        CWAIT();
        *(float4*)(hd + 0*2048) = a0; *(float4*)(hd + 1*2048) = a1;
        *(float4*)(hd + 2*2048) = a2; *(float4*)(hd + 3*2048) = a3;
        *(float4*)(hd + 4*2048) = a4; *(float4*)(hd + 5*2048) = a5;
        *(float4*)(hd + 6*2048) = a6; *(float4*)(hd + 7*2048) = a7;
        __syncthreads();
        // ---- issue chunk 1 loads (fly during chunk-0 compute) ----
        CLOAD4(a0, hc +  8*2048); CLOAD4(a1, hc +  9*2048);
        CLOAD4(a2, hc + 10*2048); CLOAD4(a3, hc + 11*2048);
        CLOAD4(a4, hc + 12*2048); CLOAD4(a5, hc + 13*2048);
        CLOAD4(a6, hc + 14*2048); CLOAD4(a7, hc + 15*2048);

        float aR = bR, aZ = bZ, aN = bN, dot = 0.f, hp = 0.f;
        if (comp) {
            if (w == 0) sel_chunk<true,true >(hs, b, wR, wZ, wN, dWl, 0, aR, aZ, aN, dot);
            else        sel_chunk<true,false>(hs, b, wR, wZ, wN, dWl, 0, aR, aZ, aN, dot);
            if (hchunk == 0) hp = hs[(i & 255)*64 + b];
        } else if (w == 0) {
            sel_chunk<false,true>(hs, b, wR, wZ, wN, dWl, 0, aR, aZ, aN, dot);
        }
        __syncthreads();            // everyone done reading chunk 0
        CWAIT();
        *(float4*)(hd + 0*2048) = a0; *(float4*)(hd + 1*2048) = a1;
        *(float4*)(hd + 2*2048) = a2; *(float4*)(hd + 3*2048) = a3;
        *(float4*)(hd + 4*2048) = a4; *(float4*)(hd + 5*2048) = a5;
        *(float4*)(hd + 6*2048) = a6; *(float4*)(hd + 7*2048) = a7;
        __syncthreads();
        if (comp) {
            if (w == 0) sel_chunk<true,true >(hs, b, wR, wZ, wN, dWl, 256, aR, aZ, aN, dot);
            else        sel_chunk<true,false>(hs, b, wR, wZ, wN, dWl, 256, aR, aZ, aN, dot);
            if (hchunk == 1) hp = hs[(i & 255)*64 + b];
        } else if (w == 0) {
            sel_chunk<false,true>(hs, b, wR, wZ, wN, dWl, 256, aR, aZ, aN, dot);
        }

        if (comp) {
            const float r = sigm(pgR + aR);
            const float z = sigm(pgZ + aZ);
            const float n = tanhf(pgN + r * aN);
            const float hn = (1.f - z) * n + z * hp;
            const float* hdst = hnxt + (size_t)i * 64 + b;   // coalesced
            CSTORE4(hdst, hn);
        }
        // sel bit for index t-1 (from staged h(t)): ballot on wave 0
        if (w == 0 && t >= 1) {
            unsigned long long m = __ballot((dot + db) > 0.f);
            if (tid == 0) selmask[t - 1] = m;
        }

        if (t < T_) {
            bar_arrive(flags, t, tid, bx);
            // FIX 1: prefetch gi(t+1) AFTER the flag store — latency
            // overlaps the next bar_wait spin + stage instead of sitting
            // inside the barrier's vmcnt(0) drain.
            if (t + 1 < T_) {
                const float* gp = giF + ((size_t)b * T_ + t + 1) * G_;
                pgR = gp[i]; pgZ = gp[512 + i]; pgN = gp[1024 + i];
            }
        }
    }

    // FIX 2: one coalesced selp write-out (WG0 only)
    __syncthreads();
    if (bx == 0) {
        for (int idx = tid; idx < B_ * T_; idx += 512) {
            const int b2 = idx >> 9, tt = idx & 511;
            selp[b2 * T_ + tt] = (int)((selmask[tt] >> b2) & 1ull);
        }
    }
}

// =====================================================================
// Layer GRU via MFMA (unchanged, verified round 6).
// =====================================================================
__global__ __launch_bounds__(256) void rec_mfma(
    const unsigned short* __restrict__ giB,
    const unsigned short* __restrict__ wbf,
    const float* __restrict__ bhh,
    const int* __restrict__ nselp, const int* __restrict__ maxnp,
    unsigned short* __restrict__ hA, unsigned short* __restrict__ hBp,
    float* __restrict__ outp, int* __restrict__ flags)
{
    __shared__ __align__(16) unsigned char ldsW[48 * 1040];
    __shared__ __align__(16) unsigned char ldsH[64 * 1040];
    __shared__ float gbuf[48 * 66];

    const int tid = threadIdx.x;
    const int l = tid & 63;
    const int q = tid >> 6;
    const int bx = blockIdx.x;
    const int i0 = bx * 16;
    const int b = tid & 63;

    for (int idx = tid; idx < 48 * 64; idx += 256) {
        const int r = idx >> 6, seg = idx & 63;
        const int tier = r >> 4, ul = r & 15;
        const float4 v = *(const float4*)((const char*)wbf
            + ((size_t)(tier * 512 + i0 + ul) * 512) * 2 + seg * 16);
        *(float4*)(ldsW + r * 1040 + seg * 16) = v;
    }
    const float4 bRv = *(const float4*)(bhh + i0 + 4 * q);
    const float4 bZv = *(const float4*)(bhh + 512 + i0 + 4 * q);
    const float4 bNv = *(const float4*)(bhh + 1024 + i0 + 4 * q);
    const int ns = nselp[b];
    const int TOTAL = *maxnp;
    __syncthreads();

    for (int t = 0; t < TOTAL; ++t) {
        const unsigned short* hcur = (t & 1) ? hBp : hA;
        unsigned short* hnxt = (t & 1) ? hA : hBp;

        if (t > 0) bar_wait<32>(flags, t, tid);

        const unsigned short* gp = giB + ((size_t)b * T_ + t) * (size_t)G_ + i0 + 4 * q;
        const uint2 gR = *(const uint2*)gp;
        const uint2 gZ = *(const uint2*)(gp + 512);
        const uint2 gN = *(const uint2*)(gp + 1024);

        {
            const char* src = (const char*)hcur + tid * 256;
            float4 s0, s1, s2, s3, s4, s5, s6, s7, s8, s9, sa, sb_, sc, sd, se, sf;
            CLOAD4(s0, src + 0 * 16);  CLOAD4(s1, src + 1 * 16);
            CLOAD4(s2, src + 2 * 16);  CLOAD4(s3, src + 3 * 16);
            CLOAD4(s4, src + 4 * 16);  CLOAD4(s5, src + 5 * 16);
            CLOAD4(s6, src + 6 * 16);  CLOAD4(s7, src + 7 * 16);
            CLOAD4(s8, src + 8 * 16);  CLOAD4(s9, src + 9 * 16);
            CLOAD4(sa, src + 10 * 16); CLOAD4(sb_, src + 11 * 16);
            CLOAD4(sc, src + 12 * 16); CLOAD4(sd, src + 13 * 16);
            CLOAD4(se, src + 14 * 16); CLOAD4(sf, src + 15 * 16);
            CWAIT();
            char* dst = (char*)ldsH + (tid >> 2) * 1040 + (tid & 3) * 256;
            *(float4*)(dst + 0 * 16) = s0;  *(float4*)(dst + 1 * 16) = s1;
            *(float4*)(dst + 2 * 16) = s2;  *(float4*)(dst + 3 * 16) = s3;
            *(float4*)(dst + 4 * 16) = s4;  *(float4*)(dst + 5 * 16) = s5;
            *(float4*)(dst + 6 * 16) = s6;  *(float4*)(dst + 7 * 16) = s7;
            *(float4*)(dst + 8 * 16) = s8;  *(float4*)(dst + 9 * 16) = s9;
            *(float4*)(dst + 10 * 16) = sa; *(float4*)(dst + 11 * 16) = sb_;
            *(float4*)(dst + 12 * 16) = sc; *(float4*)(dst + 13 * 16) = sd;
            *(float4*)(dst + 14 * 16) = se; *(float4*)(dst + 15 * 16) = sf;
        }
        __syncthreads();

        f32x4 ac0 = {0.f, 0.f, 0.f, 0.f};
        f32x4 ac1 = {0.f, 0.f, 0.f, 0.f};
        f32x4 ac2 = {0.f, 0.f, 0.f, 0.f};
        {
            const char* ab = (const char*)ldsH + (q * 16 + (l & 15)) * 1040 + (l >> 4) * 16;
            const char* bb = (const char*)ldsW + (l & 15) * 1040 + (l >> 4) * 16;
            #pragma unroll
            for (int ks = 0; ks < 16; ++ks) {
                const bf16x8 av = *(const bf16x8*)(ab + ks * 64);
                const bf16x8 w0 = *(const bf16x8*)(bb + ks * 64);
                const bf16x8 w1 = *(const bf16x8*)(bb + 16 * 1040 + ks * 64);
                const bf16x8 w2 = *(const bf16x8*)(bb + 32 * 1040 + ks * 64);
                ac0 = __builtin_amdgcn_mfma_f32_16x16x32_bf16(av, w0, ac0, 0, 0, 0);
                ac1 = __builtin_amdgcn_mfma_f32_16x16x32_bf16(av, w1, ac1, 0, 0, 0);
                ac2 = __builtin_amdgcn_mfma_f32_16x16x32_bf16(av, w2, ac2, 0, 0, 0);
            }
        }
        {
            const int gcol = q * 16 + 4 * (l >> 4);
            const int grow = l & 15;
            #pragma unroll
            for (int r = 0; r < 4; ++r) {
                gbuf[grow * 66 + gcol + r]        = ac0[r];
                gbuf[(16 + grow) * 66 + gcol + r] = ac1[r];
                gbuf[(32 + grow) * 66 + gcol + r] = ac2[r];
            }
        }
        __syncthreads();

        {
            const ushort4 hp4 = *(const ushort4*)((const char*)ldsH
                                 + b * 1040 + (i0 + 4 * q) * 2);
            const unsigned short hpb[4] = {hp4.x, hp4.y, hp4.z, hp4.w};
            const float irv[4] = {b2f(gR.x & 0xffff), b2f(gR.x >> 16),
                                  b2f(gR.y & 0xffff), b2f(gR.y >> 16)};
            const float izv[4] = {b2f(gZ.x & 0xffff), b2f(gZ.x >> 16),
                                  b2f(gZ.y & 0xffff), b2f(gZ.y >> 16)};
            const float inv[4] = {b2f(gN.x & 0xffff), b2f(gN.x >> 16),
                                  b2f(gN.y & 0xffff), b2f(gN.y >> 16)};
            float4 o;
            unsigned short ob[4];
            #pragma unroll
            for (int j = 0; j < 4; ++j) {
                const int u = 4 * q + j;
                const float hr = gbuf[u * 66 + b]        + bRv[j];
                const float hz = gbuf[(16 + u) * 66 + b] + bZv[j];
                const float hn = gbuf[(32 + u) * 66 + b] + bNv[j];
                const float rr = sigm(irv[j] + hr);
                const float zz = sigm(izv[j] + hz);
                const float nn = tanhf(inv[j] + rr * hn);
                const float hpf = b2f(hpb[j]);
                float hv = (1.f - zz) * nn + zz * hpf;
                if (t >= ns) hv = hpf;
                ((float*)&o)[j] = hv;
                ob[j] = f2bu(hv);
            }
            if (t < ns)
                *(float4*)(outp + ((size_t)b * T_ + t) * 512 + i0 + 4 * q) = o;
            uint2 hpk;
            hpk.x = (unsigned)ob[0] | ((unsigned)ob[1] << 16);
            hpk.y = (unsigned)ob[2] | ((unsigned)ob[3] << 16);
            const unsigned short* hdst = hnxt + (size_t)b * 512 + i0 + 4 * q;
            CSTORE8(hdst, hpk);
        }

        if (t + 1 < TOTAL) bar_arrive(flags, t, tid, bx);
    }
}

// =====================================================================
// Per-batch selection post-processing (unchanged).
// =====================================================================
__global__ void build_order_k(const int* __restrict__ mask, const int* __restrict__ sel,
                              int* __restrict__ order, int* __restrict__ nsel,
                              int* __restrict__ maxn)
{
    const int b = threadIdx.x;
    int lens = 0;
    for (int t = 0; t < T_; ++t) lens += (mask[b * T_ + t] != 0);
    int cnt = 0;
    for (int t = 0; t < T_; ++t) {
        int s = sel[b * T_ + t];
        if (t == 0) s = 1;
        if (t == lens - 1) s = 1;
        if (t >= lens) s = 0;
        if (s) order[b * T_ + (cnt++)] = t;
    }
    nsel[b] = cnt;
    int c2 = cnt;
    for (int t = 0; t < T_; ++t) {
        int s = sel[b * T_ + t];
        if (t == 0) s = 1;
        if (t == lens - 1) s = 1;
        if (t >= lens) s = 0;
        if (!s) order[b * T_ + (c2++)] = t;
    }
    __shared__ int red[64];
    red[b] = cnt;
    __syncthreads();
    if (b == 0) {
        int m = 0;
        for (int qq = 0; qq < 64; ++qq) m = max(m, red[qq]);
        *maxn = m;
    }
}

// =====================================================================
// Final linear (unchanged).
// =====================================================================
__global__ void final_k(const unsigned int* __restrict__ pool,
                        const float* __restrict__ Wo, const float* __restrict__ bo,
                        float* __restrict__ out)
{
    const int b = threadIdx.x;
    float s = bo[0];
    for (int f = 0; f < 3 * NF_; ++f)
        s = fmaf(__uint_as_float(pool[b * (3*NF_) + f]), Wo[f], s);
    out[b] = s;
}

// =====================================================================
extern "C" void kernel_launch(void* const* d_in, const int* in_sizes, int n_in,
                              void* d_out, int out_size, void* d_ws, size_t ws_size,
                              hipStream_t stream)
{
    (void)in_sizes; (void)n_in; (void)out_size;
    const float* emb   = (const float*)d_in[0];
    const int*   mask  = (const int*)d_in[1];
    const float* Wih_c = (const float*)d_in[2];
    const float* Whh_c = (const float*)d_in[3];
    const float* bih_c = (const float*)d_in[4];
    const float* bhh_c = (const float*)d_in[5];
    const float* Ws    = (const float*)d_in[6];
    const float* bs    = (const float*)d_in[7];
    const float* Wih0  = (const float*)d_in[8];
    const float* Whh0  = (const float*)d_in[9];
    const float* bih0  = (const float*)d_in[10];
    const float* bhh0  = (const float*)d_in[11];
    const float* Wih1  = (const float*)d_in[12];
    const float* Whh1  = (const float*)d_in[13];
    const float* bih1  = (const float*)d_in[14];
    const float* bhh1  = (const float*)d_in[15];
    const float* Wc3   = (const float*)d_in[16];
    const float* bc3   = (const float*)d_in[17];
    const float* Wc4   = (const float*)d_in[18];
    const float* bc4   = (const float*)d_in[19];
    const float* Wc5   = (const float*)d_in[20];
    const float* bc5   = (const float*)d_in[21];
    const float* Wo    = (const float*)d_in[22];
    const float* bo    = (const float*)d_in[23];

    if (ws_size < WS_NEED) return;
    char* ws = (char*)d_ws;
    float*          giC    = (float*)(ws + OFF_GI);
    unsigned short* giB    = (unsigned short*)(ws + OFF_GI);
    float*          outbuf = (float*)(ws + OFF_OUT);
    unsigned short* wbf0   = (unsigned short*)(ws + OFF_WBF0);
    unsigned short* wbf1   = (unsigned short*)(ws + OFF_WBF1);
    unsigned short* wih0b  = (unsigned short*)(ws + OFF_WIH0);
    unsigned short* wih1b  = (unsigned short*)(ws + OFF_WIH1);
    unsigned short* wc3b   = (unsigned short*)(ws + OFF_WC3);
    unsigned short* wc4b   = (unsigned short*)(ws + OFF_WC4);
    unsigned short* wc5b   = (unsigned short*)(ws + OFF_WC5);
    float*          h0     = (float*)(ws + OFF_H0);
    float*          h1     = (float*)(ws + OFF_H1);
    int*            sel    = (int*)(ws + OFF_SEL);
    int*            order  = (int*)(ws + OFF_ORD);
    int*            nsel   = (int*)(ws + OFF_NSEL);
    int*            maxn   = (int*)(ws + OFF_MAXN);
    int*            flags  = (int*)(ws + OFF_FLG);
    unsigned int*   pool   = (unsigned int*)(ws + OFF_POOL);

    // 1. gi_c = emb @ Wih_c^T + bih_c  (fp32 — argmax precision)
    gemm_f32<<<dim3(512, 24), 256, 0, stream>>>(emb, Wih_c, bih_c, giC, G_, E_, E_);
    // 2. selector recurrence -> sel
    hipMemsetAsync(flags, 0, 256, stream);
    hipMemsetAsync(h0, 0, (size_t)B_ * H_ * 4, stream);
    rec_sel<<<64, 512, 0, stream>>>(giC, Whh_c, bhh_c, Ws, bs, h0, h1, sel, flags);
    // 3. forcing + stable partition
    build_order_k<<<1, 64, 0, stream>>>(mask, sel, order, nsel, maxn);
    // 3b. bf16 weight prep — after rec_sel (region aliases gi_c tail).
    wprep_k<<<(G_*H_ + 255)/256, 256, 0, stream>>>(Whh0, wbf0, G_*H_);
    wprep_k<<<(G_*H_ + 255)/256, 256, 0, stream>>>(Whh1, wbf1, G_*H_);
    wprep_k<<<(G_*E_ + 255)/256, 256, 0, stream>>>(Wih0, wih0b, G_*E_);
    wprep_k<<<(G_*H_ + 255)/256, 256, 0, stream>>>(Wih1, wih1b, G_*H_);
    wprep_k<<<(NF_*3*H_ + 255)/256, 256, 0, stream>>>(Wc3, wc3b, NF_*3*H_);
    wprep_k<<<(NF_*4*H_ + 255)/256, 256, 0, stream>>>(Wc4, wc4b, NF_*4*H_);
    wprep_k<<<(NF_*5*H_ + 255)/256, 256, 0, stream>>>(Wc5, wc5b, NF_*5*H_);
    // 4. gi0 = new_emb @ Wih0^T + bih0 (gathered rows, bf16 MFMA)
    gemm_mfma<1,0><<<dim3(512, 24), 256, 0, stream>>>(emb, wih0b, bih0, giB, nullptr,
                                                      G_, E_, E_, T_, 8, order, nsel, 0);
    // 5. layer0 recurrence -> out0
    hipMemsetAsync(flags, 0, 256, stream);
    hipMemsetAsync(h0, 0, (size_t)B_ * H_ * 2, stream);
    hipMemsetAsync(outbuf, 0, (size_t)B_ * T_ * H_ * 4, stream);
    rec_mfma<<<32, 256, 0, stream>>>(giB, wbf0, bhh0, nsel, maxn,
                                     (unsigned short*)h0, (unsigned short*)h1, outbuf, flags);
    // 6. gi1 = out0 @ Wih1^T + bih1 (bf16 MFMA)
    gemm_mfma<0,0><<<dim3(512, 24), 256, 0, stream>>>(outbuf, wih1b, bih1, giB, nullptr,
                                                      G_, H_, H_, 0, 0, nullptr, nullptr, 0);
    // 7. layer1 recurrence -> out1
    hipMemsetAsync(flags, 0, 256, stream);
    hipMemsetAsync(h0, 0, (size_t)B_ * H_ * 2, stream);
    hipMemsetAsync(outbuf, 0, (size_t)B_ * T_ * H_ * 4, stream);
    rec_mfma<<<32, 256, 0, stream>>>(giB, wbf1, bhh1, nsel, maxn,
                                     (unsigned short*)h0, (unsigned short*)h1, outbuf, flags);
    // 8. convs (bf16 MFMA sliding-window) + relu + time-max pooling
    hipMemsetAsync(pool, 0, (size_t)B_ * 3 * NF_ * 4, stream);
    gemm_mfma<2,1><<<dim3(512, 4), 256, 0, stream>>>(outbuf, wc3b, bc3, nullptr, pool,
                                                     NF_, 3*H_, H_, 510, 8, nullptr, nullptr, 0);
    gemm_mfma<2,1><<<dim3(512, 4), 256, 0, stream>>>(outbuf, wc4b, bc4, nullptr, pool,
                                                     NF_, 4*H_, H_, 509, 8, nullptr, nullptr, 256);
    gemm_mfma<2,1><<<dim3(512, 4), 256, 0, stream>>>(outbuf, wc5b, bc5, nullptr, pool,
                                                     NF_, 5*H_, H_, 508, 8, nullptr, nullptr, 512);
    // 9. final linear -> d_out (64 f32)
    final_k<<<1, 64, 0, stream>>>(pool, Wo, bo, (float*)d_out);
}

// Round 9
// 13734.032 us; speedup vs baseline: 2.3304x; 1.1417x over previous
//
#include <hip/hip_runtime.h>
#include <hip/hip_bf16.h>
#include <cstddef>

// ---------------- problem constants ----------------
constexpr int B_ = 64, T_ = 512, E_ = 768, H_ = 512, G_ = 1536, NF_ = 256;

typedef float f32x4 __attribute__((ext_vector_type(4)));
typedef __bf16 bf16x8 __attribute__((ext_vector_type(8)));

// ---------------- workspace layout (bytes) ----------------
constexpr size_t SZ_GIC   = (size_t)B_ * T_ * G_ * 4;       // 192 MiB
constexpr size_t OFF_GI   = 0;                              // f32 gi_c / later bf16 gi
constexpr size_t OFF_OUT  = (size_t)B_ * T_ * G_ * 2;       // 96MiB: out f32 (64MiB)
// bf16 weight copies alias gi_c's tail -> wprep_k must run AFTER rec_sel.
constexpr size_t OFF_WBF0 = 170u * 1024 * 1024;
constexpr size_t OFF_WBF1 = OFF_WBF0 + (size_t)G_ * H_ * 2;
constexpr size_t OFF_WIH0 = OFF_WBF1 + (size_t)G_ * H_ * 2;
constexpr size_t OFF_WIH1 = OFF_WIH0 + (size_t)G_ * E_ * 2;
constexpr size_t OFF_WC3  = OFF_WIH1 + (size_t)G_ * H_ * 2;
constexpr size_t OFF_WC4  = OFF_WC3 + (size_t)NF_ * 3 * H_ * 2;
constexpr size_t OFF_WC5  = OFF_WC4 + (size_t)NF_ * 4 * H_ * 2;
constexpr size_t OFF_MISC = SZ_GIC;
constexpr size_t OFF_H0   = OFF_MISC;
constexpr size_t OFF_H1   = OFF_H0 + (size_t)B_ * H_ * 4;
constexpr size_t OFF_SEL  = OFF_H1 + (size_t)B_ * H_ * 4;
constexpr size_t OFF_ORD  = OFF_SEL + (size_t)B_ * T_ * 4;
constexpr size_t OFF_NSEL = OFF_ORD + (size_t)B_ * T_ * 4;
constexpr size_t OFF_MAXN = OFF_NSEL + 256;
constexpr size_t OFF_FLG  = OFF_MAXN + 256;                 // 128 ints (512 B)
constexpr size_t OFF_POOL = OFF_FLG + 512;
constexpr size_t WS_NEED  = OFF_POOL + (size_t)B_ * 3 * NF_ * 4;

// coherent (fabric-level, L1/L2-bypass) access helpers
#define CLOAD4(dst, ptr) \
    asm volatile("global_load_dwordx4 %0, %1, off sc0 sc1" : "=v"(dst) : "v"(ptr))
#define CWAIT() do { \
    asm volatile("s_waitcnt vmcnt(0)" ::: "memory"); \
    __builtin_amdgcn_sched_barrier(0); } while (0)
#define CSTORE4(ptr, val) \
    asm volatile("global_store_dword %0, %1, off sc0 sc1" :: "v"(ptr), "v"(val) : "memory")
#define CSTORE8(ptr, val) \
    asm volatile("global_store_dwordx2 %0, %1, off sc0 sc1" :: "v"(ptr), "v"(val) : "memory")

__device__ __forceinline__ float sigm(float x) { return 1.f / (1.f + expf(-x)); }
__device__ __forceinline__ float b2f(unsigned short u) {
    return __uint_as_float(((unsigned int)u) << 16);
}
__device__ __forceinline__ unsigned short f2bu(float x) {
    __hip_bfloat16 h = __float2bfloat16(x);
    return *(unsigned short*)&h;
}

template<int NWG>
__device__ __forceinline__ void bar_wait(const int* flags, int t, int tid) {
    if (tid < 64) {
        int v;
        for (;;) {
            asm volatile("global_load_dword %0, %1, off sc0 sc1\n\t"
                         "s_waitcnt vmcnt(0)"
                         : "=v"(v) : "v"(flags + (tid & (NWG - 1))) : "memory");
            if (__all(v >= t)) break;
            __builtin_amdgcn_s_sleep(1);
        }
    }
    __syncthreads();
}

// 128-WG variant: each of 64 lanes polls two flags.
__device__ __forceinline__ void bar_wait128(const int* flags, int t, int tid) {
    if (tid < 64) {
        int v1, v2;
        for (;;) {
            asm volatile("global_load_dword %0, %2, off sc0 sc1\n\t"
                         "global_load_dword %1, %3, off sc0 sc1\n\t"
                         "s_waitcnt vmcnt(0)"
                         : "=&v"(v1), "=&v"(v2)
                         : "v"(flags + tid), "v"(flags + tid + 64) : "memory");
            if (__all((v1 >= t) && (v2 >= t))) break;
            __builtin_amdgcn_s_sleep(1);
        }
    }
    __syncthreads();
}

__device__ __forceinline__ void bar_arrive(int* flags, int t, int tid, int bx) {
    asm volatile("s_waitcnt vmcnt(0)" ::: "memory");
    __syncthreads();
    if (tid == 0) { int pv = t + 1; CSTORE4(flags + bx, pv); }
}

// =====================================================================
// fp32 tiled GEMM — gi_c only (argmax precision). Stride 21.
// =====================================================================
__global__ __launch_bounds__(256) void gemm_f32(
    const float* __restrict__ A, const float* __restrict__ W,
    const float* __restrict__ bias, float* __restrict__ Cf,
    int N, int K, int ldA)
{
    __shared__ float As[64 * 21];
    __shared__ float Bs[64 * 21];
    const int tid = threadIdx.x;
    const int tx = tid & 15, ty = tid >> 4;
    const int bx = blockIdx.x;
    const int n0 = blockIdx.y * 64;

    float acc[4][4] = {};
    const int rl = tid >> 2, kl = (tid & 3) * 4;
    const float* __restrict__ ap = A + ((size_t)bx * 64 + rl) * (size_t)ldA + kl;
    const float* __restrict__ wrow = W + (size_t)(n0 + rl) * (size_t)K + kl;

    for (int k0 = 0; k0 < K; k0 += 16) {
        float4 av = *(const float4*)(ap + k0);
        float4 wv = *(const float4*)(wrow + k0);
        __syncthreads();
        As[rl*21+kl+0] = av.x; As[rl*21+kl+1] = av.y;
        As[rl*21+kl+2] = av.z; As[rl*21+kl+3] = av.w;
        Bs[rl*21+kl+0] = wv.x; Bs[rl*21+kl+1] = wv.y;
        Bs[rl*21+kl+2] = wv.z; Bs[rl*21+kl+3] = wv.w;
        __syncthreads();
        #pragma unroll
        for (int kk = 0; kk < 16; ++kk) {
            float a0 = As[(ty*4+0)*21+kk], a1 = As[(ty*4+1)*21+kk];
            float a2 = As[(ty*4+2)*21+kk], a3 = As[(ty*4+3)*21+kk];
            float w0 = Bs[(tx*4+0)*21+kk], w1 = Bs[(tx*4+1)*21+kk];
            float w2 = Bs[(tx*4+2)*21+kk], w3 = Bs[(tx*4+3)*21+kk];
            acc[0][0]=fmaf(a0,w0,acc[0][0]); acc[0][1]=fmaf(a0,w1,acc[0][1]);
            acc[0][2]=fmaf(a0,w2,acc[0][2]); acc[0][3]=fmaf(a0,w3,acc[0][3]);
            acc[1][0]=fmaf(a1,w0,acc[1][0]); acc[1][1]=fmaf(a1,w1,acc[1][1]);
            acc[1][2]=fmaf(a1,w2,acc[1][2]); acc[1][3]=fmaf(a1,w3,acc[1][3]);
            acc[2][0]=fmaf(a2,w0,acc[2][0]); acc[2][1]=fmaf(a2,w1,acc[2][1]);
            acc[2][2]=fmaf(a2,w2,acc[2][2]); acc[2][3]=fmaf(a2,w3,acc[2][3]);
            acc[3][0]=fmaf(a3,w0,acc[3][0]); acc[3][1]=fmaf(a3,w1,acc[3][1]);
            acc[3][2]=fmaf(a3,w2,acc[3][2]); acc[3][3]=fmaf(a3,w3,acc[3][3]);
        }
    }
    #pragma unroll
    for (int i = 0; i < 4; ++i) {
        int m = bx * 64 + ty*4 + i;
        size_t co = (size_t)m * (size_t)N + n0 + tx*4;
        #pragma unroll
        for (int j = 0; j < 4; ++j)
            Cf[co + j] = acc[i][j] + bias[n0 + tx*4 + j];
    }
}

// =====================================================================
// bf16 MFMA GEMM (unchanged, verified round 6).
// =====================================================================
template<int AMODE, int OMODE>
__global__ __launch_bounds__(256) void gemm_mfma(
    const float* __restrict__ A, const unsigned short* __restrict__ Wb,
    const float* __restrict__ bias,
    unsigned short* __restrict__ Cb, unsigned int* __restrict__ pool,
    int N, int K, int ldA, int rowsPerB, int tilesPerB,
    const int* __restrict__ order, const int* __restrict__ nsel, int poolOff)
{
    __shared__ __align__(16) unsigned short As[64][40];
    __shared__ __align__(16) unsigned short Bs[64][40];
    __shared__ const float* rowp[64];

    const int tid = threadIdx.x;
    const int l = tid & 63;
    const int q = tid >> 6;
    const int bx = blockIdx.x;
    const int n0 = blockIdx.y * 64;

    int tileb = 0, tilet0 = 0;
    if (AMODE != 0) { tileb = bx / tilesPerB; tilet0 = (bx % tilesPerB) * 64; }

    if (tid < 64) {
        const float* p = nullptr;
        if (AMODE == 0) {
            p = A + ((size_t)bx * 64 + tid) * (size_t)ldA;
        } else if (AMODE == 1) {
            int t = tilet0 + tid;
            if (t < nsel[tileb]) {
                int src = order[tileb * T_ + t];
                p = A + ((size_t)tileb * T_ + src) * (size_t)ldA;
            }
        } else {
            int t = tilet0 + tid;
            if (t < rowsPerB) p = A + ((size_t)tileb * T_ + t) * (size_t)ldA;
        }
        rowp[tid] = p;
    }
    __syncthreads();

    f32x4 acc0 = {0.f,0.f,0.f,0.f}, acc1 = {0.f,0.f,0.f,0.f};
    f32x4 acc2 = {0.f,0.f,0.f,0.f}, acc3 = {0.f,0.f,0.f,0.f};

    const int r = tid & 63, seg = tid >> 6;
    const float* ap = rowp[r];
    if (ap) ap += seg * 8;
    const unsigned short* wrow = Wb + (size_t)(n0 + r) * (size_t)K + seg * 8;

    for (int k0 = 0; k0 < K; k0 += 32) {
        float4 fa = make_float4(0,0,0,0), fb = make_float4(0,0,0,0);
        if (ap) { fa = *(const float4*)(ap + k0); fb = *(const float4*)(ap + k0 + 4); }
        const uint4 wv = *(const uint4*)(wrow + k0);
        __syncthreads();
        uint4 pk;
        pk.x = (unsigned)f2bu(fa.x) | ((unsigned)f2bu(fa.y) << 16);
        pk.y = (unsigned)f2bu(fa.z) | ((unsigned)f2bu(fa.w) << 16);
        pk.z = (unsigned)f2bu(fb.x) | ((unsigned)f2bu(fb.y) << 16);
        pk.w = (unsigned)f2bu(fb.z) | ((unsigned)f2bu(fb.w) << 16);
        *(uint4*)&As[r][seg * 8] = pk;
        *(uint4*)&Bs[r][seg * 8] = wv;
        __syncthreads();
        const bf16x8 av = *(const bf16x8*)&As[q * 16 + (l & 15)][(l >> 4) * 8];
        const bf16x8 b0 = *(const bf16x8*)&Bs[ 0 + (l & 15)][(l >> 4) * 8];
        const bf16x8 b1 = *(const bf16x8*)&Bs[16 + (l & 15)][(l >> 4) * 8];
        const bf16x8 b2 = *(const bf16x8*)&Bs[32 + (l & 15)][(l >> 4) * 8];
        const bf16x8 b3 = *(const bf16x8*)&Bs[48 + (l & 15)][(l >> 4) * 8];
        acc0 = __builtin_amdgcn_mfma_f32_16x16x32_bf16(av, b0, acc0, 0, 0, 0);
        acc1 = __builtin_amdgcn_mfma_f32_16x16x32_bf16(av, b1, acc1, 0, 0, 0);
        acc2 = __builtin_amdgcn_mfma_f32_16x16x32_bf16(av, b2, acc2, 0, 0, 0);
        acc3 = __builtin_amdgcn_mfma_f32_16x16x32_bf16(av, b3, acc3, 0, 0, 0);
    }

    f32x4 accs[4] = {acc0, acc1, acc2, acc3};
    if (OMODE == 0) {
        const int mbase = (AMODE == 0) ? bx * 64 : tileb * T_ + tilet0;
        #pragma unroll
        for (int s = 0; s < 4; ++s) {
            const int col = n0 + s * 16 + (l & 15);
            const float bv = bias[col];
            #pragma unroll
            for (int reg = 0; reg < 4; ++reg) {
                const int m = mbase + q * 16 + (l >> 4) * 4 + reg;
                Cb[(size_t)m * (size_t)N + col] = f2bu(accs[s][reg] + bv);
            }
        }
    } else {
        #pragma unroll
        for (int s = 0; s < 4; ++s) {
            const int col = n0 + s * 16 + (l & 15);
            const float bv = bias[col];
            float mx = 0.f;
            #pragma unroll
            for (int reg = 0; reg < 4; ++reg) {
                const int t = tilet0 + q * 16 + (l >> 4) * 4 + reg;
                const float val = fmaxf(accs[s][reg] + bv, 0.f);
                if (t < rowsPerB) mx = fmaxf(mx, val);
            }
            mx = fmaxf(mx, __shfl_xor(mx, 16));
            mx = fmaxf(mx, __shfl_xor(mx, 32));
            if (l < 16)
                atomicMax(&pool[(size_t)tileb * (3*NF_) + poolOff + n0 + s*16 + l],
                          __float_as_uint(mx));
        }
    }
}

// =====================================================================
// Weight f32 -> bf16 prep.
// =====================================================================
__global__ void wprep_k(const float* __restrict__ W, unsigned short* __restrict__ o, int n)
{
    int i = blockIdx.x * 256 + threadIdx.x;
    if (i < n) o[i] = f2bu(W[i]);
}

// =====================================================================
// Selector GRU v6 — 128 WGs x 512 thr, k-split wave pairs.
// WG bx owns 4 units iu = bx*4 + u (u = wave>>1); wave s = wave&1 is the
// k-half: gate chains over k in [s*128, s*128+128) of each 256-k chunk
// (seeded with bias on s==0, 0 on s==1; combined s0 + s1 via LDS).
// Selector dot spread uniformly: wave w owns k in [64w, 64w+64); 8 LDS
// partials summed in fixed order by wave 0, ballot -> selmask.
// h ping-pong [k][b] + coherent staging + flag barrier: identical to
// the round-8 proven code (incl. FIX1 gi-prefetch-after-arrive and
// FIX2 deferred selp write-out).
// =====================================================================
__device__ __forceinline__ void gates_span(
    const float* __restrict__ hs, int b, int glo, int kbase,
    const float* __restrict__ wR, const float* __restrict__ wZ,
    const float* __restrict__ wN,
    float& aR, float& aZ, float& aN)
{
    #pragma unroll 4
    for (int kq = 0; kq < 32; ++kq) {
        const int kl = glo + kq * 4;
        const float hv0 = hs[(kl+0)*64 + b];
        const float hv1 = hs[(kl+1)*64 + b];
        const float hv2 = hs[(kl+2)*64 + b];
        const float hv3 = hs[(kl+3)*64 + b];
        const float4 wr = *(const float4*)(wR + kbase + kl);
        const float4 wz = *(const float4*)(wZ + kbase + kl);
        const float4 wn = *(const float4*)(wN + kbase + kl);
        aR = fmaf(hv0, wr.x, aR); aR = fmaf(hv1, wr.y, aR);
        aR = fmaf(hv2, wr.z, aR); aR = fmaf(hv3, wr.w, aR);
        aZ = fmaf(hv0, wz.x, aZ); aZ = fmaf(hv1, wz.y, aZ);
        aZ = fmaf(hv2, wz.z, aZ); aZ = fmaf(hv3, wz.w, aZ);
        aN = fmaf(hv0, wn.x, aN); aN = fmaf(hv1, wn.y, aN);
        aN = fmaf(hv2, wn.z, aN); aN = fmaf(hv3, wn.w, aN);
    }
}

__device__ __forceinline__ void dot_span(
    const float* __restrict__ hs, int b, int dlo, int kbase,
    const float* __restrict__ dWl, float& dot)
{
    #pragma unroll 4
    for (int kq = 0; kq < 16; ++kq) {
        const int kl = dlo + kq * 4;
        const float hv0 = hs[(kl+0)*64 + b];
        const float hv1 = hs[(kl+1)*64 + b];
        const float hv2 = hs[(kl+2)*64 + b];
        const float hv3 = hs[(kl+3)*64 + b];
        const float4 dv = *(const float4*)(dWl + kbase + kl);
        dot = fmaf(hv0, dv.x, dot); dot = fmaf(hv1, dv.y, dot);
        dot = fmaf(hv2, dv.z, dot); dot = fmaf(hv3, dv.w, dot);
    }
}

__global__ __launch_bounds__(512) void rec_sel(
    const float* __restrict__ giF,
    const float* __restrict__ Whh, const float* __restrict__ bhh,
    const float* __restrict__ Ws, const float* __restrict__ bs,
    float* __restrict__ h0, float* __restrict__ h1,
    int* __restrict__ selp, int* __restrict__ flags)
{
    __shared__ float Wl[12 * 512];              // 24KB: rows u*3+gate
    __shared__ float dWl[512];                  // 2KB
    __shared__ float hs[256 * 64];              // 64KB chunk, [k-local][b]
    __shared__ float partR[4 * 64], partZ[4 * 64], partN[4 * 64];   // 3KB
    __shared__ float pdot[8 * 64];              // 2KB
    __shared__ unsigned long long selmask[T_];  // 4KB (used by WG0)

    const int tid = threadIdx.x;
    const int b = tid & 63;
    const int w = __builtin_amdgcn_readfirstlane(tid >> 6);
    const int u = w >> 1, s = w & 1;
    const int bx = blockIdx.x;
    const int iu = bx * 4 + u;

    for (int idx = tid; idx < 12 * 512; idx += 512) {
        int rr = idx >> 9, k = idx & 511;
        int ul = rr / 3, gate = rr - ul * 3;
        Wl[idx] = Whh[((size_t)gate * 512 + bx * 4 + ul) * 512 + k];
    }
    dWl[tid] = Ws[512 + tid] - Ws[tid];
    __syncthreads();

    const float bR = bhh[iu], bZ = bhh[512 + iu], bN = bhh[1024 + iu];
    const float db = bs[1] - bs[0];
    const float* __restrict__ wR = Wl + (u*3 + 0) * 512;
    const float* __restrict__ wZ = Wl + (u*3 + 1) * 512;
    const float* __restrict__ wN = Wl + (u*3 + 2) * 512;
    const int hchunk = iu >> 8;        // which 256-k chunk holds unit iu

    // gi(t=0) prefetch (s==0 waves consume gi)
    float pgR = 0.f, pgZ = 0.f, pgN = 0.f;
    if (s == 0) {
        pgR = giF[(size_t)b * T_ * G_ + iu];
        pgZ = giF[(size_t)b * T_ * G_ + 512 + iu];
        pgN = giF[(size_t)b * T_ * G_ + 1024 + iu];
    }

    for (int t = 0; t <= T_; ++t) {
        const bool comp = (t < T_);
        const float* hcur = (t & 1) ? h1 : h0;
        float* hnxt = (t & 1) ? h0 : h1;

        if (t > 0) bar_wait128(flags, t, tid);

        const float* hc = hcur + (size_t)tid * 4;
        float* hd = hs + tid * 4;
        float4 a0,a1,a2,a3,a4,a5,a6,a7;
        // ---- chunk 0 (k 0..255): load + land ----
        CLOAD4(a0, hc + 0*2048); CLOAD4(a1, hc + 1*2048);
        CLOAD4(a2, hc + 2*2048); CLOAD4(a3, hc + 3*2048);
        CLOAD4(a4, hc + 4*2048); CLOAD4(a5, hc + 5*2048);
        CLOAD4(a6, hc + 6*2048); CLOAD4(a7, hc + 7*2048);
        CWAIT();
        *(float4*)(hd + 0*2048) = a0; *(float4*)(hd + 1*2048) = a1;
        *(float4*)(hd + 2*2048) = a2; *(float4*)(hd + 3*2048) = a3;
        *(float4*)(hd + 4*2048) = a4; *(float4*)(hd + 5*2048) = a5;
        *(float4*)(hd + 6*2048) = a6; *(float4*)(hd + 7*2048) = a7;
        __syncthreads();
        // ---- issue chunk 1 loads (fly during chunk-0 compute) ----
        CLOAD4(a0, hc +  8*2048); CLOAD4(a1, hc +  9*2048);
        CLOAD4(a2, hc + 10*2048); CLOAD4(a3, hc + 11*2048);
        CLOAD4(a4, hc + 12*2048); CLOAD4(a5, hc + 13*2048);
        CLOAD4(a6, hc + 14*2048); CLOAD4(a7, hc + 15*2048);

        float aR = (s == 0) ? bR : 0.f;
        float aZ = (s == 0) ? bZ : 0.f;
        float aN = (s == 0) ? bN : 0.f;
        float dot = 0.f, hp = 0.f;

        // chunk 0 compute
        if (comp) gates_span(hs, b, s * 128, 0, wR, wZ, wN, aR, aZ, aN);
        if (w < 4) dot_span(hs, b, w * 64, 0, dWl, dot);
        if (comp && s == 0 && hchunk == 0) hp = hs[(iu & 255)*64 + b];
        __syncthreads();            // everyone done reading chunk 0
        CWAIT();
        *(float4*)(hd + 0*2048) = a0; *(float4*)(hd + 1*2048) = a1;
        *(float4*)(hd + 2*2048) = a2; *(float4*)(hd + 3*2048) = a3;
        *(float4*)(hd + 4*2048) = a4; *(float4*)(hd + 5*2048) = a5;
        *(float4*)(hd + 6*2048) = a6; *(float4*)(hd + 7*2048) = a7;
        __syncthreads();
        // chunk 1 compute (k 256..511)
        if (comp) gates_span(hs, b, s * 128, 256, wR, wZ, wN, aR, aZ, aN);
        if (w >= 4) dot_span(hs, b, (w - 4) * 64, 256, dWl, dot);
        if (comp && s == 0 && hchunk == 1) hp = hs[(iu & 255)*64 + b];

        // exchange partials
        if (comp && s == 1) {
            partR[u*64 + b] = aR; partZ[u*64 + b] = aZ; partN[u*64 + b] = aN;
        }
        pdot[w*64 + b] = dot;
        __syncthreads();

        if (comp && s == 0) {
            aR += partR[u*64 + b]; aZ += partZ[u*64 + b]; aN += partN[u*64 + b];
            const float r = sigm(pgR + aR);
            const float z = sigm(pgZ + aZ);
            const float n = tanhf(pgN + r * aN);
            const float hn = (1.f - z) * n + z * hp;
            const float* hdst = hnxt + (size_t)iu * 64 + b;   // coalesced
            CSTORE4(hdst, hn);
        }
        if (w == 0 && t >= 1) {
            float p = pdot[0*64 + b];
            p += pdot[1*64 + b]; p += pdot[2*64 + b]; p += pdot[3*64 + b];
            p += pdot[4*64 + b]; p += pdot[5*64 + b]; p += pdot[6*64 + b];
            p += pdot[7*64 + b];
            unsigned long long m = __ballot((p + db) > 0.f);
            if (tid == 0) selmask[t - 1] = m;
        }

        if (t < T_) {
            bar_arrive(flags, t, tid, bx);
            // gi(t+1) prefetch AFTER the flag store (round-8 FIX 1)
            if (s == 0 && t + 1 < T_) {
                const float* gp = giF + ((size_t)b * T_ + t + 1) * G_;
                pgR = gp[iu]; pgZ = gp[512 + iu]; pgN = gp[1024 + iu];
            }
        }
    }

    // one coalesced selp write-out (WG0 only; round-8 FIX 2)
    __syncthreads();
    if (bx == 0) {
        for (int idx = tid; idx < B_ * T_; idx += 512) {
            const int b2 = idx >> 9, tt = idx & 511;
            selp[b2 * T_ + tt] = (int)((selmask[tt] >> b2) & 1ull);
        }
    }
}

// =====================================================================
// Layer GRU via MFMA (unchanged, verified round 6).
// =====================================================================
__global__ __launch_bounds__(256) void rec_mfma(
    const unsigned short* __restrict__ giB,
    const unsigned short* __restrict__ wbf,
    const float* __restrict__ bhh,
    const int* __restrict__ nselp, const int* __restrict__ maxnp,
    unsigned short* __restrict__ hA, unsigned short* __restrict__ hBp,
    float* __restrict__ outp, int* __restrict__ flags)
{
    __shared__ __align__(16) unsigned char ldsW[48 * 1040];
    __shared__ __align__(16) unsigned char ldsH[64 * 1040];
    __shared__ float gbuf[48 * 66];

    const int tid = threadIdx.x;
    const int l = tid & 63;
    const int q = tid >> 6;
    const int bx = blockIdx.x;
    const int i0 = bx * 16;
    const int b = tid & 63;

    for (int idx = tid; idx < 48 * 64; idx += 256) {
        const int r = idx >> 6, seg = idx & 63;
        const int tier = r >> 4, ul = r & 15;
        const float4 v = *(const float4*)((const char*)wbf
            + ((size_t)(tier * 512 + i0 + ul) * 512) * 2 + seg * 16);
        *(float4*)(ldsW + r * 1040 + seg * 16) = v;
    }
    const float4 bRv = *(const float4*)(bhh + i0 + 4 * q);
    const float4 bZv = *(const float4*)(bhh + 512 + i0 + 4 * q);
    const float4 bNv = *(const float4*)(bhh + 1024 + i0 + 4 * q);
    const int ns = nselp[b];
    const int TOTAL = *maxnp;
    __syncthreads();

    for (int t = 0; t < TOTAL; ++t) {
        const unsigned short* hcur = (t & 1) ? hBp : hA;
        unsigned short* hnxt = (t & 1) ? hA : hBp;

        if (t > 0) bar_wait<32>(flags, t, tid);

        const unsigned short* gp = giB + ((size_t)b * T_ + t) * (size_t)G_ + i0 + 4 * q;
        const uint2 gR = *(const uint2*)gp;
        const uint2 gZ = *(const uint2*)(gp + 512);
        const uint2 gN = *(const uint2*)(gp + 1024);

        {
            const char* src = (const char*)hcur + tid * 256;
            float4 s0, s1, s2, s3, s4, s5, s6, s7, s8, s9, sa, sb_, sc, sd, se, sf;
            CLOAD4(s0, src + 0 * 16);  CLOAD4(s1, src + 1 * 16);
            CLOAD4(s2, src + 2 * 16);  CLOAD4(s3, src + 3 * 16);
            CLOAD4(s4, src + 4 * 16);  CLOAD4(s5, src + 5 * 16);
            CLOAD4(s6, src + 6 * 16);  CLOAD4(s7, src + 7 * 16);
            CLOAD4(s8, src + 8 * 16);  CLOAD4(s9, src + 9 * 16);
            CLOAD4(sa, src + 10 * 16); CLOAD4(sb_, src + 11 * 16);
            CLOAD4(sc, src + 12 * 16); CLOAD4(sd, src + 13 * 16);
            CLOAD4(se, src + 14 * 16); CLOAD4(sf, src + 15 * 16);
            CWAIT();
            char* dst = (char*)ldsH + (tid >> 2) * 1040 + (tid & 3) * 256;
            *(float4*)(dst + 0 * 16) = s0;  *(float4*)(dst + 1 * 16) = s1;
            *(float4*)(dst + 2 * 16) = s2;  *(float4*)(dst + 3 * 16) = s3;
            *(float4*)(dst + 4 * 16) = s4;  *(float4*)(dst + 5 * 16) = s5;
            *(float4*)(dst + 6 * 16) = s6;  *(float4*)(dst + 7 * 16) = s7;
            *(float4*)(dst + 8 * 16) = s8;  *(float4*)(dst + 9 * 16) = s9;
            *(float4*)(dst + 10 * 16) = sa; *(float4*)(dst + 11 * 16) = sb_;
            *(float4*)(dst + 12 * 16) = sc; *(float4*)(dst + 13 * 16) = sd;
            *(float4*)(dst + 14 * 16) = se; *(float4*)(dst + 15 * 16) = sf;
        }
        __syncthreads();

        f32x4 ac0 = {0.f, 0.f, 0.f, 0.f};
        f32x4 ac1 = {0.f, 0.f, 0.f, 0.f};
        f32x4 ac2 = {0.f, 0.f, 0.f, 0.f};
        {
            const char* ab = (const char*)ldsH + (q * 16 + (l & 15)) * 1040 + (l >> 4) * 16;
            const char* bb = (const char*)ldsW + (l & 15) * 1040 + (l >> 4) * 16;
            #pragma unroll
            for (int ks = 0; ks < 16; ++ks) {
                const bf16x8 av = *(const bf16x8*)(ab + ks * 64);
                const bf16x8 w0 = *(const bf16x8*)(bb + ks * 64);
                const bf16x8 w1 = *(const bf16x8*)(bb + 16 * 1040 + ks * 64);
                const bf16x8 w2 = *(const bf16x8*)(bb + 32 * 1040 + ks * 64);
                ac0 = __builtin_amdgcn_mfma_f32_16x16x32_bf16(av, w0, ac0, 0, 0, 0);
                ac1 = __builtin_amdgcn_mfma_f32_16x16x32_bf16(av, w1, ac1, 0, 0, 0);
                ac2 = __builtin_amdgcn_mfma_f32_16x16x32_bf16(av, w2, ac2, 0, 0, 0);
            }
        }
        {
            const int gcol = q * 16 + 4 * (l >> 4);
            const int grow = l & 15;
            #pragma unroll
            for (int r = 0; r < 4; ++r) {
                gbuf[grow * 66 + gcol + r]        = ac0[r];
                gbuf[(16 + grow) * 66 + gcol + r] = ac1[r];
                gbuf[(32 + grow) * 66 + gcol + r] = ac2[r];
            }
        }
        __syncthreads();

        {
            const ushort4 hp4 = *(const ushort4*)((const char*)ldsH
                                 + b * 1040 + (i0 + 4 * q) * 2);
            const unsigned short hpb[4] = {hp4.x, hp4.y, hp4.z, hp4.w};
            const float irv[4] = {b2f(gR.x & 0xffff), b2f(gR.x >> 16),
                                  b2f(gR.y & 0xffff), b2f(gR.y >> 16)};
            const float izv[4] = {b2f(gZ.x & 0xffff), b2f(gZ.x >> 16),
                                  b2f(gZ.y & 0xffff), b2f(gZ.y >> 16)};
            const float inv[4] = {b2f(gN.x & 0xffff), b2f(gN.x >> 16),
                                  b2f(gN.y & 0xffff), b2f(gN.y >> 16)};
            float4 o;
            unsigned short ob[4];
            #pragma unroll
            for (int j = 0; j < 4; ++j) {
                const int u2 = 4 * q + j;
                const float hr = gbuf[u2 * 66 + b]        + bRv[j];
                const float hz = gbuf[(16 + u2) * 66 + b] + bZv[j];
                const float hn = gbuf[(32 + u2) * 66 + b] + bNv[j];
                const float rr = sigm(irv[j] + hr);
                const float zz = sigm(izv[j] + hz);
                const float nn = tanhf(inv[j] + rr * hn);
                const float hpf = b2f(hpb[j]);
                float hv = (1.f - zz) * nn + zz * hpf;
                if (t >= ns) hv = hpf;
                ((float*)&o)[j] = hv;
                ob[j] = f2bu(hv);
            }
            if (t < ns)
                *(float4*)(outp + ((size_t)b * T_ + t) * 512 + i0 + 4 * q) = o;
            uint2 hpk;
            hpk.x = (unsigned)ob[0] | ((unsigned)ob[1] << 16);
            hpk.y = (unsigned)ob[2] | ((unsigned)ob[3] << 16);
            const unsigned short* hdst = hnxt + (size_t)b * 512 + i0 + 4 * q;
            CSTORE8(hdst, hpk);
        }

        if (t + 1 < TOTAL) bar_arrive(flags, t, tid, bx);
    }
}

// =====================================================================
// Per-batch selection post-processing (unchanged).
// =====================================================================
__global__ void build_order_k(const int* __restrict__ mask, const int* __restrict__ sel,
                              int* __restrict__ order, int* __restrict__ nsel,
                              int* __restrict__ maxn)
{
    const int b = threadIdx.x;
    int lens = 0;
    for (int t = 0; t < T_; ++t) lens += (mask[b * T_ + t] != 0);
    int cnt = 0;
    for (int t = 0; t < T_; ++t) {
        int s = sel[b * T_ + t];
        if (t == 0) s = 1;
        if (t == lens - 1) s = 1;
        if (t >= lens) s = 0;
        if (s) order[b * T_ + (cnt++)] = t;
    }
    nsel[b] = cnt;
    int c2 = cnt;
    for (int t = 0; t < T_; ++t) {
        int s = sel[b * T_ + t];
        if (t == 0) s = 1;
        if (t == lens - 1) s = 1;
        if (t >= lens) s = 0;
        if (!s) order[b * T_ + (c2++)] = t;
    }
    __shared__ int red[64];
    red[b] = cnt;
    __syncthreads();
    if (b == 0) {
        int m = 0;
        for (int qq = 0; qq < 64; ++qq) m = max(m, red[qq]);
        *maxn = m;
    }
}

// =====================================================================
// Final linear (unchanged).
// =====================================================================
__global__ void final_k(const unsigned int* __restrict__ pool,
                        const float* __restrict__ Wo, const float* __restrict__ bo,
                        float* __restrict__ out)
{
    const int b = threadIdx.x;
    float s = bo[0];
    for (int f = 0; f < 3 * NF_; ++f)
        s = fmaf(__uint_as_float(pool[b * (3*NF_) + f]), Wo[f], s);
    out[b] = s;
}

// =====================================================================
extern "C" void kernel_launch(void* const* d_in, const int* in_sizes, int n_in,
                              void* d_out, int out_size, void* d_ws, size_t ws_size,
                              hipStream_t stream)
{
    (void)in_sizes; (void)n_in; (void)out_size;
    const float* emb   = (const float*)d_in[0];
    const int*   mask  = (const int*)d_in[1];
    const float* Wih_c = (const float*)d_in[2];
    const float* Whh_c = (const float*)d_in[3];
    const float* bih_c = (const float*)d_in[4];
    const float* bhh_c = (const float*)d_in[5];
    const float* Ws    = (const float*)d_in[6];
    const float* bs    = (const float*)d_in[7];
    const float* Wih0  = (const float*)d_in[8];
    const float* Whh0  = (const float*)d_in[9];
    const float* bih0  = (const float*)d_in[10];
    const float* bhh0  = (const float*)d_in[11];
    const float* Wih1  = (const float*)d_in[12];
    const float* Whh1  = (const float*)d_in[13];
    const float* bih1  = (const float*)d_in[14];
    const float* bhh1  = (const float*)d_in[15];
    const float* Wc3   = (const float*)d_in[16];
    const float* bc3   = (const float*)d_in[17];
    const float* Wc4   = (const float*)d_in[18];
    const float* bc4   = (const float*)d_in[19];
    const float* Wc5   = (const float*)d_in[20];
    const float* bc5   = (const float*)d_in[21];
    const float* Wo    = (const float*)d_in[22];
    const float* bo    = (const float*)d_in[23];

    if (ws_size < WS_NEED) return;
    char* ws = (char*)d_ws;
    float*          giC    = (float*)(ws + OFF_GI);
    unsigned short* giB    = (unsigned short*)(ws + OFF_GI);
    float*          outbuf = (float*)(ws + OFF_OUT);
    unsigned short* wbf0   = (unsigned short*)(ws + OFF_WBF0);
    unsigned short* wbf1   = (unsigned short*)(ws + OFF_WBF1);
    unsigned short* wih0b  = (unsigned short*)(ws + OFF_WIH0);
    unsigned short* wih1b  = (unsigned short*)(ws + OFF_WIH1);
    unsigned short* wc3b   = (unsigned short*)(ws + OFF_WC3);
    unsigned short* wc4b   = (unsigned short*)(ws + OFF_WC4);
    unsigned short* wc5b   = (unsigned short*)(ws + OFF_WC5);
    float*          h0     = (float*)(ws + OFF_H0);
    float*          h1     = (float*)(ws + OFF_H1);
    int*            sel    = (int*)(ws + OFF_SEL);
    int*            order  = (int*)(ws + OFF_ORD);
    int*            nsel   = (int*)(ws + OFF_NSEL);
    int*            maxn   = (int*)(ws + OFF_MAXN);
    int*            flags  = (int*)(ws + OFF_FLG);
    unsigned int*   pool   = (unsigned int*)(ws + OFF_POOL);

    // 1. gi_c = emb @ Wih_c^T + bih_c  (fp32 — argmax precision)
    gemm_f32<<<dim3(512, 24), 256, 0, stream>>>(emb, Wih_c, bih_c, giC, G_, E_, E_);
    // 2. selector recurrence -> sel (128 WGs, k-split wave pairs)
    hipMemsetAsync(flags, 0, 512, stream);
    hipMemsetAsync(h0, 0, (size_t)B_ * H_ * 4, stream);
    rec_sel<<<128, 512, 0, stream>>>(giC, Whh_c, bhh_c, Ws, bs, h0, h1, sel, flags);
    // 3. forcing + stable partition
    build_order_k<<<1, 64, 0, stream>>>(mask, sel, order, nsel, maxn);
    // 3b. bf16 weight prep — after rec_sel (region aliases gi_c tail).
    wprep_k<<<(G_*H_ + 255)/256, 256, 0, stream>>>(Whh0, wbf0, G_*H_);
    wprep_k<<<(G_*H_ + 255)/256, 256, 0, stream>>>(Whh1, wbf1, G_*H_);
    wprep_k<<<(G_*E_ + 255)/256, 256, 0, stream>>>(Wih0, wih0b, G_*E_);
    wprep_k<<<(G_*H_ + 255)/256, 256, 0, stream>>>(Wih1, wih1b, G_*H_);
    wprep_k<<<(NF_*3*H_ + 255)/256, 256, 0, stream>>>(Wc3, wc3b, NF_*3*H_);
    wprep_k<<<(NF_*4*H_ + 255)/256, 256, 0, stream>>>(Wc4, wc4b, NF_*4*H_);
    wprep_k<<<(NF_*5*H_ + 255)/256, 256, 0, stream>>>(Wc5, wc5b, NF_*5*H_);
    // 4. gi0 = new_emb @ Wih0^T + bih0 (gathered rows, bf16 MFMA)
    gemm_mfma<1,0><<<dim3(512, 24), 256, 0, stream>>>(emb, wih0b, bih0, giB, nullptr,
                                                      G_, E_, E_, T_, 8, order, nsel, 0);
    // 5. layer0 recurrence -> out0
    hipMemsetAsync(flags, 0, 512, stream);
    hipMemsetAsync(h0, 0, (size_t)B_ * H_ * 2, stream);
    hipMemsetAsync(outbuf, 0, (size_t)B_ * T_ * H_ * 4, stream);
    rec_mfma<<<32, 256, 0, stream>>>(giB, wbf0, bhh0, nsel, maxn,
                                     (unsigned short*)h0, (unsigned short*)h1, outbuf, flags);
    // 6. gi1 = out0 @ Wih1^T + bih1 (bf16 MFMA)
    gemm_mfma<0,0><<<dim3(512, 24), 256, 0, stream>>>(outbuf, wih1b, bih1, giB, nullptr,
                                                      G_, H_, H_, 0, 0, nullptr, nullptr, 0);
    // 7. layer1 recurrence -> out1
    hipMemsetAsync(flags, 0, 512, stream);
    hipMemsetAsync(h0, 0, (size_t)B_ * H_ * 2, stream);
    hipMemsetAsync(outbuf, 0, (size_t)B_ * T_ * H_ * 4, stream);
    rec_mfma<<<32, 256, 0, stream>>>(giB, wbf1, bhh1, nsel, maxn,
                                     (unsigned short*)h0, (unsigned short*)h1, outbuf, flags);
    // 8. convs (bf16 MFMA sliding-window) + relu + time-max pooling
    hipMemsetAsync(pool, 0, (size_t)B_ * 3 * NF_ * 4, stream);
    gemm_mfma<2,1><<<dim3(512, 4), 256, 0, stream>>>(outbuf, wc3b, bc3, nullptr, pool,
                                                     NF_, 3*H_, H_, 510, 8, nullptr, nullptr, 0);
    gemm_mfma<2,1><<<dim3(512, 4), 256, 0, stream>>>(outbuf, wc4b, bc4, nullptr, pool,
                                                     NF_, 4*H_, H_, 509, 8, nullptr, nullptr, 256);
    gemm_mfma<2,1><<<dim3(512, 4), 256, 0, stream>>>(outbuf, wc5b, bc5, nullptr, pool,
                                                     NF_, 5*H_, H_, 508, 8, nullptr, nullptr, 512);
    // 9. final linear -> d_out (64 f32)
    final_k<<<1, 64, 0, stream>>>(pool, Wo, bo, (float*)d_out);
}

// Round 10
// 13202.751 us; speedup vs baseline: 2.4242x; 1.0402x over previous
//
#include <hip/hip_runtime.h>
#include <hip/hip_bf16.h>
#include <cstddef>

// ---------------- problem constants ----------------
constexpr int B_ = 64, T_ = 512, E_ = 768, H_ = 512, G_ = 1536, NF_ = 256;

typedef float f32x4 __attribute__((ext_vector_type(4)));
typedef __bf16 bf16x8 __attribute__((ext_vector_type(8)));

// ---------------- workspace layout (bytes) ----------------
constexpr size_t SZ_GIC   = (size_t)B_ * T_ * G_ * 4;       // 192 MiB
constexpr size_t OFF_GI   = 0;                              // f32 gi_c / later bf16 gi
constexpr size_t OFF_OUT  = (size_t)B_ * T_ * G_ * 2;       // 96MiB: out f32 (64MiB)
// bf16 weight copies alias gi_c's tail -> wprep_k must run AFTER rec_sel.
constexpr size_t OFF_WBF0 = 170u * 1024 * 1024;
constexpr size_t OFF_WBF1 = OFF_WBF0 + (size_t)G_ * H_ * 2;
constexpr size_t OFF_WIH0 = OFF_WBF1 + (size_t)G_ * H_ * 2;
constexpr size_t OFF_WIH1 = OFF_WIH0 + (size_t)G_ * E_ * 2;
constexpr size_t OFF_WC3  = OFF_WIH1 + (size_t)G_ * H_ * 2;
constexpr size_t OFF_WC4  = OFF_WC3 + (size_t)NF_ * 3 * H_ * 2;
constexpr size_t OFF_WC5  = OFF_WC4 + (size_t)NF_ * 4 * H_ * 2;
constexpr size_t OFF_MISC = SZ_GIC;
constexpr size_t OFF_H0   = OFF_MISC;
constexpr size_t OFF_H1   = OFF_H0 + (size_t)B_ * H_ * 4;
constexpr size_t OFF_SEL  = OFF_H1 + (size_t)B_ * H_ * 4;
constexpr size_t OFF_ORD  = OFF_SEL + (size_t)B_ * T_ * 4;
constexpr size_t OFF_NSEL = OFF_ORD + (size_t)B_ * T_ * 4;
constexpr size_t OFF_MAXN = OFF_NSEL + 256;
constexpr size_t OFF_FLG  = OFF_MAXN + 256;                 // 128 ints (512 B)
constexpr size_t OFF_POOL = OFF_FLG + 512;
constexpr size_t WS_NEED  = OFF_POOL + (size_t)B_ * 3 * NF_ * 4;

// coherent (fabric-level, L1/L2-bypass) access helpers
#define CLOAD4(dst, ptr) \
    asm volatile("global_load_dwordx4 %0, %1, off sc0 sc1" : "=v"(dst) : "v"(ptr))
#define CWAIT() do { \
    asm volatile("s_waitcnt vmcnt(0)" ::: "memory"); \
    __builtin_amdgcn_sched_barrier(0); } while (0)
#define CSTORE4(ptr, val) \
    asm volatile("global_store_dword %0, %1, off sc0 sc1" :: "v"(ptr), "v"(val) : "memory")
#define CSTORE8(ptr, val) \
    asm volatile("global_store_dwordx2 %0, %1, off sc0 sc1" :: "v"(ptr), "v"(val) : "memory")

__device__ __forceinline__ float sigm(float x) { return 1.f / (1.f + expf(-x)); }
__device__ __forceinline__ float b2f(unsigned short u) {
    return __uint_as_float(((unsigned int)u) << 16);
}
__device__ __forceinline__ unsigned short f2bu(float x) {
    __hip_bfloat16 h = __float2bfloat16(x);
    return *(unsigned short*)&h;
}

template<int NWG>
__device__ __forceinline__ void bar_wait(const int* flags, int t, int tid) {
    if (tid < 64) {
        int v;
        for (;;) {
            asm volatile("global_load_dword %0, %1, off sc0 sc1\n\t"
                         "s_waitcnt vmcnt(0)"
                         : "=v"(v) : "v"(flags + (tid & (NWG - 1))) : "memory");
            if (__all(v >= t)) break;
            __builtin_amdgcn_s_sleep(1);
        }
    }
    __syncthreads();
}

// 128-WG variant: each of 64 lanes polls two flags.
__device__ __forceinline__ void bar_wait128(const int* flags, int t, int tid) {
    if (tid < 64) {
        int v1, v2;
        for (;;) {
            asm volatile("global_load_dword %0, %2, off sc0 sc1\n\t"
                         "global_load_dword %1, %3, off sc0 sc1\n\t"
                         "s_waitcnt vmcnt(0)"
                         : "=&v"(v1), "=&v"(v2)
                         : "v"(flags + tid), "v"(flags + tid + 64) : "memory");
            if (__all((v1 >= t) && (v2 >= t))) break;
            __builtin_amdgcn_s_sleep(1);
        }
    }
    __syncthreads();
}

__device__ __forceinline__ void bar_arrive(int* flags, int t, int tid, int bx) {
    asm volatile("s_waitcnt vmcnt(0)" ::: "memory");
    __syncthreads();
    if (tid == 0) { int pv = t + 1; CSTORE4(flags + bx, pv); }
}

// =====================================================================
// fp32 tiled GEMM — gi_c only (argmax precision). Stride 21.
// r10: supertile-swizzled 1-D grid — 32 supertiles x (16 m x 24 n).
// Concurrent blocks share a 3.1MB A-panel + 4.5MB W (L2-resident),
// fixing the 12x HBM overfetch (FETCH 1.25GB) of the (512,24) grid.
// Per-output arithmetic identical (bit-exact gi_c).
// =====================================================================
__global__ __launch_bounds__(256) void gemm_f32(
    const float* __restrict__ A, const float* __restrict__ W,
    const float* __restrict__ bias, float* __restrict__ Cf,
    int N, int K, int ldA)
{
    __shared__ float As[64 * 21];
    __shared__ float Bs[64 * 21];
    const int tid = threadIdx.x;
    const int tx = tid & 15, ty = tid >> 4;
    const int id = blockIdx.x;
    const int sup = id / 384, rr = id % 384;   // 384 = 16 m-blocks x 24 n-blocks
    const int bx = sup * 16 + (rr & 15);
    const int n0 = (rr >> 4) * 64;

    float acc[4][4] = {};
    const int rl = tid >> 2, kl = (tid & 3) * 4;
    const float* __restrict__ ap = A + ((size_t)bx * 64 + rl) * (size_t)ldA + kl;
    const float* __restrict__ wrow = W + (size_t)(n0 + rl) * (size_t)K + kl;

    for (int k0 = 0; k0 < K; k0 += 16) {
        float4 av = *(const float4*)(ap + k0);
        float4 wv = *(const float4*)(wrow + k0);
        __syncthreads();
        As[rl*21+kl+0] = av.x; As[rl*21+kl+1] = av.y;
        As[rl*21+kl+2] = av.z; As[rl*21+kl+3] = av.w;
        Bs[rl*21+kl+0] = wv.x; Bs[rl*21+kl+1] = wv.y;
        Bs[rl*21+kl+2] = wv.z; Bs[rl*21+kl+3] = wv.w;
        __syncthreads();
        #pragma unroll
        for (int kk = 0; kk < 16; ++kk) {
            float a0 = As[(ty*4+0)*21+kk], a1 = As[(ty*4+1)*21+kk];
            float a2 = As[(ty*4+2)*21+kk], a3 = As[(ty*4+3)*21+kk];
            float w0 = Bs[(tx*4+0)*21+kk], w1 = Bs[(tx*4+1)*21+kk];
            float w2 = Bs[(tx*4+2)*21+kk], w3 = Bs[(tx*4+3)*21+kk];
            acc[0][0]=fmaf(a0,w0,acc[0][0]); acc[0][1]=fmaf(a0,w1,acc[0][1]);
            acc[0][2]=fmaf(a0,w2,acc[0][2]); acc[0][3]=fmaf(a0,w3,acc[0][3]);
            acc[1][0]=fmaf(a1,w0,acc[1][0]); acc[1][1]=fmaf(a1,w1,acc[1][1]);
            acc[1][2]=fmaf(a1,w2,acc[1][2]); acc[1][3]=fmaf(a1,w3,acc[1][3]);
            acc[2][0]=fmaf(a2,w0,acc[2][0]); acc[2][1]=fmaf(a2,w1,acc[2][1]);
            acc[2][2]=fmaf(a2,w2,acc[2][2]); acc[2][3]=fmaf(a2,w3,acc[2][3]);
            acc[3][0]=fmaf(a3,w0,acc[3][0]); acc[3][1]=fmaf(a3,w1,acc[3][1]);
            acc[3][2]=fmaf(a3,w2,acc[3][2]); acc[3][3]=fmaf(a3,w3,acc[3][3]);
        }
    }
    #pragma unroll
    for (int i = 0; i < 4; ++i) {
        int m = bx * 64 + ty*4 + i;
        size_t co = (size_t)m * (size_t)N + n0 + tx*4;
        #pragma unroll
        for (int j = 0; j < 4; ++j)
            Cf[co + j] = acc[i][j] + bias[n0 + tx*4 + j];
    }
}

// =====================================================================
// bf16 MFMA GEMM (unchanged, verified round 6).
// =====================================================================
template<int AMODE, int OMODE>
__global__ __launch_bounds__(256) void gemm_mfma(
    const float* __restrict__ A, const unsigned short* __restrict__ Wb,
    const float* __restrict__ bias,
    unsigned short* __restrict__ Cb, unsigned int* __restrict__ pool,
    int N, int K, int ldA, int rowsPerB, int tilesPerB,
    const int* __restrict__ order, const int* __restrict__ nsel, int poolOff)
{
    __shared__ __align__(16) unsigned short As[64][40];
    __shared__ __align__(16) unsigned short Bs[64][40];
    __shared__ const float* rowp[64];

    const int tid = threadIdx.x;
    const int l = tid & 63;
    const int q = tid >> 6;
    const int bx = blockIdx.x;
    const int n0 = blockIdx.y * 64;

    int tileb = 0, tilet0 = 0;
    if (AMODE != 0) { tileb = bx / tilesPerB; tilet0 = (bx % tilesPerB) * 64; }

    if (tid < 64) {
        const float* p = nullptr;
        if (AMODE == 0) {
            p = A + ((size_t)bx * 64 + tid) * (size_t)ldA;
        } else if (AMODE == 1) {
            int t = tilet0 + tid;
            if (t < nsel[tileb]) {
                int src = order[tileb * T_ + t];
                p = A + ((size_t)tileb * T_ + src) * (size_t)ldA;
            }
        } else {
            int t = tilet0 + tid;
            if (t < rowsPerB) p = A + ((size_t)tileb * T_ + t) * (size_t)ldA;
        }
        rowp[tid] = p;
    }
    __syncthreads();

    f32x4 acc0 = {0.f,0.f,0.f,0.f}, acc1 = {0.f,0.f,0.f,0.f};
    f32x4 acc2 = {0.f,0.f,0.f,0.f}, acc3 = {0.f,0.f,0.f,0.f};

    const int r = tid & 63, seg = tid >> 6;
    const float* ap = rowp[r];
    if (ap) ap += seg * 8;
    const unsigned short* wrow = Wb + (size_t)(n0 + r) * (size_t)K + seg * 8;

    for (int k0 = 0; k0 < K; k0 += 32) {
        float4 fa = make_float4(0,0,0,0), fb = make_float4(0,0,0,0);
        if (ap) { fa = *(const float4*)(ap + k0); fb = *(const float4*)(ap + k0 + 4); }
        const uint4 wv = *(const uint4*)(wrow + k0);
        __syncthreads();
        uint4 pk;
        pk.x = (unsigned)f2bu(fa.x) | ((unsigned)f2bu(fa.y) << 16);
        pk.y = (unsigned)f2bu(fa.z) | ((unsigned)f2bu(fa.w) << 16);
        pk.z = (unsigned)f2bu(fb.x) | ((unsigned)f2bu(fb.y) << 16);
        pk.w = (unsigned)f2bu(fb.z) | ((unsigned)f2bu(fb.w) << 16);
        *(uint4*)&As[r][seg * 8] = pk;
        *(uint4*)&Bs[r][seg * 8] = wv;
        __syncthreads();
        const bf16x8 av = *(const bf16x8*)&As[q * 16 + (l & 15)][(l >> 4) * 8];
        const bf16x8 b0 = *(const bf16x8*)&Bs[ 0 + (l & 15)][(l >> 4) * 8];
        const bf16x8 b1 = *(const bf16x8*)&Bs[16 + (l & 15)][(l >> 4) * 8];
        const bf16x8 b2 = *(const bf16x8*)&Bs[32 + (l & 15)][(l >> 4) * 8];
        const bf16x8 b3 = *(const bf16x8*)&Bs[48 + (l & 15)][(l >> 4) * 8];
        acc0 = __builtin_amdgcn_mfma_f32_16x16x32_bf16(av, b0, acc0, 0, 0, 0);
        acc1 = __builtin_amdgcn_mfma_f32_16x16x32_bf16(av, b1, acc1, 0, 0, 0);
        acc2 = __builtin_amdgcn_mfma_f32_16x16x32_bf16(av, b2, acc2, 0, 0, 0);
        acc3 = __builtin_amdgcn_mfma_f32_16x16x32_bf16(av, b3, acc3, 0, 0, 0);
    }

    f32x4 accs[4] = {acc0, acc1, acc2, acc3};
    if (OMODE == 0) {
        const int mbase = (AMODE == 0) ? bx * 64 : tileb * T_ + tilet0;
        #pragma unroll
        for (int s = 0; s < 4; ++s) {
            const int col = n0 + s * 16 + (l & 15);
            const float bv = bias[col];
            #pragma unroll
            for (int reg = 0; reg < 4; ++reg) {
                const int m = mbase + q * 16 + (l >> 4) * 4 + reg;
                Cb[(size_t)m * (size_t)N + col] = f2bu(accs[s][reg] + bv);
            }
        }
    } else {
        #pragma unroll
        for (int s = 0; s < 4; ++s) {
            const int col = n0 + s * 16 + (l & 15);
            const float bv = bias[col];
            float mx = 0.f;
            #pragma unroll
            for (int reg = 0; reg < 4; ++reg) {
                const int t = tilet0 + q * 16 + (l >> 4) * 4 + reg;
                const float val = fmaxf(accs[s][reg] + bv, 0.f);
                if (t < rowsPerB) mx = fmaxf(mx, val);
            }
            mx = fmaxf(mx, __shfl_xor(mx, 16));
            mx = fmaxf(mx, __shfl_xor(mx, 32));
            if (l < 16)
                atomicMax(&pool[(size_t)tileb * (3*NF_) + poolOff + n0 + s*16 + l],
                          __float_as_uint(mx));
        }
    }
}

// =====================================================================
// Weight f32 -> bf16 prep.
// =====================================================================
__global__ void wprep_k(const float* __restrict__ W, unsigned short* __restrict__ o, int n)
{
    int i = blockIdx.x * 256 + threadIdx.x;
    if (i < n) o[i] = f2bu(W[i]);
}

// =====================================================================
// Selector GRU v6 (unchanged, verified round 9) — 128 WGs x 512 thr.
// =====================================================================
__device__ __forceinline__ void gates_span(
    const float* __restrict__ hs, int b, int glo, int kbase,
    const float* __restrict__ wR, const float* __restrict__ wZ,
    const float* __restrict__ wN,
    float& aR, float& aZ, float& aN)
{
    #pragma unroll 4
    for (int kq = 0; kq < 32; ++kq) {
        const int kl = glo + kq * 4;
        const float hv0 = hs[(kl+0)*64 + b];
        const float hv1 = hs[(kl+1)*64 + b];
        const float hv2 = hs[(kl+2)*64 + b];
        const float hv3 = hs[(kl+3)*64 + b];
        const float4 wr = *(const float4*)(wR + kbase + kl);
        const float4 wz = *(const float4*)(wZ + kbase + kl);
        const float4 wn = *(const float4*)(wN + kbase + kl);
        aR = fmaf(hv0, wr.x, aR); aR = fmaf(hv1, wr.y, aR);
        aR = fmaf(hv2, wr.z, aR); aR = fmaf(hv3, wr.w, aR);
        aZ = fmaf(hv0, wz.x, aZ); aZ = fmaf(hv1, wz.y, aZ);
        aZ = fmaf(hv2, wz.z, aZ); aZ = fmaf(hv3, wz.w, aZ);
        aN = fmaf(hv0, wn.x, aN); aN = fmaf(hv1, wn.y, aN);
        aN = fmaf(hv2, wn.z, aN); aN = fmaf(hv3, wn.w, aN);
    }
}

__device__ __forceinline__ void dot_span(
    const float* __restrict__ hs, int b, int dlo, int kbase,
    const float* __restrict__ dWl, float& dot)
{
    #pragma unroll 4
    for (int kq = 0; kq < 16; ++kq) {
        const int kl = dlo + kq * 4;
        const float hv0 = hs[(kl+0)*64 + b];
        const float hv1 = hs[(kl+1)*64 + b];
        const float hv2 = hs[(kl+2)*64 + b];
        const float hv3 = hs[(kl+3)*64 + b];
        const float4 dv = *(const float4*)(dWl + kbase + kl);
        dot = fmaf(hv0, dv.x, dot); dot = fmaf(hv1, dv.y, dot);
        dot = fmaf(hv2, dv.z, dot); dot = fmaf(hv3, dv.w, dot);
    }
}

__global__ __launch_bounds__(512) void rec_sel(
    const float* __restrict__ giF,
    const float* __restrict__ Whh, const float* __restrict__ bhh,
    const float* __restrict__ Ws, const float* __restrict__ bs,
    float* __restrict__ h0, float* __restrict__ h1,
    int* __restrict__ selp, int* __restrict__ flags)
{
    __shared__ float Wl[12 * 512];              // 24KB: rows u*3+gate
    __shared__ float dWl[512];                  // 2KB
    __shared__ float hs[256 * 64];              // 64KB chunk, [k-local][b]
    __shared__ float partR[4 * 64], partZ[4 * 64], partN[4 * 64];   // 3KB
    __shared__ float pdot[8 * 64];              // 2KB
    __shared__ unsigned long long selmask[T_];  // 4KB (used by WG0)

    const int tid = threadIdx.x;
    const int b = tid & 63;
    const int w = __builtin_amdgcn_readfirstlane(tid >> 6);
    const int u = w >> 1, s = w & 1;
    const int bx = blockIdx.x;
    const int iu = bx * 4 + u;

    for (int idx = tid; idx < 12 * 512; idx += 512) {
        int rr = idx >> 9, k = idx & 511;
        int ul = rr / 3, gate = rr - ul * 3;
        Wl[idx] = Whh[((size_t)gate * 512 + bx * 4 + ul) * 512 + k];
    }
    dWl[tid] = Ws[512 + tid] - Ws[tid];
    __syncthreads();

    const float bR = bhh[iu], bZ = bhh[512 + iu], bN = bhh[1024 + iu];
    const float db = bs[1] - bs[0];
    const float* __restrict__ wR = Wl + (u*3 + 0) * 512;
    const float* __restrict__ wZ = Wl + (u*3 + 1) * 512;
    const float* __restrict__ wN = Wl + (u*3 + 2) * 512;
    const int hchunk = iu >> 8;        // which 256-k chunk holds unit iu

    // gi(t=0) prefetch (s==0 waves consume gi)
    float pgR = 0.f, pgZ = 0.f, pgN = 0.f;
    if (s == 0) {
        pgR = giF[(size_t)b * T_ * G_ + iu];
        pgZ = giF[(size_t)b * T_ * G_ + 512 + iu];
        pgN = giF[(size_t)b * T_ * G_ + 1024 + iu];
    }

    for (int t = 0; t <= T_; ++t) {
        const bool comp = (t < T_);
        const float* hcur = (t & 1) ? h1 : h0;
        float* hnxt = (t & 1) ? h0 : h1;

        if (t > 0) bar_wait128(flags, t, tid);

        const float* hc = hcur + (size_t)tid * 4;
        float* hd = hs + tid * 4;
        float4 a0,a1,a2,a3,a4,a5,a6,a7;
        // ---- chunk 0 (k 0..255): load + land ----
        CLOAD4(a0, hc + 0*2048); CLOAD4(a1, hc + 1*2048);
        CLOAD4(a2, hc + 2*2048); CLOAD4(a3, hc + 3*2048);
        CLOAD4(a4, hc + 4*2048); CLOAD4(a5, hc + 5*2048);
        CLOAD4(a6, hc + 6*2048); CLOAD4(a7, hc + 7*2048);
        CWAIT();
        *(float4*)(hd + 0*2048) = a0; *(float4*)(hd + 1*2048) = a1;
        *(float4*)(hd + 2*2048) = a2; *(float4*)(hd + 3*2048) = a3;
        *(float4*)(hd + 4*2048) = a4; *(float4*)(hd + 5*2048) = a5;
        *(float4*)(hd + 6*2048) = a6; *(float4*)(hd + 7*2048) = a7;
        __syncthreads();
        // ---- issue chunk 1 loads (fly during chunk-0 compute) ----
        CLOAD4(a0, hc +  8*2048); CLOAD4(a1, hc +  9*2048);
        CLOAD4(a2, hc + 10*2048); CLOAD4(a3, hc + 11*2048);
        CLOAD4(a4, hc + 12*2048); CLOAD4(a5, hc + 13*2048);
        CLOAD4(a6, hc + 14*2048); CLOAD4(a7, hc + 15*2048);

        float aR = (s == 0) ? bR : 0.f;
        float aZ = (s == 0) ? bZ : 0.f;
        float aN = (s == 0) ? bN : 0.f;
        float dot = 0.f, hp = 0.f;

        // chunk 0 compute
        if (comp) gates_span(hs, b, s * 128, 0, wR, wZ, wN, aR, aZ, aN);
        if (w < 4) dot_span(hs, b, w * 64, 0, dWl, dot);
        if (comp && s == 0 && hchunk == 0) hp = hs[(iu & 255)*64 + b];
        __syncthreads();            // everyone done reading chunk 0
        CWAIT();
        *(float4*)(hd + 0*2048) = a0; *(float4*)(hd + 1*2048) = a1;
        *(float4*)(hd + 2*2048) = a2; *(float4*)(hd + 3*2048) = a3;
        *(float4*)(hd + 4*2048) = a4; *(float4*)(hd + 5*2048) = a5;
        *(float4*)(hd + 6*2048) = a6; *(float4*)(hd + 7*2048) = a7;
        __syncthreads();
        // chunk 1 compute (k 256..511)
        if (comp) gates_span(hs, b, s * 128, 256, wR, wZ, wN, aR, aZ, aN);
        if (w >= 4) dot_span(hs, b, (w - 4) * 64, 256, dWl, dot);
        if (comp && s == 0 && hchunk == 1) hp = hs[(iu & 255)*64 + b];

        // exchange partials
        if (comp && s == 1) {
            partR[u*64 + b] = aR; partZ[u*64 + b] = aZ; partN[u*64 + b] = aN;
        }
        pdot[w*64 + b] = dot;
        __syncthreads();

        if (comp && s == 0) {
            aR += partR[u*64 + b]; aZ += partZ[u*64 + b]; aN += partN[u*64 + b];
            const float r = sigm(pgR + aR);
            const float z = sigm(pgZ + aZ);
            const float n = tanhf(pgN + r * aN);
            const float hn = (1.f - z) * n + z * hp;
            const float* hdst = hnxt + (size_t)iu * 64 + b;   // coalesced
            CSTORE4(hdst, hn);
        }
        if (w == 0 && t >= 1) {
            float p = pdot[0*64 + b];
            p += pdot[1*64 + b]; p += pdot[2*64 + b]; p += pdot[3*64 + b];
            p += pdot[4*64 + b]; p += pdot[5*64 + b]; p += pdot[6*64 + b];
            p += pdot[7*64 + b];
            unsigned long long m = __ballot((p + db) > 0.f);
            if (tid == 0) selmask[t - 1] = m;
        }

        if (t < T_) {
            bar_arrive(flags, t, tid, bx);
            // gi(t+1) prefetch AFTER the flag store (round-8 FIX 1)
            if (s == 0 && t + 1 < T_) {
                const float* gp = giF + ((size_t)b * T_ + t + 1) * G_;
                pgR = gp[iu]; pgZ = gp[512 + iu]; pgN = gp[1024 + iu];
            }
        }
    }

    // one coalesced selp write-out (WG0 only; round-8 FIX 2)
    __syncthreads();
    if (bx == 0) {
        for (int idx = tid; idx < B_ * T_; idx += 512) {
            const int b2 = idx >> 9, tt = idx & 511;
            selp[b2 * T_ + tt] = (int)((selmask[tt] >> b2) & 1ull);
        }
    }
}

// =====================================================================
// Layer GRU via MFMA (round-6 structure + r10: gi(t+1) prefetch moved
// after bar_arrive — hides the scattered gi gather under the next
// barrier wait instead of ahead of the staging burst).
// =====================================================================
__global__ __launch_bounds__(256) void rec_mfma(
    const unsigned short* __restrict__ giB,
    const unsigned short* __restrict__ wbf,
    const float* __restrict__ bhh,
    const int* __restrict__ nselp, const int* __restrict__ maxnp,
    unsigned short* __restrict__ hA, unsigned short* __restrict__ hBp,
    float* __restrict__ outp, int* __restrict__ flags)
{
    __shared__ __align__(16) unsigned char ldsW[48 * 1040];
    __shared__ __align__(16) unsigned char ldsH[64 * 1040];
    __shared__ float gbuf[48 * 66];

    const int tid = threadIdx.x;
    const int l = tid & 63;
    const int q = tid >> 6;
    const int bx = blockIdx.x;
    const int i0 = bx * 16;
    const int b = tid & 63;

    for (int idx = tid; idx < 48 * 64; idx += 256) {
        const int r = idx >> 6, seg = idx & 63;
        const int tier = r >> 4, ul = r & 15;
        const float4 v = *(const float4*)((const char*)wbf
            + ((size_t)(tier * 512 + i0 + ul) * 512) * 2 + seg * 16);
        *(float4*)(ldsW + r * 1040 + seg * 16) = v;
    }
    const float4 bRv = *(const float4*)(bhh + i0 + 4 * q);
    const float4 bZv = *(const float4*)(bhh + 512 + i0 + 4 * q);
    const float4 bNv = *(const float4*)(bhh + 1024 + i0 + 4 * q);
    const int ns = nselp[b];
    const int TOTAL = *maxnp;

    // gi(t=0) prefetch
    const unsigned short* gbase = giB + (size_t)b * T_ * (size_t)G_ + i0 + 4 * q;
    uint2 gR = *(const uint2*)(gbase);
    uint2 gZ = *(const uint2*)(gbase + 512);
    uint2 gN = *(const uint2*)(gbase + 1024);
    __syncthreads();

    for (int t = 0; t < TOTAL; ++t) {
        const unsigned short* hcur = (t & 1) ? hBp : hA;
        unsigned short* hnxt = (t & 1) ? hA : hBp;

        if (t > 0) bar_wait<32>(flags, t, tid);

        {
            const char* src = (const char*)hcur + tid * 256;
            float4 s0, s1, s2, s3, s4, s5, s6, s7, s8, s9, sa, sb_, sc, sd, se, sf;
            CLOAD4(s0, src + 0 * 16);  CLOAD4(s1, src + 1 * 16);
            CLOAD4(s2, src + 2 * 16);  CLOAD4(s3, src + 3 * 16);
            CLOAD4(s4, src + 4 * 16);  CLOAD4(s5, src + 5 * 16);
            CLOAD4(s6, src + 6 * 16);  CLOAD4(s7, src + 7 * 16);
            CLOAD4(s8, src + 8 * 16);  CLOAD4(s9, src + 9 * 16);
            CLOAD4(sa, src + 10 * 16); CLOAD4(sb_, src + 11 * 16);
            CLOAD4(sc, src + 12 * 16); CLOAD4(sd, src + 13 * 16);
            CLOAD4(se, src + 14 * 16); CLOAD4(sf, src + 15 * 16);
            CWAIT();
            char* dst = (char*)ldsH + (tid >> 2) * 1040 + (tid & 3) * 256;
            *(float4*)(dst + 0 * 16) = s0;  *(float4*)(dst + 1 * 16) = s1;
            *(float4*)(dst + 2 * 16) = s2;  *(float4*)(dst + 3 * 16) = s3;
            *(float4*)(dst + 4 * 16) = s4;  *(float4*)(dst + 5 * 16) = s5;
            *(float4*)(dst + 6 * 16) = s6;  *(float4*)(dst + 7 * 16) = s7;
            *(float4*)(dst + 8 * 16) = s8;  *(float4*)(dst + 9 * 16) = s9;
            *(float4*)(dst + 10 * 16) = sa; *(float4*)(dst + 11 * 16) = sb_;
            *(float4*)(dst + 12 * 16) = sc; *(float4*)(dst + 13 * 16) = sd;
            *(float4*)(dst + 14 * 16) = se; *(float4*)(dst + 15 * 16) = sf;
        }
        __syncthreads();

        f32x4 ac0 = {0.f, 0.f, 0.f, 0.f};
        f32x4 ac1 = {0.f, 0.f, 0.f, 0.f};
        f32x4 ac2 = {0.f, 0.f, 0.f, 0.f};
        {
            const char* ab = (const char*)ldsH + (q * 16 + (l & 15)) * 1040 + (l >> 4) * 16;
            const char* bb = (const char*)ldsW + (l & 15) * 1040 + (l >> 4) * 16;
            #pragma unroll
            for (int ks = 0; ks < 16; ++ks) {
                const bf16x8 av = *(const bf16x8*)(ab + ks * 64);
                const bf16x8 w0 = *(const bf16x8*)(bb + ks * 64);
                const bf16x8 w1 = *(const bf16x8*)(bb + 16 * 1040 + ks * 64);
                const bf16x8 w2 = *(const bf16x8*)(bb + 32 * 1040 + ks * 64);
                ac0 = __builtin_amdgcn_mfma_f32_16x16x32_bf16(av, w0, ac0, 0, 0, 0);
                ac1 = __builtin_amdgcn_mfma_f32_16x16x32_bf16(av, w1, ac1, 0, 0, 0);
                ac2 = __builtin_amdgcn_mfma_f32_16x16x32_bf16(av, w2, ac2, 0, 0, 0);
            }
        }
        {
            const int gcol = q * 16 + 4 * (l >> 4);
            const int grow = l & 15;
            #pragma unroll
            for (int r = 0; r < 4; ++r) {
                gbuf[grow * 66 + gcol + r]        = ac0[r];
                gbuf[(16 + grow) * 66 + gcol + r] = ac1[r];
                gbuf[(32 + grow) * 66 + gcol + r] = ac2[r];
            }
        }
        __syncthreads();

        {
            const ushort4 hp4 = *(const ushort4*)((const char*)ldsH
                                 + b * 1040 + (i0 + 4 * q) * 2);
            const unsigned short hpb[4] = {hp4.x, hp4.y, hp4.z, hp4.w};
            const float irv[4] = {b2f(gR.x & 0xffff), b2f(gR.x >> 16),
                                  b2f(gR.y & 0xffff), b2f(gR.y >> 16)};
            const float izv[4] = {b2f(gZ.x & 0xffff), b2f(gZ.x >> 16),
                                  b2f(gZ.y & 0xffff), b2f(gZ.y >> 16)};
            const float inv[4] = {b2f(gN.x & 0xffff), b2f(gN.x >> 16),
                                  b2f(gN.y & 0xffff), b2f(gN.y >> 16)};
            float4 o;
            unsigned short ob[4];
            #pragma unroll
            for (int j = 0; j < 4; ++j) {
                const int u2 = 4 * q + j;
                const float hr = gbuf[u2 * 66 + b]        + bRv[j];
                const float hz = gbuf[(16 + u2) * 66 + b] + bZv[j];
                const float hn = gbuf[(32 + u2) * 66 + b] + bNv[j];
                const float rr = sigm(irv[j] + hr);
                const float zz = sigm(izv[j] + hz);
                const float nn = tanhf(inv[j] + rr * hn);
                const float hpf = b2f(hpb[j]);
                float hv = (1.f - zz) * nn + zz * hpf;
                if (t >= ns) hv = hpf;
                ((float*)&o)[j] = hv;
                ob[j] = f2bu(hv);
            }
            if (t < ns)
                *(float4*)(outp + ((size_t)b * T_ + t) * 512 + i0 + 4 * q) = o;
            uint2 hpk;
            hpk.x = (unsigned)ob[0] | ((unsigned)ob[1] << 16);
            hpk.y = (unsigned)ob[2] | ((unsigned)ob[3] << 16);
            const unsigned short* hdst = hnxt + (size_t)b * 512 + i0 + 4 * q;
            CSTORE8(hdst, hpk);
        }

        if (t + 1 < TOTAL) {
            bar_arrive(flags, t, tid, bx);
            // r10: prefetch gi(t+1) after the flag store — overlaps the
            // next bar_wait spin instead of delaying the staging burst.
            const unsigned short* gp = gbase + (size_t)(t + 1) * G_;
            gR = *(const uint2*)gp;
            gZ = *(const uint2*)(gp + 512);
            gN = *(const uint2*)(gp + 1024);
        }
    }
}

// =====================================================================
// Per-batch selection post-processing (unchanged).
// =====================================================================
__global__ void build_order_k(const int* __restrict__ mask, const int* __restrict__ sel,
                              int* __restrict__ order, int* __restrict__ nsel,
                              int* __restrict__ maxn)
{
    const int b = threadIdx.x;
    int lens = 0;
    for (int t = 0; t < T_; ++t) lens += (mask[b * T_ + t] != 0);
    int cnt = 0;
    for (int t = 0; t < T_; ++t) {
        int s = sel[b * T_ + t];
        if (t == 0) s = 1;
        if (t == lens - 1) s = 1;
        if (t >= lens) s = 0;
        if (s) order[b * T_ + (cnt++)] = t;
    }
    nsel[b] = cnt;
    int c2 = cnt;
    for (int t = 0; t < T_; ++t) {
        int s = sel[b * T_ + t];
        if (t == 0) s = 1;
        if (t == lens - 1) s = 1;
        if (t >= lens) s = 0;
        if (!s) order[b * T_ + (c2++)] = t;
    }
    __shared__ int red[64];
    red[b] = cnt;
    __syncthreads();
    if (b == 0) {
        int m = 0;
        for (int qq = 0; qq < 64; ++qq) m = max(m, red[qq]);
        *maxn = m;
    }
}

// =====================================================================
// Final linear (unchanged).
// =====================================================================
__global__ void final_k(const unsigned int* __restrict__ pool,
                        const float* __restrict__ Wo, const float* __restrict__ bo,
                        float* __restrict__ out)
{
    const int b = threadIdx.x;
    float s = bo[0];
    for (int f = 0; f < 3 * NF_; ++f)
        s = fmaf(__uint_as_float(pool[b * (3*NF_) + f]), Wo[f], s);
    out[b] = s;
}

// =====================================================================
extern "C" void kernel_launch(void* const* d_in, const int* in_sizes, int n_in,
                              void* d_out, int out_size, void* d_ws, size_t ws_size,
                              hipStream_t stream)
{
    (void)in_sizes; (void)n_in; (void)out_size;
    const float* emb   = (const float*)d_in[0];
    const int*   mask  = (const int*)d_in[1];
    const float* Wih_c = (const float*)d_in[2];
    const float* Whh_c = (const float*)d_in[3];
    const float* bih_c = (const float*)d_in[4];
    const float* bhh_c = (const float*)d_in[5];
    const float* Ws    = (const float*)d_in[6];
    const float* bs    = (const float*)d_in[7];
    const float* Wih0  = (const float*)d_in[8];
    const float* Whh0  = (const float*)d_in[9];
    const float* bih0  = (const float*)d_in[10];
    const float* bhh0  = (const float*)d_in[11];
    const float* Wih1  = (const float*)d_in[12];
    const float* Whh1  = (const float*)d_in[13];
    const float* bih1  = (const float*)d_in[14];
    const float* bhh1  = (const float*)d_in[15];
    const float* Wc3   = (const float*)d_in[16];
    const float* bc3   = (const float*)d_in[17];
    const float* Wc4   = (const float*)d_in[18];
    const float* bc4   = (const float*)d_in[19];
    const float* Wc5   = (const float*)d_in[20];
    const float* bc5   = (const float*)d_in[21];
    const float* Wo    = (const float*)d_in[22];
    const float* bo    = (const float*)d_in[23];

    if (ws_size < WS_NEED) return;
    char* ws = (char*)d_ws;
    float*          giC    = (float*)(ws + OFF_GI);
    unsigned short* giB    = (unsigned short*)(ws + OFF_GI);
    float*          outbuf = (float*)(ws + OFF_OUT);
    unsigned short* wbf0   = (unsigned short*)(ws + OFF_WBF0);
    unsigned short* wbf1   = (unsigned short*)(ws + OFF_WBF1);
    unsigned short* wih0b  = (unsigned short*)(ws + OFF_WIH0);
    unsigned short* wih1b  = (unsigned short*)(ws + OFF_WIH1);
    unsigned short* wc3b   = (unsigned short*)(ws + OFF_WC3);
    unsigned short* wc4b   = (unsigned short*)(ws + OFF_WC4);
    unsigned short* wc5b   = (unsigned short*)(ws + OFF_WC5);
    float*          h0     = (float*)(ws + OFF_H0);
    float*          h1     = (float*)(ws + OFF_H1);
    int*            sel    = (int*)(ws + OFF_SEL);
    int*            order  = (int*)(ws + OFF_ORD);
    int*            nsel   = (int*)(ws + OFF_NSEL);
    int*            maxn   = (int*)(ws + OFF_MAXN);
    int*            flags  = (int*)(ws + OFF_FLG);
    unsigned int*   pool   = (unsigned int*)(ws + OFF_POOL);

    // 1. gi_c = emb @ Wih_c^T + bih_c  (fp32 — argmax precision; supertile grid)
    gemm_f32<<<dim3(12288), 256, 0, stream>>>(emb, Wih_c, bih_c, giC, G_, E_, E_);
    // 2. selector recurrence -> sel (128 WGs, k-split wave pairs)
    hipMemsetAsync(flags, 0, 512, stream);
    hipMemsetAsync(h0, 0, (size_t)B_ * H_ * 4, stream);
    rec_sel<<<128, 512, 0, stream>>>(giC, Whh_c, bhh_c, Ws, bs, h0, h1, sel, flags);
    // 3. forcing + stable partition
    build_order_k<<<1, 64, 0, stream>>>(mask, sel, order, nsel, maxn);
    // 3b. bf16 weight prep — after rec_sel (region aliases gi_c tail).
    wprep_k<<<(G_*H_ + 255)/256, 256, 0, stream>>>(Whh0, wbf0, G_*H_);
    wprep_k<<<(G_*H_ + 255)/256, 256, 0, stream>>>(Whh1, wbf1, G_*H_);
    wprep_k<<<(G_*E_ + 255)/256, 256, 0, stream>>>(Wih0, wih0b, G_*E_);
    wprep_k<<<(G_*H_ + 255)/256, 256, 0, stream>>>(Wih1, wih1b, G_*H_);
    wprep_k<<<(NF_*3*H_ + 255)/256, 256, 0, stream>>>(Wc3, wc3b, NF_*3*H_);
    wprep_k<<<(NF_*4*H_ + 255)/256, 256, 0, stream>>>(Wc4, wc4b, NF_*4*H_);
    wprep_k<<<(NF_*5*H_ + 255)/256, 256, 0, stream>>>(Wc5, wc5b, NF_*5*H_);
    // 4. gi0 = new_emb @ Wih0^T + bih0 (gathered rows, bf16 MFMA)
    gemm_mfma<1,0><<<dim3(512, 24), 256, 0, stream>>>(emb, wih0b, bih0, giB, nullptr,
                                                      G_, E_, E_, T_, 8, order, nsel, 0);
    // 5. layer0 recurrence -> out0
    hipMemsetAsync(flags, 0, 512, stream);
    hipMemsetAsync(h0, 0, (size_t)B_ * H_ * 2, stream);
    hipMemsetAsync(outbuf, 0, (size_t)B_ * T_ * H_ * 4, stream);
    rec_mfma<<<32, 256, 0, stream>>>(giB, wbf0, bhh0, nsel, maxn,
                                     (unsigned short*)h0, (unsigned short*)h1, outbuf, flags);
    // 6. gi1 = out0 @ Wih1^T + bih1 (bf16 MFMA)
    gemm_mfma<0,0><<<dim3(512, 24), 256, 0, stream>>>(outbuf, wih1b, bih1, giB, nullptr,
                                                      G_, H_, H_, 0, 0, nullptr, nullptr, 0);
    // 7. layer1 recurrence -> out1
    hipMemsetAsync(flags, 0, 512, stream);
    hipMemsetAsync(h0, 0, (size_t)B_ * H_ * 2, stream);
    hipMemsetAsync(outbuf, 0, (size_t)B_ * T_ * H_ * 4, stream);
    rec_mfma<<<32, 256, 0, stream>>>(giB, wbf1, bhh1, nsel, maxn,
                                     (unsigned short*)h0, (unsigned short*)h1, outbuf, flags);
    // 8. convs (bf16 MFMA sliding-window) + relu + time-max pooling
    hipMemsetAsync(pool, 0, (size_t)B_ * 3 * NF_ * 4, stream);
    gemm_mfma<2,1><<<dim3(512, 4), 256, 0, stream>>>(outbuf, wc3b, bc3, nullptr, pool,
                                                     NF_, 3*H_, H_, 510, 8, nullptr, nullptr, 0);
    gemm_mfma<2,1><<<dim3(512, 4), 256, 0, stream>>>(outbuf, wc4b, bc4, nullptr, pool,
                                                     NF_, 4*H_, H_, 509, 8, nullptr, nullptr, 256);
    gemm_mfma<2,1><<<dim3(512, 4), 256, 0, stream>>>(outbuf, wc5b, bc5, nullptr, pool,
                                                     NF_, 5*H_, H_, 508, 8, nullptr, nullptr, 512);
    // 9. final linear -> d_out (64 f32)
    final_k<<<1, 64, 0, stream>>>(pool, Wo, bo, (float*)d_out);
}

// Round 11
// 12441.882 us; speedup vs baseline: 2.5724x; 1.0612x over previous
//
#include <hip/hip_runtime.h>
#include <hip/hip_bf16.h>
#include <cstddef>

// ---------------- problem constants ----------------
constexpr int B_ = 64, T_ = 512, E_ = 768, H_ = 512, G_ = 1536, NF_ = 256;

typedef float f32x4 __attribute__((ext_vector_type(4)));
typedef __bf16 bf16x8 __attribute__((ext_vector_type(8)));

// ---------------- workspace layout (bytes) ----------------
constexpr size_t SZ_GIC   = (size_t)B_ * T_ * G_ * 4;       // 192 MiB
constexpr size_t OFF_GI   = 0;                              // f32 gi_c / later bf16 gi
constexpr size_t OFF_OUT  = (size_t)B_ * T_ * G_ * 2;       // 96MiB: out f32 (64MiB)
// bf16 weight copies alias gi_c's tail -> wprep_k must run AFTER rec_sel.
constexpr size_t OFF_WBF0 = 170u * 1024 * 1024;
constexpr size_t OFF_WBF1 = OFF_WBF0 + (size_t)G_ * H_ * 2;
constexpr size_t OFF_WIH0 = OFF_WBF1 + (size_t)G_ * H_ * 2;
constexpr size_t OFF_WIH1 = OFF_WIH0 + (size_t)G_ * E_ * 2;
constexpr size_t OFF_WC3  = OFF_WIH1 + (size_t)G_ * H_ * 2;
constexpr size_t OFF_WC4  = OFF_WC3 + (size_t)NF_ * 3 * H_ * 2;
constexpr size_t OFF_WC5  = OFF_WC4 + (size_t)NF_ * 4 * H_ * 2;
constexpr size_t OFF_MISC = SZ_GIC;
constexpr size_t OFF_H0   = OFF_MISC;
constexpr size_t OFF_H1   = OFF_H0 + (size_t)B_ * H_ * 4;
constexpr size_t OFF_SEL  = OFF_H1 + (size_t)B_ * H_ * 4;   // uint64 selm[T_]
constexpr size_t OFF_ORD  = OFF_SEL + (size_t)B_ * T_ * 4;
constexpr size_t OFF_NSEL = OFF_ORD + (size_t)B_ * T_ * 4;
constexpr size_t OFF_MAXN = OFF_NSEL + 256;
constexpr size_t OFF_FLG  = OFF_MAXN + 256;                 // 128 ints (512 B)
constexpr size_t OFF_POOL = OFF_FLG + 512;
constexpr size_t WS_NEED  = OFF_POOL + (size_t)B_ * 3 * NF_ * 4;

// coherent (fabric-level, L1/L2-bypass) access helpers
#define CLOAD4(dst, ptr) \
    asm volatile("global_load_dwordx4 %0, %1, off sc0 sc1" : "=v"(dst) : "v"(ptr))
#define CWAIT() do { \
    asm volatile("s_waitcnt vmcnt(0)" ::: "memory"); \
    __builtin_amdgcn_sched_barrier(0); } while (0)
#define CSTORE4(ptr, val) \
    asm volatile("global_store_dword %0, %1, off sc0 sc1" :: "v"(ptr), "v"(val) : "memory")
#define CSTORE8(ptr, val) \
    asm volatile("global_store_dwordx2 %0, %1, off sc0 sc1" :: "v"(ptr), "v"(val) : "memory")

__device__ __forceinline__ float sigm(float x) { return 1.f / (1.f + expf(-x)); }
__device__ __forceinline__ float b2f(unsigned short u) {
    return __uint_as_float(((unsigned int)u) << 16);
}
__device__ __forceinline__ unsigned short f2bu(float x) {
    __hip_bfloat16 h = __float2bfloat16(x);
    return *(unsigned short*)&h;
}

template<int NWG>
__device__ __forceinline__ void bar_wait(const int* flags, int t, int tid) {
    if (tid < 64) {
        int v;
        for (;;) {
            asm volatile("global_load_dword %0, %1, off sc0 sc1\n\t"
                         "s_waitcnt vmcnt(0)"
                         : "=v"(v) : "v"(flags + (tid & (NWG - 1))) : "memory");
            if (__all(v >= t)) break;
            __builtin_amdgcn_s_sleep(1);
        }
    }
    __syncthreads();
}

// 128-WG variant: each of 64 lanes polls two flags.
__device__ __forceinline__ void bar_wait128(const int* flags, int t, int tid) {
    if (tid < 64) {
        int v1, v2;
        for (;;) {
            asm volatile("global_load_dword %0, %2, off sc0 sc1\n\t"
                         "global_load_dword %1, %3, off sc0 sc1\n\t"
                         "s_waitcnt vmcnt(0)"
                         : "=&v"(v1), "=&v"(v2)
                         : "v"(flags + tid), "v"(flags + tid + 64) : "memory");
            if (__all((v1 >= t) && (v2 >= t))) break;
            __builtin_amdgcn_s_sleep(1);
        }
    }
    __syncthreads();
}

__device__ __forceinline__ void bar_arrive(int* flags, int t, int tid, int bx) {
    asm volatile("s_waitcnt vmcnt(0)" ::: "memory");
    __syncthreads();
    if (tid == 0) { int pv = t + 1; CSTORE4(flags + bx, pv); }
}

// =====================================================================
// fp32 tiled GEMM — gi_c only (argmax precision).
// r11: k-major LDS layout (As[kk][m], stride 68) — inner loop is
// 2x ds_read_b128 + 16 fma per kk (was 8x ds_read_b32 + 16 fma).
// Operand values and per-output fma chains identical (bit-exact).
// r10 supertile grid kept: 32 supertiles x (16 m x 24 n).
// =====================================================================
__global__ __launch_bounds__(256) void gemm_f32(
    const float* __restrict__ A, const float* __restrict__ W,
    const float* __restrict__ bias, float* __restrict__ Cf,
    int N, int K, int ldA)
{
    __shared__ float As[16 * 68];
    __shared__ float Bs[16 * 68];
    const int tid = threadIdx.x;
    const int tx = tid & 15, ty = tid >> 4;
    const int id = blockIdx.x;
    const int sup = id / 384, rr = id % 384;   // 384 = 16 m-blocks x 24 n-blocks
    const int bx = sup * 16 + (rr & 15);
    const int n0 = (rr >> 4) * 64;

    float acc[4][4] = {};
    const int rl = tid >> 2, kl = (tid & 3) * 4;
    const float* __restrict__ ap = A + ((size_t)bx * 64 + rl) * (size_t)ldA + kl;
    const float* __restrict__ wrow = W + (size_t)(n0 + rl) * (size_t)K + kl;

    for (int k0 = 0; k0 < K; k0 += 16) {
        float4 av = *(const float4*)(ap + k0);
        float4 wv = *(const float4*)(wrow + k0);
        __syncthreads();
        As[(kl+0)*68+rl] = av.x; As[(kl+1)*68+rl] = av.y;
        As[(kl+2)*68+rl] = av.z; As[(kl+3)*68+rl] = av.w;
        Bs[(kl+0)*68+rl] = wv.x; Bs[(kl+1)*68+rl] = wv.y;
        Bs[(kl+2)*68+rl] = wv.z; Bs[(kl+3)*68+rl] = wv.w;
        __syncthreads();
        #pragma unroll
        for (int kk = 0; kk < 16; ++kk) {
            const float4 a4 = *(const float4*)&As[kk*68 + ty*4];
            const float4 w4 = *(const float4*)&Bs[kk*68 + tx*4];
            acc[0][0]=fmaf(a4.x,w4.x,acc[0][0]); acc[0][1]=fmaf(a4.x,w4.y,acc[0][1]);
            acc[0][2]=fmaf(a4.x,w4.z,acc[0][2]); acc[0][3]=fmaf(a4.x,w4.w,acc[0][3]);
            acc[1][0]=fmaf(a4.y,w4.x,acc[1][0]); acc[1][1]=fmaf(a4.y,w4.y,acc[1][1]);
            acc[1][2]=fmaf(a4.y,w4.z,acc[1][2]); acc[1][3]=fmaf(a4.y,w4.w,acc[1][3]);
            acc[2][0]=fmaf(a4.z,w4.x,acc[2][0]); acc[2][1]=fmaf(a4.z,w4.y,acc[2][1]);
            acc[2][2]=fmaf(a4.z,w4.z,acc[2][2]); acc[2][3]=fmaf(a4.z,w4.w,acc[2][3]);
            acc[3][0]=fmaf(a4.w,w4.x,acc[3][0]); acc[3][1]=fmaf(a4.w,w4.y,acc[3][1]);
            acc[3][2]=fmaf(a4.w,w4.z,acc[3][2]); acc[3][3]=fmaf(a4.w,w4.w,acc[3][3]);
        }
    }
    #pragma unroll
    for (int i = 0; i < 4; ++i) {
        int m = bx * 64 + ty*4 + i;
        size_t co = (size_t)m * (size_t)N + n0 + tx*4;
        #pragma unroll
        for (int j = 0; j < 4; ++j)
            Cf[co + j] = acc[i][j] + bias[n0 + tx*4 + j];
    }
}

// =====================================================================
// bf16 MFMA GEMM (unchanged, verified round 6).
// =====================================================================
template<int AMODE, int OMODE>
__global__ __launch_bounds__(256) void gemm_mfma(
    const float* __restrict__ A, const unsigned short* __restrict__ Wb,
    const float* __restrict__ bias,
    unsigned short* __restrict__ Cb, unsigned int* __restrict__ pool,
    int N, int K, int ldA, int rowsPerB, int tilesPerB,
    const int* __restrict__ order, const int* __restrict__ nsel, int poolOff)
{
    __shared__ __align__(16) unsigned short As[64][40];
    __shared__ __align__(16) unsigned short Bs[64][40];
    __shared__ const float* rowp[64];

    const int tid = threadIdx.x;
    const int l = tid & 63;
    const int q = tid >> 6;
    const int bx = blockIdx.x;
    const int n0 = blockIdx.y * 64;

    int tileb = 0, tilet0 = 0;
    if (AMODE != 0) { tileb = bx / tilesPerB; tilet0 = (bx % tilesPerB) * 64; }

    if (tid < 64) {
        const float* p = nullptr;
        if (AMODE == 0) {
            p = A + ((size_t)bx * 64 + tid) * (size_t)ldA;
        } else if (AMODE == 1) {
            int t = tilet0 + tid;
            if (t < nsel[tileb]) {
                int src = order[tileb * T_ + t];
                p = A + ((size_t)tileb * T_ + src) * (size_t)ldA;
            }
        } else {
            int t = tilet0 + tid;
            if (t < rowsPerB) p = A + ((size_t)tileb * T_ + t) * (size_t)ldA;
        }
        rowp[tid] = p;
    }
    __syncthreads();

    f32x4 acc0 = {0.f,0.f,0.f,0.f}, acc1 = {0.f,0.f,0.f,0.f};
    f32x4 acc2 = {0.f,0.f,0.f,0.f}, acc3 = {0.f,0.f,0.f,0.f};

    const int r = tid & 63, seg = tid >> 6;
    const float* ap = rowp[r];
    if (ap) ap += seg * 8;
    const unsigned short* wrow = Wb + (size_t)(n0 + r) * (size_t)K + seg * 8;

    for (int k0 = 0; k0 < K; k0 += 32) {
        float4 fa = make_float4(0,0,0,0), fb = make_float4(0,0,0,0);
        if (ap) { fa = *(const float4*)(ap + k0); fb = *(const float4*)(ap + k0 + 4); }
        const uint4 wv = *(const uint4*)(wrow + k0);
        __syncthreads();
        uint4 pk;
        pk.x = (unsigned)f2bu(fa.x) | ((unsigned)f2bu(fa.y) << 16);
        pk.y = (unsigned)f2bu(fa.z) | ((unsigned)f2bu(fa.w) << 16);
        pk.z = (unsigned)f2bu(fb.x) | ((unsigned)f2bu(fb.y) << 16);
        pk.w = (unsigned)f2bu(fb.z) | ((unsigned)f2bu(fb.w) << 16);
        *(uint4*)&As[r][seg * 8] = pk;
        *(uint4*)&Bs[r][seg * 8] = wv;
        __syncthreads();
        const bf16x8 av = *(const bf16x8*)&As[q * 16 + (l & 15)][(l >> 4) * 8];
        const bf16x8 b0 = *(const bf16x8*)&Bs[ 0 + (l & 15)][(l >> 4) * 8];
        const bf16x8 b1 = *(const bf16x8*)&Bs[16 + (l & 15)][(l >> 4) * 8];
        const bf16x8 b2 = *(const bf16x8*)&Bs[32 + (l & 15)][(l >> 4) * 8];
        const bf16x8 b3 = *(const bf16x8*)&Bs[48 + (l & 15)][(l >> 4) * 8];
        acc0 = __builtin_amdgcn_mfma_f32_16x16x32_bf16(av, b0, acc0, 0, 0, 0);
        acc1 = __builtin_amdgcn_mfma_f32_16x16x32_bf16(av, b1, acc1, 0, 0, 0);
        acc2 = __builtin_amdgcn_mfma_f32_16x16x32_bf16(av, b2, acc2, 0, 0, 0);
        acc3 = __builtin_amdgcn_mfma_f32_16x16x32_bf16(av, b3, acc3, 0, 0, 0);
    }

    f32x4 accs[4] = {acc0, acc1, acc2, acc3};
    if (OMODE == 0) {
        const int mbase = (AMODE == 0) ? bx * 64 : tileb * T_ + tilet0;
        #pragma unroll
        for (int s = 0; s < 4; ++s) {
            const int col = n0 + s * 16 + (l & 15);
            const float bv = bias[col];
            #pragma unroll
            for (int reg = 0; reg < 4; ++reg) {
                const int m = mbase + q * 16 + (l >> 4) * 4 + reg;
                Cb[(size_t)m * (size_t)N + col] = f2bu(accs[s][reg] + bv);
            }
        }
    } else {
        #pragma unroll
        for (int s = 0; s < 4; ++s) {
            const int col = n0 + s * 16 + (l & 15);
            const float bv = bias[col];
            float mx = 0.f;
            #pragma unroll
            for (int reg = 0; reg < 4; ++reg) {
                const int t = tilet0 + q * 16 + (l >> 4) * 4 + reg;
                const float val = fmaxf(accs[s][reg] + bv, 0.f);
                if (t < rowsPerB) mx = fmaxf(mx, val);
            }
            mx = fmaxf(mx, __shfl_xor(mx, 16));
            mx = fmaxf(mx, __shfl_xor(mx, 32));
            if (l < 16)
                atomicMax(&pool[(size_t)tileb * (3*NF_) + poolOff + n0 + s*16 + l],
                          __float_as_uint(mx));
        }
    }
}

// =====================================================================
// Weight f32 -> bf16 prep.
// =====================================================================
__global__ void wprep_k(const float* __restrict__ W, unsigned short* __restrict__ o, int n)
{
    int i = blockIdx.x * 256 + threadIdx.x;
    if (i < n) o[i] = f2bu(W[i]);
}

// =====================================================================
// Selector GRU v7 — 128 WGs x 512 thr, k-split wave pairs.
// r11 changes vs round-9/10 verified v6 (all bit-exact on the h chain):
//  - single-shot 128KB h staging (16 CLOAD4, one CWAIT, one sync) —
//    removes 2 syncs + 1 CWAIT serialization per step. LDS fits (159KB)
//    because selmask moved to a global uint64[T] (selm).
//  - dot-reduce + ballot + selm store moved AFTER bar_arrive (off the
//    critical path; bar_arrive's sync orders the pdot reads).
// Accumulation sequences (gate chains, dot spans) identical to v6.
// =====================================================================
__device__ __forceinline__ void gates_abs(
    const float* __restrict__ hs, int b, int base,
    const float* __restrict__ wR, const float* __restrict__ wZ,
    const float* __restrict__ wN,
    float& aR, float& aZ, float& aN)
{
    #pragma unroll 4
    for (int kq = 0; kq < 32; ++kq) {
        const int k = base + kq * 4;
        const float hv0 = hs[(k+0)*64 + b];
        const float hv1 = hs[(k+1)*64 + b];
        const float hv2 = hs[(k+2)*64 + b];
        const float hv3 = hs[(k+3)*64 + b];
        const float4 wr = *(const float4*)(wR + k);
        const float4 wz = *(const float4*)(wZ + k);
        const float4 wn = *(const float4*)(wN + k);
        aR = fmaf(hv0, wr.x, aR); aR = fmaf(hv1, wr.y, aR);
        aR = fmaf(hv2, wr.z, aR); aR = fmaf(hv3, wr.w, aR);
        aZ = fmaf(hv0, wz.x, aZ); aZ = fmaf(hv1, wz.y, aZ);
        aZ = fmaf(hv2, wz.z, aZ); aZ = fmaf(hv3, wz.w, aZ);
        aN = fmaf(hv0, wn.x, aN); aN = fmaf(hv1, wn.y, aN);
        aN = fmaf(hv2, wn.z, aN); aN = fmaf(hv3, wn.w, aN);
    }
}

__device__ __forceinline__ void dot_abs(
    const float* __restrict__ hs, int b, int base,
    const float* __restrict__ dWl, float& dot)
{
    #pragma unroll 4
    for (int kq = 0; kq < 16; ++kq) {
        const int k = base + kq * 4;
        const float hv0 = hs[(k+0)*64 + b];
        const float hv1 = hs[(k+1)*64 + b];
        const float hv2 = hs[(k+2)*64 + b];
        const float hv3 = hs[(k+3)*64 + b];
        const float4 dv = *(const float4*)(dWl + k);
        dot = fmaf(hv0, dv.x, dot); dot = fmaf(hv1, dv.y, dot);
        dot = fmaf(hv2, dv.z, dot); dot = fmaf(hv3, dv.w, dot);
    }
}

__global__ __launch_bounds__(512) void rec_sel(
    const float* __restrict__ giF,
    const float* __restrict__ Whh, const float* __restrict__ bhh,
    const float* __restrict__ Ws, const float* __restrict__ bs,
    float* __restrict__ h0, float* __restrict__ h1,
    unsigned long long* __restrict__ selm, int* __restrict__ flags)
{
    __shared__ float Wl[12 * 512];              // 24KB: rows u*3+gate
    __shared__ float dWl[512];                  // 2KB
    __shared__ float hs[512 * 64];              // 128KB full h, [k][b]
    __shared__ float partR[4 * 64], partZ[4 * 64], partN[4 * 64];   // 3KB
    __shared__ float pdot[8 * 64];              // 2KB   (total 159KB)

    const int tid = threadIdx.x;
    const int b = tid & 63;
    const int w = __builtin_amdgcn_readfirstlane(tid >> 6);
    const int u = w >> 1, s = w & 1;
    const int bx = blockIdx.x;
    const int iu = bx * 4 + u;

    for (int idx = tid; idx < 12 * 512; idx += 512) {
        int rr = idx >> 9, k = idx & 511;
        int ul = rr / 3, gate = rr - ul * 3;
        Wl[idx] = Whh[((size_t)gate * 512 + bx * 4 + ul) * 512 + k];
    }
    dWl[tid] = Ws[512 + tid] - Ws[tid];
    __syncthreads();

    const float bR = bhh[iu], bZ = bhh[512 + iu], bN = bhh[1024 + iu];
    const float db = bs[1] - bs[0];
    const float* __restrict__ wR = Wl + (u*3 + 0) * 512;
    const float* __restrict__ wZ = Wl + (u*3 + 1) * 512;
    const float* __restrict__ wN = Wl + (u*3 + 2) * 512;

    // gi(t=0) prefetch (s==0 waves consume gi)
    float pgR = 0.f, pgZ = 0.f, pgN = 0.f;
    if (s == 0) {
        pgR = giF[(size_t)b * T_ * G_ + iu];
        pgZ = giF[(size_t)b * T_ * G_ + 512 + iu];
        pgN = giF[(size_t)b * T_ * G_ + 1024 + iu];
    }

    for (int t = 0; t <= T_; ++t) {
        const bool comp = (t < T_);
        const float* hcur = (t & 1) ? h1 : h0;
        float* hnxt = (t & 1) ? h0 : h1;

        if (t > 0) bar_wait128(flags, t, tid);

        // ---- single-shot stage of full h(t): 16 CLOAD4/thread ----
        const float* hc = hcur + (size_t)tid * 4;
        float* hd = hs + tid * 4;
        float4 a0,a1,a2,a3,a4,a5,a6,a7,a8,a9,aa,ab,ac,ad,ae,af;
        CLOAD4(a0, hc +  0*2048); CLOAD4(a1, hc +  1*2048);
        CLOAD4(a2, hc +  2*2048); CLOAD4(a3, hc +  3*2048);
        CLOAD4(a4, hc +  4*2048); CLOAD4(a5, hc +  5*2048);
        CLOAD4(a6, hc +  6*2048); CLOAD4(a7, hc +  7*2048);
        CLOAD4(a8, hc +  8*2048); CLOAD4(a9, hc +  9*2048);
        CLOAD4(aa, hc + 10*2048); CLOAD4(ab, hc + 11*2048);
        CLOAD4(ac, hc + 12*2048); CLOAD4(ad, hc + 13*2048);
        CLOAD4(ae, hc + 14*2048); CLOAD4(af, hc + 15*2048);
        CWAIT();
        *(float4*)(hd +  0*2048) = a0; *(float4*)(hd +  1*2048) = a1;
        *(float4*)(hd +  2*2048) = a2; *(float4*)(hd +  3*2048) = a3;
        *(float4*)(hd +  4*2048) = a4; *(float4*)(hd +  5*2048) = a5;
        *(float4*)(hd +  6*2048) = a6; *(float4*)(hd +  7*2048) = a7;
        *(float4*)(hd +  8*2048) = a8; *(float4*)(hd +  9*2048) = a9;
        *(float4*)(hd + 10*2048) = aa; *(float4*)(hd + 11*2048) = ab;
        *(float4*)(hd + 12*2048) = ac; *(float4*)(hd + 13*2048) = ad;
        *(float4*)(hd + 14*2048) = ae; *(float4*)(hd + 15*2048) = af;
        __syncthreads();

        float aR = (s == 0) ? bR : 0.f;
        float aZ = (s == 0) ? bZ : 0.f;
        float aN = (s == 0) ? bN : 0.f;
        float dot = 0.f, hp = 0.f;

        if (comp) {
            gates_abs(hs, b, s * 128,       wR, wZ, wN, aR, aZ, aN);
            gates_abs(hs, b, 256 + s * 128, wR, wZ, wN, aR, aZ, aN);
            if (s == 0) hp = hs[iu * 64 + b];
        }
        dot_abs(hs, b, (w < 4) ? w * 64 : 256 + (w - 4) * 64, dWl, dot);

        // exchange partials
        if (comp && s == 1) {
            partR[u*64 + b] = aR; partZ[u*64 + b] = aZ; partN[u*64 + b] = aN;
        }
        pdot[w*64 + b] = dot;
        __syncthreads();

        if (comp && s == 0) {
            aR += partR[u*64 + b]; aZ += partZ[u*64 + b]; aN += partN[u*64 + b];
            const float r = sigm(pgR + aR);
            const float z = sigm(pgZ + aZ);
            const float n = tanhf(pgN + r * aN);
            const float hn = (1.f - z) * n + z * hp;
            const float* hdst = hnxt + (size_t)iu * 64 + b;   // coalesced
            CSTORE4(hdst, hn);
        }

        if (t < T_) {
            bar_arrive(flags, t, tid, bx);
            // gi(t+1) prefetch AFTER flag store (round-8 FIX 1)
            if (s == 0 && t + 1 < T_) {
                const float* gp = giF + ((size_t)b * T_ + t + 1) * G_;
                pgR = gp[iu]; pgZ = gp[512 + iu]; pgN = gp[1024 + iu];
            }
        }
        // dot finish off the critical path (synced by the partial-exchange
        // sync; additionally by bar_arrive's sync when t < T_)
        if (w == 0 && t >= 1) {
            float p = pdot[0*64 + b];
            p += pdot[1*64 + b]; p += pdot[2*64 + b]; p += pdot[3*64 + b];
            p += pdot[4*64 + b]; p += pdot[5*64 + b]; p += pdot[6*64 + b];
            p += pdot[7*64 + b];
            unsigned long long m = __ballot((p + db) > 0.f);
            if (tid == 0 && bx == 0) selm[t - 1] = m;
        }
    }
}

// =====================================================================
// Layer GRU via MFMA (unchanged, verified rounds 6/10).
// =====================================================================
__global__ __launch_bounds__(256) void rec_mfma(
    const unsigned short* __restrict__ giB,
    const unsigned short* __restrict__ wbf,
    const float* __restrict__ bhh,
    const int* __restrict__ nselp, const int* __restrict__ maxnp,
    unsigned short* __restrict__ hA, unsigned short* __restrict__ hBp,
    float* __restrict__ outp, int* __restrict__ flags)
{
    __shared__ __align__(16) unsigned char ldsW[48 * 1040];
    __shared__ __align__(16) unsigned char ldsH[64 * 1040];
    __shared__ float gbuf[48 * 66];

    const int tid = threadIdx.x;
    const int l = tid & 63;
    const int q = tid >> 6;
    const int bx = blockIdx.x;
    const int i0 = bx * 16;
    const int b = tid & 63;

    for (int idx = tid; idx < 48 * 64; idx += 256) {
        const int r = idx >> 6, seg = idx & 63;
        const int tier = r >> 4, ul = r & 15;
        const float4 v = *(const float4*)((const char*)wbf
            + ((size_t)(tier * 512 + i0 + ul) * 512) * 2 + seg * 16);
        *(float4*)(ldsW + r * 1040 + seg * 16) = v;
    }
    const float4 bRv = *(const float4*)(bhh + i0 + 4 * q);
    const float4 bZv = *(const float4*)(bhh + 512 + i0 + 4 * q);
    const float4 bNv = *(const float4*)(bhh + 1024 + i0 + 4 * q);
    const int ns = nselp[b];
    const int TOTAL = *maxnp;

    const unsigned short* gbase = giB + (size_t)b * T_ * (size_t)G_ + i0 + 4 * q;
    uint2 gR = *(const uint2*)(gbase);
    uint2 gZ = *(const uint2*)(gbase + 512);
    uint2 gN = *(const uint2*)(gbase + 1024);
    __syncthreads();

    for (int t = 0; t < TOTAL; ++t) {
        const unsigned short* hcur = (t & 1) ? hBp : hA;
        unsigned short* hnxt = (t & 1) ? hA : hBp;

        if (t > 0) bar_wait<32>(flags, t, tid);

        {
            const char* src = (const char*)hcur + tid * 256;
            float4 s0, s1, s2, s3, s4, s5, s6, s7, s8, s9, sa, sb_, sc, sd, se, sf;
            CLOAD4(s0, src + 0 * 16);  CLOAD4(s1, src + 1 * 16);
            CLOAD4(s2, src + 2 * 16);  CLOAD4(s3, src + 3 * 16);
            CLOAD4(s4, src + 4 * 16);  CLOAD4(s5, src + 5 * 16);
            CLOAD4(s6, src + 6 * 16);  CLOAD4(s7, src + 7 * 16);
            CLOAD4(s8, src + 8 * 16);  CLOAD4(s9, src + 9 * 16);
            CLOAD4(sa, src + 10 * 16); CLOAD4(sb_, src + 11 * 16);
            CLOAD4(sc, src + 12 * 16); CLOAD4(sd, src + 13 * 16);
            CLOAD4(se, src + 14 * 16); CLOAD4(sf, src + 15 * 16);
            CWAIT();
            char* dst = (char*)ldsH + (tid >> 2) * 1040 + (tid & 3) * 256;
            *(float4*)(dst + 0 * 16) = s0;  *(float4*)(dst + 1 * 16) = s1;
            *(float4*)(dst + 2 * 16) = s2;  *(float4*)(dst + 3 * 16) = s3;
            *(float4*)(dst + 4 * 16) = s4;  *(float4*)(dst + 5 * 16) = s5;
            *(float4*)(dst + 6 * 16) = s6;  *(float4*)(dst + 7 * 16) = s7;
            *(float4*)(dst + 8 * 16) = s8;  *(float4*)(dst + 9 * 16) = s9;
            *(float4*)(dst + 10 * 16) = sa; *(float4*)(dst + 11 * 16) = sb_;
            *(float4*)(dst + 12 * 16) = sc; *(float4*)(dst + 13 * 16) = sd;
            *(float4*)(dst + 14 * 16) = se; *(float4*)(dst + 15 * 16) = sf;
        }
        __syncthreads();

        f32x4 ac0 = {0.f, 0.f, 0.f, 0.f};
        f32x4 ac1 = {0.f, 0.f, 0.f, 0.f};
        f32x4 ac2 = {0.f, 0.f, 0.f, 0.f};
        {
            const char* ab2 = (const char*)ldsH + (q * 16 + (l & 15)) * 1040 + (l >> 4) * 16;
            const char* bb = (const char*)ldsW + (l & 15) * 1040 + (l >> 4) * 16;
            #pragma unroll
            for (int ks = 0; ks < 16; ++ks) {
                const bf16x8 av = *(const bf16x8*)(ab2 + ks * 64);
                const bf16x8 w0 = *(const bf16x8*)(bb + ks * 64);
                const bf16x8 w1 = *(const bf16x8*)(bb + 16 * 1040 + ks * 64);
                const bf16x8 w2 = *(const bf16x8*)(bb + 32 * 1040 + ks * 64);
                ac0 = __builtin_amdgcn_mfma_f32_16x16x32_bf16(av, w0, ac0, 0, 0, 0);
                ac1 = __builtin_amdgcn_mfma_f32_16x16x32_bf16(av, w1, ac1, 0, 0, 0);
                ac2 = __builtin_amdgcn_mfma_f32_16x16x32_bf16(av, w2, ac2, 0, 0, 0);
            }
        }
        {
            const int gcol = q * 16 + 4 * (l >> 4);
            const int grow = l & 15;
            #pragma unroll
            for (int r = 0; r < 4; ++r) {
                gbuf[grow * 66 + gcol + r]        = ac0[r];
                gbuf[(16 + grow) * 66 + gcol + r] = ac1[r];
                gbuf[(32 + grow) * 66 + gcol + r] = ac2[r];
            }
        }
        __syncthreads();

        {
            const ushort4 hp4 = *(const ushort4*)((const char*)ldsH
                                 + b * 1040 + (i0 + 4 * q) * 2);
            const unsigned short hpb[4] = {hp4.x, hp4.y, hp4.z, hp4.w};
            const float irv[4] = {b2f(gR.x & 0xffff), b2f(gR.x >> 16),
                                  b2f(gR.y & 0xffff), b2f(gR.y >> 16)};
            const float izv[4] = {b2f(gZ.x & 0xffff), b2f(gZ.x >> 16),
                                  b2f(gZ.y & 0xffff), b2f(gZ.y >> 16)};
            const float inv[4] = {b2f(gN.x & 0xffff), b2f(gN.x >> 16),
                                  b2f(gN.y & 0xffff), b2f(gN.y >> 16)};
            float4 o;
            unsigned short ob[4];
            #pragma unroll
            for (int j = 0; j < 4; ++j) {
                const int u2 = 4 * q + j;
                const float hr = gbuf[u2 * 66 + b]        + bRv[j];
                const float hz = gbuf[(16 + u2) * 66 + b] + bZv[j];
                const float hn = gbuf[(32 + u2) * 66 + b] + bNv[j];
                const float rr = sigm(irv[j] + hr);
                const float zz = sigm(izv[j] + hz);
                const float nn = tanhf(inv[j] + rr * hn);
                const float hpf = b2f(hpb[j]);
                float hv = (1.f - zz) * nn + zz * hpf;
                if (t >= ns) hv = hpf;
                ((float*)&o)[j] = hv;
                ob[j] = f2bu(hv);
            }
            if (t < ns)
                *(float4*)(outp + ((size_t)b * T_ + t) * 512 + i0 + 4 * q) = o;
            uint2 hpk;
            hpk.x = (unsigned)ob[0] | ((unsigned)ob[1] << 16);
            hpk.y = (unsigned)ob[2] | ((unsigned)ob[3] << 16);
            const unsigned short* hdst = hnxt + (size_t)b * 512 + i0 + 4 * q;
            CSTORE8(hdst, hpk);
        }

        if (t + 1 < TOTAL) {
            bar_arrive(flags, t, tid, bx);
            const unsigned short* gp = gbase + (size_t)(t + 1) * G_;
            gR = *(const uint2*)gp;
            gZ = *(const uint2*)(gp + 512);
            gN = *(const uint2*)(gp + 1024);
        }
    }
}

// =====================================================================
// Per-batch selection post-processing — r11: decodes sel bits from the
// global uint64 mask array written by rec_sel.
// =====================================================================
__global__ void build_order_k(const int* __restrict__ mask,
                              const unsigned long long* __restrict__ selm,
                              int* __restrict__ order, int* __restrict__ nsel,
                              int* __restrict__ maxn)
{
    const int b = threadIdx.x;
    int lens = 0;
    for (int t = 0; t < T_; ++t) lens += (mask[b * T_ + t] != 0);
    int cnt = 0;
    for (int t = 0; t < T_; ++t) {
        int s = (int)((selm[t] >> b) & 1ull);
        if (t == 0) s = 1;
        if (t == lens - 1) s = 1;
        if (t >= lens) s = 0;
        if (s) order[b * T_ + (cnt++)] = t;
    }
    nsel[b] = cnt;
    int c2 = cnt;
    for (int t = 0; t < T_; ++t) {
        int s = (int)((selm[t] >> b) & 1ull);
        if (t == 0) s = 1;
        if (t == lens - 1) s = 1;
        if (t >= lens) s = 0;
        if (!s) order[b * T_ + (c2++)] = t;
    }
    __shared__ int red[64];
    red[b] = cnt;
    __syncthreads();
    if (b == 0) {
        int m = 0;
        for (int qq = 0; qq < 64; ++qq) m = max(m, red[qq]);
        *maxn = m;
    }
}

// =====================================================================
// Final linear (unchanged).
// =====================================================================
__global__ void final_k(const unsigned int* __restrict__ pool,
                        const float* __restrict__ Wo, const float* __restrict__ bo,
                        float* __restrict__ out)
{
    const int b = threadIdx.x;
    float s = bo[0];
    for (int f = 0; f < 3 * NF_; ++f)
        s = fmaf(__uint_as_float(pool[b * (3*NF_) + f]), Wo[f], s);
    out[b] = s;
}

// =====================================================================
extern "C" void kernel_launch(void* const* d_in, const int* in_sizes, int n_in,
                              void* d_out, int out_size, void* d_ws, size_t ws_size,
                              hipStream_t stream)
{
    (void)in_sizes; (void)n_in; (void)out_size;
    const float* emb   = (const float*)d_in[0];
    const int*   mask  = (const int*)d_in[1];
    const float* Wih_c = (const float*)d_in[2];
    const float* Whh_c = (const float*)d_in[3];
    const float* bih_c = (const float*)d_in[4];
    const float* bhh_c = (const float*)d_in[5];
    const float* Ws    = (const float*)d_in[6];
    const float* bs    = (const float*)d_in[7];
    const float* Wih0  = (const float*)d_in[8];
    const float* Whh0  = (const float*)d_in[9];
    const float* bih0  = (const float*)d_in[10];
    const float* bhh0  = (const float*)d_in[11];
    const float* Wih1  = (const float*)d_in[12];
    const float* Whh1  = (const float*)d_in[13];
    const float* bih1  = (const float*)d_in[14];
    const float* bhh1  = (const float*)d_in[15];
    const float* Wc3   = (const float*)d_in[16];
    const float* bc3   = (const float*)d_in[17];
    const float* Wc4   = (const float*)d_in[18];
    const float* bc4   = (const float*)d_in[19];
    const float* Wc5   = (const float*)d_in[20];
    const float* bc5   = (const float*)d_in[21];
    const float* Wo    = (const float*)d_in[22];
    const float* bo    = (const float*)d_in[23];

    if (ws_size < WS_NEED) return;
    char* ws = (char*)d_ws;
    float*          giC    = (float*)(ws + OFF_GI);
    unsigned short* giB    = (unsigned short*)(ws + OFF_GI);
    float*          outbuf = (float*)(ws + OFF_OUT);
    unsigned short* wbf0   = (unsigned short*)(ws + OFF_WBF0);
    unsigned short* wbf1   = (unsigned short*)(ws + OFF_WBF1);
    unsigned short* wih0b  = (unsigned short*)(ws + OFF_WIH0);
    unsigned short* wih1b  = (unsigned short*)(ws + OFF_WIH1);
    unsigned short* wc3b   = (unsigned short*)(ws + OFF_WC3);
    unsigned short* wc4b   = (unsigned short*)(ws + OFF_WC4);
    unsigned short* wc5b   = (unsigned short*)(ws + OFF_WC5);
    float*          h0     = (float*)(ws + OFF_H0);
    float*          h1     = (float*)(ws + OFF_H1);
    unsigned long long* selm = (unsigned long long*)(ws + OFF_SEL);
    int*            order  = (int*)(ws + OFF_ORD);
    int*            nsel   = (int*)(ws + OFF_NSEL);
    int*            maxn   = (int*)(ws + OFF_MAXN);
    int*            flags  = (int*)(ws + OFF_FLG);
    unsigned int*   pool   = (unsigned int*)(ws + OFF_POOL);

    // 1. gi_c = emb @ Wih_c^T + bih_c  (fp32 — argmax precision; supertile grid)
    gemm_f32<<<dim3(12288), 256, 0, stream>>>(emb, Wih_c, bih_c, giC, G_, E_, E_);
    // 2. selector recurrence -> selm (128 WGs, k-split wave pairs)
    hipMemsetAsync(flags, 0, 512, stream);
    hipMemsetAsync(h0, 0, (size_t)B_ * H_ * 4, stream);
    rec_sel<<<128, 512, 0, stream>>>(giC, Whh_c, bhh_c, Ws, bs, h0, h1, selm, flags);
    // 3. forcing + stable partition
    build_order_k<<<1, 64, 0, stream>>>(mask, selm, order, nsel, maxn);
    // 3b. bf16 weight prep — after rec_sel (region aliases gi_c tail).
    wprep_k<<<(G_*H_ + 255)/256, 256, 0, stream>>>(Whh0, wbf0, G_*H_);
    wprep_k<<<(G_*H_ + 255)/256, 256, 0, stream>>>(Whh1, wbf1, G_*H_);
    wprep_k<<<(G_*E_ + 255)/256, 256, 0, stream>>>(Wih0, wih0b, G_*E_);
    wprep_k<<<(G_*H_ + 255)/256, 256, 0, stream>>>(Wih1, wih1b, G_*H_);
    wprep_k<<<(NF_*3*H_ + 255)/256, 256, 0, stream>>>(Wc3, wc3b, NF_*3*H_);
    wprep_k<<<(NF_*4*H_ + 255)/256, 256, 0, stream>>>(Wc4, wc4b, NF_*4*H_);
    wprep_k<<<(NF_*5*H_ + 255)/256, 256, 0, stream>>>(Wc5, wc5b, NF_*5*H_);
    // 4. gi0 = new_emb @ Wih0^T + bih0 (gathered rows, bf16 MFMA)
    gemm_mfma<1,0><<<dim3(512, 24), 256, 0, stream>>>(emb, wih0b, bih0, giB, nullptr,
                                                      G_, E_, E_, T_, 8, order, nsel, 0);
    // 5. layer0 recurrence -> out0
    hipMemsetAsync(flags, 0, 512, stream);
    hipMemsetAsync(h0, 0, (size_t)B_ * H_ * 2, stream);
    hipMemsetAsync(outbuf, 0, (size_t)B_ * T_ * H_ * 4, stream);
    rec_mfma<<<32, 256, 0, stream>>>(giB, wbf0, bhh0, nsel, maxn,
                                     (unsigned short*)h0, (unsigned short*)h1, outbuf, flags);
    // 6. gi1 = out0 @ Wih1^T + bih1 (bf16 MFMA)
    gemm_mfma<0,0><<<dim3(512, 24), 256, 0, stream>>>(outbuf, wih1b, bih1, giB, nullptr,
                                                      G_, H_, H_, 0, 0, nullptr, nullptr, 0);
    // 7. layer1 recurrence -> out1
    hipMemsetAsync(flags, 0, 512, stream);
    hipMemsetAsync(h0, 0, (size_t)B_ * H_ * 2, stream);
    hipMemsetAsync(outbuf, 0, (size_t)B_ * T_ * H_ * 4, stream);
    rec_mfma<<<32, 256, 0, stream>>>(giB, wbf1, bhh1, nsel, maxn,
                                     (unsigned short*)h0, (unsigned short*)h1, outbuf, flags);
    // 8. convs (bf16 MFMA sliding-window) + relu + time-max pooling
    hipMemsetAsync(pool, 0, (size_t)B_ * 3 * NF_ * 4, stream);
    gemm_mfma<2,1><<<dim3(512, 4), 256, 0, stream>>>(outbuf, wc3b, bc3, nullptr, pool,
                                                     NF_, 3*H_, H_, 510, 8, nullptr, nullptr, 0);
    gemm_mfma<2,1><<<dim3(512, 4), 256, 0, stream>>>(outbuf, wc4b, bc4, nullptr, pool,
                                                     NF_, 4*H_, H_, 509, 8, nullptr, nullptr, 256);
    gemm_mfma<2,1><<<dim3(512, 4), 256, 0, stream>>>(outbuf, wc5b, bc5, nullptr, pool,
                                                     NF_, 5*H_, H_, 508, 8, nullptr, nullptr, 512);
    // 9. final linear -> d_out (64 f32)
    final_k<<<1, 64, 0, stream>>>(pool, Wo, bo, (float*)d_out);
}

// Round 12
// 12263.738 us; speedup vs baseline: 2.6098x; 1.0145x over previous
//
#include <hip/hip_runtime.h>
#include <hip/hip_bf16.h>
#include <cstddef>

// ---------------- problem constants ----------------
constexpr int B_ = 64, T_ = 512, E_ = 768, H_ = 512, G_ = 1536, NF_ = 256;

typedef float f32x4 __attribute__((ext_vector_type(4)));
typedef __bf16 bf16x8 __attribute__((ext_vector_type(8)));

// ---------------- workspace layout (bytes) ----------------
constexpr size_t SZ_GIC   = (size_t)B_ * T_ * G_ * 4;       // 192 MiB
constexpr size_t OFF_GI   = 0;                              // f32 gi_c / later bf16 gi
constexpr size_t OFF_OUT  = (size_t)B_ * T_ * G_ * 2;       // 96MiB: out f32 (64MiB)
// bf16 weight copies alias gi_c's tail -> wprep must run AFTER rec_sel.
// They are CONTIGUOUS from OFF_WBF0 (merged single-prep kernel relies on it).
constexpr size_t OFF_WBF0 = 170u * 1024 * 1024;
constexpr size_t OFF_WBF1 = OFF_WBF0 + (size_t)G_ * H_ * 2;
constexpr size_t OFF_WIH0 = OFF_WBF1 + (size_t)G_ * H_ * 2;
constexpr size_t OFF_WIH1 = OFF_WIH0 + (size_t)G_ * E_ * 2;
constexpr size_t OFF_WC3  = OFF_WIH1 + (size_t)G_ * H_ * 2;
constexpr size_t OFF_WC4  = OFF_WC3 + (size_t)NF_ * 3 * H_ * 2;
constexpr size_t OFF_WC5  = OFF_WC4 + (size_t)NF_ * 4 * H_ * 2;
constexpr size_t OFF_MISC = SZ_GIC;
constexpr size_t OFF_H0   = OFF_MISC;
constexpr size_t OFF_H1   = OFF_H0 + (size_t)B_ * H_ * 4;
constexpr size_t OFF_SEL  = OFF_H1 + (size_t)B_ * H_ * 4;   // uint64 selm[T_]
constexpr size_t OFF_ORD  = OFF_SEL + (size_t)B_ * T_ * 4;
constexpr size_t OFF_NSEL = OFF_ORD + (size_t)B_ * T_ * 4;
constexpr size_t OFF_MAXN = OFF_NSEL + 256;
constexpr size_t OFF_FLG  = OFF_MAXN + 256;                 // 128 ints (512 B)
constexpr size_t OFF_POOL = OFF_FLG + 512;
constexpr size_t WS_NEED  = OFF_POOL + (size_t)B_ * 3 * NF_ * 4;

// merged weight-prep region sizes (elements)
constexpr int WP_N0 = G_ * H_;            // wbf0
constexpr int WP_N1 = WP_N0 + G_ * H_;    // wbf1
constexpr int WP_N2 = WP_N1 + G_ * E_;    // wih0b
constexpr int WP_N3 = WP_N2 + G_ * H_;    // wih1b
constexpr int WP_N4 = WP_N3 + NF_ * 3 * H_;
constexpr int WP_N5 = WP_N4 + NF_ * 4 * H_;
constexpr int WP_N6 = WP_N5 + NF_ * 5 * H_;   // total 5111808

// coherent (fabric-level, L1/L2-bypass) access helpers
#define CLOAD4(dst, ptr) \
    asm volatile("global_load_dwordx4 %0, %1, off sc0 sc1" : "=v"(dst) : "v"(ptr))
#define CWAIT() do { \
    asm volatile("s_waitcnt vmcnt(0)" ::: "memory"); \
    __builtin_amdgcn_sched_barrier(0); } while (0)
#define CSTORE4(ptr, val) \
    asm volatile("global_store_dword %0, %1, off sc0 sc1" :: "v"(ptr), "v"(val) : "memory")
#define CSTORE8(ptr, val) \
    asm volatile("global_store_dwordx2 %0, %1, off sc0 sc1" :: "v"(ptr), "v"(val) : "memory")

__device__ __forceinline__ float sigm(float x) { return 1.f / (1.f + expf(-x)); }
__device__ __forceinline__ float b2f(unsigned short u) {
    return __uint_as_float(((unsigned int)u) << 16);
}
__device__ __forceinline__ unsigned short f2bu(float x) {
    __hip_bfloat16 h = __float2bfloat16(x);
    return *(unsigned short*)&h;
}

template<int NWG>
__device__ __forceinline__ void bar_wait(const int* flags, int t, int tid) {
    if (tid < 64) {
        int v;
        for (;;) {
            asm volatile("global_load_dword %0, %1, off sc0 sc1\n\t"
                         "s_waitcnt vmcnt(0)"
                         : "=v"(v) : "v"(flags + (tid & (NWG - 1))) : "memory");
            if (__all(v >= t)) break;
            __builtin_amdgcn_s_sleep(1);
        }
    }
    __syncthreads();
}

// 128-WG variant: each of 64 lanes polls two flags.
__device__ __forceinline__ void bar_wait128(const int* flags, int t, int tid) {
    if (tid < 64) {
        int v1, v2;
        for (;;) {
            asm volatile("global_load_dword %0, %2, off sc0 sc1\n\t"
                         "global_load_dword %1, %3, off sc0 sc1\n\t"
                         "s_waitcnt vmcnt(0)"
                         : "=&v"(v1), "=&v"(v2)
                         : "v"(flags + tid), "v"(flags + tid + 64) : "memory");
            if (__all((v1 >= t) && (v2 >= t))) break;
            __builtin_amdgcn_s_sleep(1);
        }
    }
    __syncthreads();
}

__device__ __forceinline__ void bar_arrive(int* flags, int t, int tid, int bx) {
    asm volatile("s_waitcnt vmcnt(0)" ::: "memory");
    __syncthreads();
    if (tid == 0) { int pv = t + 1; CSTORE4(flags + bx, pv); }
}

// =====================================================================
// fp32 tiled GEMM — gi_c only (argmax precision). k-major LDS (r11) +
// supertile grid (r10). Bit-exact vs previous rounds.
// =====================================================================
__global__ __launch_bounds__(256) void gemm_f32(
    const float* __restrict__ A, const float* __restrict__ W,
    const float* __restrict__ bias, float* __restrict__ Cf,
    int N, int K, int ldA)
{
    __shared__ float As[16 * 68];
    __shared__ float Bs[16 * 68];
    const int tid = threadIdx.x;
    const int tx = tid & 15, ty = tid >> 4;
    const int id = blockIdx.x;
    const int sup = id / 384, rr = id % 384;   // 384 = 16 m-blocks x 24 n-blocks
    const int bx = sup * 16 + (rr & 15);
    const int n0 = (rr >> 4) * 64;

    float acc[4][4] = {};
    const int rl = tid >> 2, kl = (tid & 3) * 4;
    const float* __restrict__ ap = A + ((size_t)bx * 64 + rl) * (size_t)ldA + kl;
    const float* __restrict__ wrow = W + (size_t)(n0 + rl) * (size_t)K + kl;

    for (int k0 = 0; k0 < K; k0 += 16) {
        float4 av = *(const float4*)(ap + k0);
        float4 wv = *(const float4*)(wrow + k0);
        __syncthreads();
        As[(kl+0)*68+rl] = av.x; As[(kl+1)*68+rl] = av.y;
        As[(kl+2)*68+rl] = av.z; As[(kl+3)*68+rl] = av.w;
        Bs[(kl+0)*68+rl] = wv.x; Bs[(kl+1)*68+rl] = wv.y;
        Bs[(kl+2)*68+rl] = wv.z; Bs[(kl+3)*68+rl] = wv.w;
        __syncthreads();
        #pragma unroll
        for (int kk = 0; kk < 16; ++kk) {
            const float4 a4 = *(const float4*)&As[kk*68 + ty*4];
            const float4 w4 = *(const float4*)&Bs[kk*68 + tx*4];
            acc[0][0]=fmaf(a4.x,w4.x,acc[0][0]); acc[0][1]=fmaf(a4.x,w4.y,acc[0][1]);
            acc[0][2]=fmaf(a4.x,w4.z,acc[0][2]); acc[0][3]=fmaf(a4.x,w4.w,acc[0][3]);
            acc[1][0]=fmaf(a4.y,w4.x,acc[1][0]); acc[1][1]=fmaf(a4.y,w4.y,acc[1][1]);
            acc[1][2]=fmaf(a4.y,w4.z,acc[1][2]); acc[1][3]=fmaf(a4.y,w4.w,acc[1][3]);
            acc[2][0]=fmaf(a4.z,w4.x,acc[2][0]); acc[2][1]=fmaf(a4.z,w4.y,acc[2][1]);
            acc[2][2]=fmaf(a4.z,w4.z,acc[2][2]); acc[2][3]=fmaf(a4.z,w4.w,acc[2][3]);
            acc[3][0]=fmaf(a4.w,w4.x,acc[3][0]); acc[3][1]=fmaf(a4.w,w4.y,acc[3][1]);
            acc[3][2]=fmaf(a4.w,w4.z,acc[3][2]); acc[3][3]=fmaf(a4.w,w4.w,acc[3][3]);
        }
    }
    #pragma unroll
    for (int i = 0; i < 4; ++i) {
        int m = bx * 64 + ty*4 + i;
        size_t co = (size_t)m * (size_t)N + n0 + tx*4;
        #pragma unroll
        for (int j = 0; j < 4; ++j)
            Cf[co + j] = acc[i][j] + bias[n0 + tx*4 + j];
    }
}

// =====================================================================
// bf16 MFMA GEMM — r12: supertile-swizzled 1-D grid (16 m-blocks x nb
// n-blocks per supertile). Concurrent blocks share the A-panel + W in
// L2, fixing gi0's 560MB FETCH (ideal ~100MB). Arithmetic unchanged.
// grid.x = tilesM_total * nb; nb passed as parameter.
// =====================================================================
template<int AMODE, int OMODE>
__global__ __launch_bounds__(256) void gemm_mfma(
    const float* __restrict__ A, const unsigned short* __restrict__ Wb,
    const float* __restrict__ bias,
    unsigned short* __restrict__ Cb, unsigned int* __restrict__ pool,
    int N, int K, int ldA, int rowsPerB, int tilesPerB, int nb,
    const int* __restrict__ order, const int* __restrict__ nsel, int poolOff)
{
    __shared__ __align__(16) unsigned short As[64][40];
    __shared__ __align__(16) unsigned short Bs[64][40];
    __shared__ const float* rowp[64];

    const int tid = threadIdx.x;
    const int l = tid & 63;
    const int q = tid >> 6;
    const int per = 16 * nb;
    const int id = blockIdx.x;
    const int sup = id / per, rr2 = id % per;
    const int mblk = sup * 16 + (rr2 & 15);
    const int n0 = (rr2 >> 4) * 64;

    int tileb = 0, tilet0 = 0;
    if (AMODE != 0) { tileb = mblk / tilesPerB; tilet0 = (mblk % tilesPerB) * 64; }

    if (tid < 64) {
        const float* p = nullptr;
        if (AMODE == 0) {
            p = A + ((size_t)mblk * 64 + tid) * (size_t)ldA;
        } else if (AMODE == 1) {
            int t = tilet0 + tid;
            if (t < nsel[tileb]) {
                int src = order[tileb * T_ + t];
                p = A + ((size_t)tileb * T_ + src) * (size_t)ldA;
            }
        } else {
            int t = tilet0 + tid;
            if (t < rowsPerB) p = A + ((size_t)tileb * T_ + t) * (size_t)ldA;
        }
        rowp[tid] = p;
    }
    __syncthreads();

    f32x4 acc0 = {0.f,0.f,0.f,0.f}, acc1 = {0.f,0.f,0.f,0.f};
    f32x4 acc2 = {0.f,0.f,0.f,0.f}, acc3 = {0.f,0.f,0.f,0.f};

    const int r = tid & 63, seg = tid >> 6;
    const float* ap = rowp[r];
    if (ap) ap += seg * 8;
    const unsigned short* wrow = Wb + (size_t)(n0 + r) * (size_t)K + seg * 8;

    for (int k0 = 0; k0 < K; k0 += 32) {
        float4 fa = make_float4(0,0,0,0), fb = make_float4(0,0,0,0);
        if (ap) { fa = *(const float4*)(ap + k0); fb = *(const float4*)(ap + k0 + 4); }
        const uint4 wv = *(const uint4*)(wrow + k0);
        __syncthreads();
        uint4 pk;
        pk.x = (unsigned)f2bu(fa.x) | ((unsigned)f2bu(fa.y) << 16);
        pk.y = (unsigned)f2bu(fa.z) | ((unsigned)f2bu(fa.w) << 16);
        pk.z = (unsigned)f2bu(fb.x) | ((unsigned)f2bu(fb.y) << 16);
        pk.w = (unsigned)f2bu(fb.z) | ((unsigned)f2bu(fb.w) << 16);
        *(uint4*)&As[r][seg * 8] = pk;
        *(uint4*)&Bs[r][seg * 8] = wv;
        __syncthreads();
        const bf16x8 av = *(const bf16x8*)&As[q * 16 + (l & 15)][(l >> 4) * 8];
        const bf16x8 b0 = *(const bf16x8*)&Bs[ 0 + (l & 15)][(l >> 4) * 8];
        const bf16x8 b1 = *(const bf16x8*)&Bs[16 + (l & 15)][(l >> 4) * 8];
        const bf16x8 b2 = *(const bf16x8*)&Bs[32 + (l & 15)][(l >> 4) * 8];
        const bf16x8 b3 = *(const bf16x8*)&Bs[48 + (l & 15)][(l >> 4) * 8];
        acc0 = __builtin_amdgcn_mfma_f32_16x16x32_bf16(av, b0, acc0, 0, 0, 0);
        acc1 = __builtin_amdgcn_mfma_f32_16x16x32_bf16(av, b1, acc1, 0, 0, 0);
        acc2 = __builtin_amdgcn_mfma_f32_16x16x32_bf16(av, b2, acc2, 0, 0, 0);
        acc3 = __builtin_amdgcn_mfma_f32_16x16x32_bf16(av, b3, acc3, 0, 0, 0);
    }

    f32x4 accs[4] = {acc0, acc1, acc2, acc3};
    if (OMODE == 0) {
        const int mbase = (AMODE == 0) ? mblk * 64 : tileb * T_ + tilet0;
        #pragma unroll
        for (int s = 0; s < 4; ++s) {
            const int col = n0 + s * 16 + (l & 15);
            const float bv = bias[col];
            #pragma unroll
            for (int reg = 0; reg < 4; ++reg) {
                const int m = mbase + q * 16 + (l >> 4) * 4 + reg;
                Cb[(size_t)m * (size_t)N + col] = f2bu(accs[s][reg] + bv);
            }
        }
    } else {
        #pragma unroll
        for (int s = 0; s < 4; ++s) {
            const int col = n0 + s * 16 + (l & 15);
            const float bv = bias[col];
            float mx = 0.f;
            #pragma unroll
            for (int reg = 0; reg < 4; ++reg) {
                const int t = tilet0 + q * 16 + (l >> 4) * 4 + reg;
                const float val = fmaxf(accs[s][reg] + bv, 0.f);
                if (t < rowsPerB) mx = fmaxf(mx, val);
            }
            mx = fmaxf(mx, __shfl_xor(mx, 16));
            mx = fmaxf(mx, __shfl_xor(mx, 32));
            if (l < 16)
                atomicMax(&pool[(size_t)tileb * (3*NF_) + poolOff + n0 + s*16 + l],
                          __float_as_uint(mx));
        }
    }
}

// =====================================================================
// Merged weight f32 -> bf16 prep (r12): one kernel, 7 source regions,
// contiguous bf16 destination at OFF_WBF0.
// =====================================================================
__global__ void wprep_all(
    const float* __restrict__ w0, const float* __restrict__ w1,
    const float* __restrict__ w2, const float* __restrict__ w3,
    const float* __restrict__ w4, const float* __restrict__ w5,
    const float* __restrict__ w6, unsigned short* __restrict__ o)
{
    const int i = blockIdx.x * 256 + threadIdx.x;
    if (i >= WP_N6) return;
    float v;
    if      (i < WP_N0) v = w0[i];
    else if (i < WP_N1) v = w1[i - WP_N0];
    else if (i < WP_N2) v = w2[i - WP_N1];
    else if (i < WP_N3) v = w3[i - WP_N2];
    else if (i < WP_N4) v = w4[i - WP_N3];
    else if (i < WP_N5) v = w5[i - WP_N4];
    else                v = w6[i - WP_N5];
    o[i] = f2bu(v);
}

// =====================================================================
// Selector GRU v7 (unchanged, verified round 11) — 128 WGs x 512 thr.
// =====================================================================
__device__ __forceinline__ void gates_abs(
    const float* __restrict__ hs, int b, int base,
    const float* __restrict__ wR, const float* __restrict__ wZ,
    const float* __restrict__ wN,
    float& aR, float& aZ, float& aN)
{
    #pragma unroll 4
    for (int kq = 0; kq < 32; ++kq) {
        const int k = base + kq * 4;
        const float hv0 = hs[(k+0)*64 + b];
        const float hv1 = hs[(k+1)*64 + b];
        const float hv2 = hs[(k+2)*64 + b];
        const float hv3 = hs[(k+3)*64 + b];
        const float4 wr = *(const float4*)(wR + k);
        const float4 wz = *(const float4*)(wZ + k);
        const float4 wn = *(const float4*)(wN + k);
        aR = fmaf(hv0, wr.x, aR); aR = fmaf(hv1, wr.y, aR);
        aR = fmaf(hv2, wr.z, aR); aR = fmaf(hv3, wr.w, aR);
        aZ = fmaf(hv0, wz.x, aZ); aZ = fmaf(hv1, wz.y, aZ);
        aZ = fmaf(hv2, wz.z, aZ); aZ = fmaf(hv3, wz.w, aZ);
        aN = fmaf(hv0, wn.x, aN); aN = fmaf(hv1, wn.y, aN);
        aN = fmaf(hv2, wn.z, aN); aN = fmaf(hv3, wn.w, aN);
    }
}

__device__ __forceinline__ void dot_abs(
    const float* __restrict__ hs, int b, int base,
    const float* __restrict__ dWl, float& dot)
{
    #pragma unroll 4
    for (int kq = 0; kq < 16; ++kq) {
        const int k = base + kq * 4;
        const float hv0 = hs[(k+0)*64 + b];
        const float hv1 = hs[(k+1)*64 + b];
        const float hv2 = hs[(k+2)*64 + b];
        const float hv3 = hs[(k+3)*64 + b];
        const float4 dv = *(const float4*)(dWl + k);
        dot = fmaf(hv0, dv.x, dot); dot = fmaf(hv1, dv.y, dot);
        dot = fmaf(hv2, dv.z, dot); dot = fmaf(hv3, dv.w, dot);
    }
}

__global__ __launch_bounds__(512) void rec_sel(
    const float* __restrict__ giF,
    const float* __restrict__ Whh, const float* __restrict__ bhh,
    const float* __restrict__ Ws, const float* __restrict__ bs,
    float* __restrict__ h0, float* __restrict__ h1,
    unsigned long long* __restrict__ selm, int* __restrict__ flags)
{
    __shared__ float Wl[12 * 512];              // 24KB: rows u*3+gate
    __shared__ float dWl[512];                  // 2KB
    __shared__ float hs[512 * 64];              // 128KB full h, [k][b]
    __shared__ float partR[4 * 64], partZ[4 * 64], partN[4 * 64];   // 3KB
    __shared__ float pdot[8 * 64];              // 2KB   (total 159KB)

    const int tid = threadIdx.x;
    const int b = tid & 63;
    const int w = __builtin_amdgcn_readfirstlane(tid >> 6);
    const int u = w >> 1, s = w & 1;
    const int bx = blockIdx.x;
    const int iu = bx * 4 + u;

    for (int idx = tid; idx < 12 * 512; idx += 512) {
        int rr = idx >> 9, k = idx & 511;
        int ul = rr / 3, gate = rr - ul * 3;
        Wl[idx] = Whh[((size_t)gate * 512 + bx * 4 + ul) * 512 + k];
    }
    dWl[tid] = Ws[512 + tid] - Ws[tid];
    __syncthreads();

    const float bR = bhh[iu], bZ = bhh[512 + iu], bN = bhh[1024 + iu];
    const float db = bs[1] - bs[0];
    const float* __restrict__ wR = Wl + (u*3 + 0) * 512;
    const float* __restrict__ wZ = Wl + (u*3 + 1) * 512;
    const float* __restrict__ wN = Wl + (u*3 + 2) * 512;

    // gi(t=0) prefetch (s==0 waves consume gi)
    float pgR = 0.f, pgZ = 0.f, pgN = 0.f;
    if (s == 0) {
        pgR = giF[(size_t)b * T_ * G_ + iu];
        pgZ = giF[(size_t)b * T_ * G_ + 512 + iu];
        pgN = giF[(size_t)b * T_ * G_ + 1024 + iu];
    }

    for (int t = 0; t <= T_; ++t) {
        const bool comp = (t < T_);
        const float* hcur = (t & 1) ? h1 : h0;
        float* hnxt = (t & 1) ? h0 : h1;

        if (t > 0) bar_wait128(flags, t, tid);

        // ---- single-shot stage of full h(t): 16 CLOAD4/thread ----
        const float* hc = hcur + (size_t)tid * 4;
        float* hd = hs + tid * 4;
        float4 a0,a1,a2,a3,a4,a5,a6,a7,a8,a9,aa,ab,ac,ad,ae,af;
        CLOAD4(a0, hc +  0*2048); CLOAD4(a1, hc +  1*2048);
        CLOAD4(a2, hc +  2*2048); CLOAD4(a3, hc +  3*2048);
        CLOAD4(a4, hc +  4*2048); CLOAD4(a5, hc +  5*2048);
        CLOAD4(a6, hc +  6*2048); CLOAD4(a7, hc +  7*2048);
        CLOAD4(a8, hc +  8*2048); CLOAD4(a9, hc +  9*2048);
        CLOAD4(aa, hc + 10*2048); CLOAD4(ab, hc + 11*2048);
        CLOAD4(ac, hc + 12*2048); CLOAD4(ad, hc + 13*2048);
        CLOAD4(ae, hc + 14*2048); CLOAD4(af, hc + 15*2048);
        CWAIT();
        *(float4*)(hd +  0*2048) = a0; *(float4*)(hd +  1*2048) = a1;
        *(float4*)(hd +  2*2048) = a2; *(float4*)(hd +  3*2048) = a3;
        *(float4*)(hd +  4*2048) = a4; *(float4*)(hd +  5*2048) = a5;
        *(float4*)(hd +  6*2048) = a6; *(float4*)(hd +  7*2048) = a7;
        *(float4*)(hd +  8*2048) = a8; *(float4*)(hd +  9*2048) = a9;
        *(float4*)(hd + 10*2048) = aa; *(float4*)(hd + 11*2048) = ab;
        *(float4*)(hd + 12*2048) = ac; *(float4*)(hd + 13*2048) = ad;
        *(float4*)(hd + 14*2048) = ae; *(float4*)(hd + 15*2048) = af;
        __syncthreads();

        float aR = (s == 0) ? bR : 0.f;
        float aZ = (s == 0) ? bZ : 0.f;
        float aN = (s == 0) ? bN : 0.f;
        float dot = 0.f, hp = 0.f;

        if (comp) {
            gates_abs(hs, b, s * 128,       wR, wZ, wN, aR, aZ, aN);
            gates_abs(hs, b, 256 + s * 128, wR, wZ, wN, aR, aZ, aN);
            if (s == 0) hp = hs[iu * 64 + b];
        }
        dot_abs(hs, b, (w < 4) ? w * 64 : 256 + (w - 4) * 64, dWl, dot);

        // exchange partials
        if (comp && s == 1) {
            partR[u*64 + b] = aR; partZ[u*64 + b] = aZ; partN[u*64 + b] = aN;
        }
        pdot[w*64 + b] = dot;
        __syncthreads();

        if (comp && s == 0) {
            aR += partR[u*64 + b]; aZ += partZ[u*64 + b]; aN += partN[u*64 + b];
            const float r = sigm(pgR + aR);
            const float z = sigm(pgZ + aZ);
            const float n = tanhf(pgN + r * aN);
            const float hn = (1.f - z) * n + z * hp;
            const float* hdst = hnxt + (size_t)iu * 64 + b;   // coalesced
            CSTORE4(hdst, hn);
        }

        if (t < T_) {
            bar_arrive(flags, t, tid, bx);
            // gi(t+1) prefetch AFTER flag store (round-8 FIX 1)
            if (s == 0 && t + 1 < T_) {
                const float* gp = giF + ((size_t)b * T_ + t + 1) * G_;
                pgR = gp[iu]; pgZ = gp[512 + iu]; pgN = gp[1024 + iu];
            }
        }
        // dot finish off the critical path
        if (w == 0 && t >= 1) {
            float p = pdot[0*64 + b];
            p += pdot[1*64 + b]; p += pdot[2*64 + b]; p += pdot[3*64 + b];
            p += pdot[4*64 + b]; p += pdot[5*64 + b]; p += pdot[6*64 + b];
            p += pdot[7*64 + b];
            unsigned long long m = __ballot((p + db) > 0.f);
            if (tid == 0 && bx == 0) selm[t - 1] = m;
        }
    }
}

// =====================================================================
// Layer GRU via MFMA (unchanged, verified rounds 6/10/11).
// =====================================================================
__global__ __launch_bounds__(256) void rec_mfma(
    const unsigned short* __restrict__ giB,
    const unsigned short* __restrict__ wbf,
    const float* __restrict__ bhh,
    const int* __restrict__ nselp, const int* __restrict__ maxnp,
    unsigned short* __restrict__ hA, unsigned short* __restrict__ hBp,
    float* __restrict__ outp, int* __restrict__ flags)
{
    __shared__ __align__(16) unsigned char ldsW[48 * 1040];
    __shared__ __align__(16) unsigned char ldsH[64 * 1040];
    __shared__ float gbuf[48 * 66];

    const int tid = threadIdx.x;
    const int l = tid & 63;
    const int q = tid >> 6;
    const int bx = blockIdx.x;
    const int i0 = bx * 16;
    const int b = tid & 63;

    for (int idx = tid; idx < 48 * 64; idx += 256) {
        const int r = idx >> 6, seg = idx & 63;
        const int tier = r >> 4, ul = r & 15;
        const float4 v = *(const float4*)((const char*)wbf
            + ((size_t)(tier * 512 + i0 + ul) * 512) * 2 + seg * 16);
        *(float4*)(ldsW + r * 1040 + seg * 16) = v;
    }
    const float4 bRv = *(const float4*)(bhh + i0 + 4 * q);
    const float4 bZv = *(const float4*)(bhh + 512 + i0 + 4 * q);
    const float4 bNv = *(const float4*)(bhh + 1024 + i0 + 4 * q);
    const int ns = nselp[b];
    const int TOTAL = *maxnp;

    const unsigned short* gbase = giB + (size_t)b * T_ * (size_t)G_ + i0 + 4 * q;
    uint2 gR = *(const uint2*)(gbase);
    uint2 gZ = *(const uint2*)(gbase + 512);
    uint2 gN = *(const uint2*)(gbase + 1024);
    __syncthreads();

    for (int t = 0; t < TOTAL; ++t) {
        const unsigned short* hcur = (t & 1) ? hBp : hA;
        unsigned short* hnxt = (t & 1) ? hA : hBp;

        if (t > 0) bar_wait<32>(flags, t, tid);

        {
            const char* src = (const char*)hcur + tid * 256;
            float4 s0, s1, s2, s3, s4, s5, s6, s7, s8, s9, sa, sb_, sc, sd, se, sf;
            CLOAD4(s0, src + 0 * 16);  CLOAD4(s1, src + 1 * 16);
            CLOAD4(s2, src + 2 * 16);  CLOAD4(s3, src + 3 * 16);
            CLOAD4(s4, src + 4 * 16);  CLOAD4(s5, src + 5 * 16);
            CLOAD4(s6, src + 6 * 16);  CLOAD4(s7, src + 7 * 16);
            CLOAD4(s8, src + 8 * 16);  CLOAD4(s9, src + 9 * 16);
            CLOAD4(sa, src + 10 * 16); CLOAD4(sb_, src + 11 * 16);
            CLOAD4(sc, src + 12 * 16); CLOAD4(sd, src + 13 * 16);
            CLOAD4(se, src + 14 * 16); CLOAD4(sf, src + 15 * 16);
            CWAIT();
            char* dst = (char*)ldsH + (tid >> 2) * 1040 + (tid & 3) * 256;
            *(float4*)(dst + 0 * 16) = s0;  *(float4*)(dst + 1 * 16) = s1;
            *(float4*)(dst + 2 * 16) = s2;  *(float4*)(dst + 3 * 16) = s3;
            *(float4*)(dst + 4 * 16) = s4;  *(float4*)(dst + 5 * 16) = s5;
            *(float4*)(dst + 6 * 16) = s6;  *(float4*)(dst + 7 * 16) = s7;
            *(float4*)(dst + 8 * 16) = s8;  *(float4*)(dst + 9 * 16) = s9;
            *(float4*)(dst + 10 * 16) = sa; *(float4*)(dst + 11 * 16) = sb_;
            *(float4*)(dst + 12 * 16) = sc; *(float4*)(dst + 13 * 16) = sd;
            *(float4*)(dst + 14 * 16) = se; *(float4*)(dst + 15 * 16) = sf;
        }
        __syncthreads();

        f32x4 ac0 = {0.f, 0.f, 0.f, 0.f};
        f32x4 ac1 = {0.f, 0.f, 0.f, 0.f};
        f32x4 ac2 = {0.f, 0.f, 0.f, 0.f};
        {
            const char* ab2 = (const char*)ldsH + (q * 16 + (l & 15)) * 1040 + (l >> 4) * 16;
            const char* bb = (const char*)ldsW + (l & 15) * 1040 + (l >> 4) * 16;
            #pragma unroll
            for (int ks = 0; ks < 16; ++ks) {
                const bf16x8 av = *(const bf16x8*)(ab2 + ks * 64);
                const bf16x8 w0 = *(const bf16x8*)(bb + ks * 64);
                const bf16x8 w1 = *(const bf16x8*)(bb + 16 * 1040 + ks * 64);
                const bf16x8 w2 = *(const bf16x8*)(bb + 32 * 1040 + ks * 64);
                ac0 = __builtin_amdgcn_mfma_f32_16x16x32_bf16(av, w0, ac0, 0, 0, 0);
                ac1 = __builtin_amdgcn_mfma_f32_16x16x32_bf16(av, w1, ac1, 0, 0, 0);
                ac2 = __builtin_amdgcn_mfma_f32_16x16x32_bf16(av, w2, ac2, 0, 0, 0);
            }
        }
        {
            const int gcol = q * 16 + 4 * (l >> 4);
            const int grow = l & 15;
            #pragma unroll
            for (int r = 0; r < 4; ++r) {
                gbuf[grow * 66 + gcol + r]        = ac0[r];
                gbuf[(16 + grow) * 66 + gcol + r] = ac1[r];
                gbuf[(32 + grow) * 66 + gcol + r] = ac2[r];
            }
        }
        __syncthreads();

        {
            const ushort4 hp4 = *(const ushort4*)((const char*)ldsH
                                 + b * 1040 + (i0 + 4 * q) * 2);
            const unsigned short hpb[4] = {hp4.x, hp4.y, hp4.z, hp4.w};
            const float irv[4] = {b2f(gR.x & 0xffff), b2f(gR.x >> 16),
                                  b2f(gR.y & 0xffff), b2f(gR.y >> 16)};
            const float izv[4] = {b2f(gZ.x & 0xffff), b2f(gZ.x >> 16),
                                  b2f(gZ.y & 0xffff), b2f(gZ.y >> 16)};
            const float inv[4] = {b2f(gN.x & 0xffff), b2f(gN.x >> 16),
                                  b2f(gN.y & 0xffff), b2f(gN.y >> 16)};
            float4 o;
            unsigned short ob[4];
            #pragma unroll
            for (int j = 0; j < 4; ++j) {
                const int u2 = 4 * q + j;
                const float hr = gbuf[u2 * 66 + b]        + bRv[j];
                const float hz = gbuf[(16 + u2) * 66 + b] + bZv[j];
                const float hn = gbuf[(32 + u2) * 66 + b] + bNv[j];
                const float rr = sigm(irv[j] + hr);
                const float zz = sigm(izv[j] + hz);
                const float nn = tanhf(inv[j] + rr * hn);
                const float hpf = b2f(hpb[j]);
                float hv = (1.f - zz) * nn + zz * hpf;
                if (t >= ns) hv = hpf;
                ((float*)&o)[j] = hv;
                ob[j] = f2bu(hv);
            }
            if (t < ns)
                *(float4*)(outp + ((size_t)b * T_ + t) * 512 + i0 + 4 * q) = o;
            uint2 hpk;
            hpk.x = (unsigned)ob[0] | ((unsigned)ob[1] << 16);
            hpk.y = (unsigned)ob[2] | ((unsigned)ob[3] << 16);
            const unsigned short* hdst = hnxt + (size_t)b * 512 + i0 + 4 * q;
            CSTORE8(hdst, hpk);
        }

        if (t + 1 < TOTAL) {
            bar_arrive(flags, t, tid, bx);
            const unsigned short* gp = gbase + (size_t)(t + 1) * G_;
            gR = *(const uint2*)gp;
            gZ = *(const uint2*)(gp + 512);
            gN = *(const uint2*)(gp + 1024);
        }
    }
}

// =====================================================================
// Per-batch selection post-processing (unchanged, r11 selm version).
// =====================================================================
__global__ void build_order_k(const int* __restrict__ mask,
                              const unsigned long long* __restrict__ selm,
                              int* __restrict__ order, int* __restrict__ nsel,
                              int* __restrict__ maxn)
{
    const int b = threadIdx.x;
    int lens = 0;
    for (int t = 0; t < T_; ++t) lens += (mask[b * T_ + t] != 0);
    int cnt = 0;
    for (int t = 0; t < T_; ++t) {
        int s = (int)((selm[t] >> b) & 1ull);
        if (t == 0) s = 1;
        if (t == lens - 1) s = 1;
        if (t >= lens) s = 0;
        if (s) order[b * T_ + (cnt++)] = t;
    }
    nsel[b] = cnt;
    int c2 = cnt;
    for (int t = 0; t < T_; ++t) {
        int s = (int)((selm[t] >> b) & 1ull);
        if (t == 0) s = 1;
        if (t == lens - 1) s = 1;
        if (t >= lens) s = 0;
        if (!s) order[b * T_ + (c2++)] = t;
    }
    __shared__ int red[64];
    red[b] = cnt;
    __syncthreads();
    if (b == 0) {
        int m = 0;
        for (int qq = 0; qq < 64; ++qq) m = max(m, red[qq]);
        *maxn = m;
    }
}

// =====================================================================
// Final linear (unchanged).
// =====================================================================
__global__ void final_k(const unsigned int* __restrict__ pool,
                        const float* __restrict__ Wo, const float* __restrict__ bo,
                        float* __restrict__ out)
{
    const int b = threadIdx.x;
    float s = bo[0];
    for (int f = 0; f < 3 * NF_; ++f)
        s = fmaf(__uint_as_float(pool[b * (3*NF_) + f]), Wo[f], s);
    out[b] = s;
}

// =====================================================================
extern "C" void kernel_launch(void* const* d_in, const int* in_sizes, int n_in,
                              void* d_out, int out_size, void* d_ws, size_t ws_size,
                              hipStream_t stream)
{
    (void)in_sizes; (void)n_in; (void)out_size;
    const float* emb   = (const float*)d_in[0];
    const int*   mask  = (const int*)d_in[1];
    const float* Wih_c = (const float*)d_in[2];
    const float* Whh_c = (const float*)d_in[3];
    const float* bih_c = (const float*)d_in[4];
    const float* bhh_c = (const float*)d_in[5];
    const float* Ws    = (const float*)d_in[6];
    const float* bs    = (const float*)d_in[7];
    const float* Wih0  = (const float*)d_in[8];
    const float* Whh0  = (const float*)d_in[9];
    const float* bih0  = (const float*)d_in[10];
    const float* bhh0  = (const float*)d_in[11];
    const float* Wih1  = (const float*)d_in[12];
    const float* Whh1  = (const float*)d_in[13];
    const float* bih1  = (const float*)d_in[14];
    const float* bhh1  = (const float*)d_in[15];
    const float* Wc3   = (const float*)d_in[16];
    const float* bc3   = (const float*)d_in[17];
    const float* Wc4   = (const float*)d_in[18];
    const float* bc4   = (const float*)d_in[19];
    const float* Wc5   = (const float*)d_in[20];
    const float* bc5   = (const float*)d_in[21];
    const float* Wo    = (const float*)d_in[22];
    const float* bo    = (const float*)d_in[23];

    if (ws_size < WS_NEED) return;
    char* ws = (char*)d_ws;
    float*          giC    = (float*)(ws + OFF_GI);
    unsigned short* giB    = (unsigned short*)(ws + OFF_GI);
    float*          outbuf = (float*)(ws + OFF_OUT);
    unsigned short* wpack  = (unsigned short*)(ws + OFF_WBF0);   // contiguous bf16 weights
    unsigned short* wbf0   = (unsigned short*)(ws + OFF_WBF0);
    unsigned short* wbf1   = (unsigned short*)(ws + OFF_WBF1);
    unsigned short* wih0b  = (unsigned short*)(ws + OFF_WIH0);
    unsigned short* wih1b  = (unsigned short*)(ws + OFF_WIH1);
    unsigned short* wc3b   = (unsigned short*)(ws + OFF_WC3);
    unsigned short* wc4b   = (unsigned short*)(ws + OFF_WC4);
    unsigned short* wc5b   = (unsigned short*)(ws + OFF_WC5);
    float*          h0     = (float*)(ws + OFF_H0);
    float*          h1     = (float*)(ws + OFF_H1);
    unsigned long long* selm = (unsigned long long*)(ws + OFF_SEL);
    int*            order  = (int*)(ws + OFF_ORD);
    int*            nsel   = (int*)(ws + OFF_NSEL);
    int*            maxn   = (int*)(ws + OFF_MAXN);
    int*            flags  = (int*)(ws + OFF_FLG);
    unsigned int*   pool   = (unsigned int*)(ws + OFF_POOL);

    // 1. gi_c = emb @ Wih_c^T + bih_c  (fp32 — argmax precision; supertile grid)
    gemm_f32<<<dim3(12288), 256, 0, stream>>>(emb, Wih_c, bih_c, giC, G_, E_, E_);
    // 2. selector recurrence -> selm (128 WGs, k-split wave pairs)
    hipMemsetAsync(flags, 0, 512, stream);
    hipMemsetAsync(h0, 0, (size_t)B_ * H_ * 4, stream);
    rec_sel<<<128, 512, 0, stream>>>(giC, Whh_c, bhh_c, Ws, bs, h0, h1, selm, flags);
    // 3. forcing + stable partition
    build_order_k<<<1, 64, 0, stream>>>(mask, selm, order, nsel, maxn);
    // 3b. merged bf16 weight prep — after rec_sel (region aliases gi_c tail).
    wprep_all<<<(WP_N6 + 255) / 256, 256, 0, stream>>>(Whh0, Whh1, Wih0, Wih1,
                                                       Wc3, Wc4, Wc5, wpack);
    // 4. gi0 = new_emb @ Wih0^T + bih0 (gathered rows, bf16 MFMA, supertile)
    gemm_mfma<1,0><<<dim3(512 * 24), 256, 0, stream>>>(emb, wih0b, bih0, giB, nullptr,
                                                       G_, E_, E_, T_, 8, 24, order, nsel, 0);
    // 5. layer0 recurrence -> out0
    hipMemsetAsync(flags, 0, 512, stream);
    hipMemsetAsync(h0, 0, (size_t)B_ * H_ * 2, stream);
    hipMemsetAsync(outbuf, 0, (size_t)B_ * T_ * H_ * 4, stream);
    rec_mfma<<<32, 256, 0, stream>>>(giB, wbf0, bhh0, nsel, maxn,
                                     (unsigned short*)h0, (unsigned short*)h1, outbuf, flags);
    // 6. gi1 = out0 @ Wih1^T + bih1 (bf16 MFMA, supertile)
    gemm_mfma<0,0><<<dim3(512 * 24), 256, 0, stream>>>(outbuf, wih1b, bih1, giB, nullptr,
                                                       G_, H_, H_, 0, 0, 24, nullptr, nullptr, 0);
    // 7. layer1 recurrence -> out1
    hipMemsetAsync(flags, 0, 512, stream);
    hipMemsetAsync(h0, 0, (size_t)B_ * H_ * 2, stream);
    hipMemsetAsync(outbuf, 0, (size_t)B_ * T_ * H_ * 4, stream);
    rec_mfma<<<32, 256, 0, stream>>>(giB, wbf1, bhh1, nsel, maxn,
                                     (unsigned short*)h0, (unsigned short*)h1, outbuf, flags);
    // 8. convs (bf16 MFMA sliding-window, supertile) + relu + time-max pooling
    hipMemsetAsync(pool, 0, (size_t)B_ * 3 * NF_ * 4, stream);
    gemm_mfma<2,1><<<dim3(512 * 4), 256, 0, stream>>>(outbuf, wc3b, bc3, nullptr, pool,
                                                      NF_, 3*H_, H_, 510, 8, 4, nullptr, nullptr, 0);
    gemm_mfma<2,1><<<dim3(512 * 4), 256, 0, stream>>>(outbuf, wc4b, bc4, nullptr, pool,
                                                      NF_, 4*H_, H_, 509, 8, 4, nullptr, nullptr, 256);
    gemm_mfma<2,1><<<dim3(512 * 4), 256, 0, stream>>>(outbuf, wc5b, bc5, nullptr, pool,
                                                      NF_, 5*H_, H_, 508, 8, 4, nullptr, nullptr, 512);
    // 9. final linear -> d_out (64 f32)
    final_k<<<1, 64, 0, stream>>>(pool, Wo, bo, (float*)d_out);
}

// Round 13
// 10588.746 us; speedup vs baseline: 3.0226x; 1.1582x over previous
//
#include <hip/hip_runtime.h>
#include <hip/hip_bf16.h>
#include <cstddef>

// ---------------- problem constants ----------------
constexpr int B_ = 64, T_ = 512, E_ = 768, H_ = 512, G_ = 1536, NF_ = 256;

typedef float f32x4 __attribute__((ext_vector_type(4)));
typedef __bf16 bf16x8 __attribute__((ext_vector_type(8)));

// ---------------- workspace layout (bytes) ----------------
constexpr size_t SZ_GIC   = (size_t)B_ * T_ * G_ * 4;       // 192 MiB
constexpr size_t OFF_GI   = 0;                              // f32 gi_c / later bf16 gi
constexpr size_t OFF_OUT  = (size_t)B_ * T_ * G_ * 2;       // 96MiB: out1 f32 (64MiB)
// bf16 weight copies alias gi_c's tail -> wprep must run AFTER rec_sel.
constexpr size_t OFF_WBF0 = 170u * 1024 * 1024;
constexpr size_t OFF_WBF1 = OFF_WBF0 + (size_t)G_ * H_ * 2;
constexpr size_t OFF_WIH0 = OFF_WBF1 + (size_t)G_ * H_ * 2;
constexpr size_t OFF_WIH1 = OFF_WIH0 + (size_t)G_ * E_ * 2;
constexpr size_t OFF_WC3  = OFF_WIH1 + (size_t)G_ * H_ * 2;
constexpr size_t OFF_WC4  = OFF_WC3 + (size_t)NF_ * 3 * H_ * 2;
constexpr size_t OFF_WC5  = OFF_WC4 + (size_t)NF_ * 4 * H_ * 2;
constexpr size_t OFF_MISC = SZ_GIC;
constexpr size_t OFF_H0   = OFF_MISC;                       // 256KB: sel f32 h0/h1; fused bf16 h x4
constexpr size_t OFF_H1   = OFF_H0 + (size_t)B_ * H_ * 4;
constexpr size_t OFF_SEL  = OFF_H1 + (size_t)B_ * H_ * 4;   // uint64 selm[T_]
constexpr size_t OFF_ORD  = OFF_SEL + (size_t)B_ * T_ * 4;
constexpr size_t OFF_NSEL = OFF_ORD + (size_t)B_ * T_ * 4;
constexpr size_t OFF_MAXN = OFF_NSEL + 256;
constexpr size_t OFF_FLG  = OFF_MAXN + 256;   // flagsA @+0 (32), flagsB @+128 (24), flagsC @+256 (32)
constexpr size_t OFF_POOL = OFF_FLG + 512;
constexpr size_t OFF_RING0 = OFF_POOL + (size_t)B_ * 3 * NF_ * 4;   // out0 ring [4][64][512] bf16
constexpr size_t OFF_RING1 = OFF_RING0 + 4ull * 64 * 512 * 2;       // gi1 ring [4][64][1536] bf16
constexpr size_t WS_NEED  = OFF_RING1 + 4ull * 64 * 1536 * 2;

// merged weight-prep region sizes (elements)
constexpr int WP_N0 = G_ * H_;
constexpr int WP_N1 = WP_N0 + G_ * H_;
constexpr int WP_N2 = WP_N1 + G_ * E_;
constexpr int WP_N3 = WP_N2 + G_ * H_;
constexpr int WP_N4 = WP_N3 + NF_ * 3 * H_;
constexpr int WP_N5 = WP_N4 + NF_ * 4 * H_;
constexpr int WP_N6 = WP_N5 + NF_ * 5 * H_;

// coherent (fabric-level, L1/L2-bypass) access helpers
#define CLOAD4(dst, ptr) \
    asm volatile("global_load_dwordx4 %0, %1, off sc0 sc1" : "=v"(dst) : "v"(ptr))
#define CLOAD2(dst, ptr) \
    asm volatile("global_load_dwordx2 %0, %1, off sc0 sc1" : "=v"(dst) : "v"(ptr))
#define CWAIT() do { \
    asm volatile("s_waitcnt vmcnt(0)" ::: "memory"); \
    __builtin_amdgcn_sched_barrier(0); } while (0)
#define CSTORE4(ptr, val) \
    asm volatile("global_store_dword %0, %1, off sc0 sc1" :: "v"(ptr), "v"(val) : "memory")
#define CSTORE8(ptr, val) \
    asm volatile("global_store_dwordx2 %0, %1, off sc0 sc1" :: "v"(ptr), "v"(val) : "memory")
#define CSTORE2(ptr, val) \
    asm volatile("global_store_short %0, %1, off sc0 sc1" :: "v"(ptr), "v"(val) : "memory")

__device__ __forceinline__ float sigm(float x) { return 1.f / (1.f + expf(-x)); }
__device__ __forceinline__ float b2f(unsigned short u) {
    return __uint_as_float(((unsigned int)u) << 16);
}
__device__ __forceinline__ unsigned short f2bu(float x) {
    __hip_bfloat16 h = __float2bfloat16(x);
    return *(unsigned short*)&h;
}

template<int NWG>
__device__ __forceinline__ void bar_wait(const int* flags, int t, int tid) {
    if (tid < 64) {
        int v;
        for (;;) {
            asm volatile("global_load_dword %0, %1, off sc0 sc1\n\t"
                         "s_waitcnt vmcnt(0)"
                         : "=v"(v) : "v"(flags + (tid & (NWG - 1))) : "memory");
            if (__all(v >= t)) break;
            __builtin_amdgcn_s_sleep(1);
        }
    }
    __syncthreads();
}

// poll first N flags (N need not be pow2) until all >= thresh
template<int N>
__device__ __forceinline__ void poll_ge(const int* flags, int thresh, int tid) {
    if (tid < 64) {
        const int idx = (tid < N) ? tid : 0;
        int v;
        for (;;) {
            asm volatile("global_load_dword %0, %1, off sc0 sc1\n\t"
                         "s_waitcnt vmcnt(0)"
                         : "=v"(v) : "v"(flags + idx) : "memory");
            if (__all(v >= thresh)) break;
            __builtin_amdgcn_s_sleep(1);
        }
    }
    __syncthreads();
}

// 128-WG variant for rec_sel
__device__ __forceinline__ void bar_wait128(const int* flags, int t, int tid) {
    if (tid < 64) {
        int v1, v2;
        for (;;) {
            asm volatile("global_load_dword %0, %2, off sc0 sc1\n\t"
                         "global_load_dword %1, %3, off sc0 sc1\n\t"
                         "s_waitcnt vmcnt(0)"
                         : "=&v"(v1), "=&v"(v2)
                         : "v"(flags + tid), "v"(flags + tid + 64) : "memory");
            if (__all((v1 >= t) && (v2 >= t))) break;
            __builtin_amdgcn_s_sleep(1);
        }
    }
    __syncthreads();
}

__device__ __forceinline__ void bar_arrive(int* flags, int t, int tid, int idx) {
    asm volatile("s_waitcnt vmcnt(0)" ::: "memory");
    __syncthreads();
    if (tid == 0) { int pv = t + 1; CSTORE4(flags + idx, pv); }
}

// =====================================================================
// fp32 tiled GEMM — gi_c only (argmax precision). Verified r10/r11.
// =====================================================================
__global__ __launch_bounds__(256) void gemm_f32(
    const float* __restrict__ A, const float* __restrict__ W,
    const float* __restrict__ bias, float* __restrict__ Cf,
    int N, int K, int ldA)
{
    __shared__ float As[16 * 68];
    __shared__ float Bs[16 * 68];
    const int tid = threadIdx.x;
    const int tx = tid & 15, ty = tid >> 4;
    const int id = blockIdx.x;
    const int sup = id / 384, rr = id % 384;
    const int bx = sup * 16 + (rr & 15);
    const int n0 = (rr >> 4) * 64;

    float acc[4][4] = {};
    const int rl = tid >> 2, kl = (tid & 3) * 4;
    const float* __restrict__ ap = A + ((size_t)bx * 64 + rl) * (size_t)ldA + kl;
    const float* __restrict__ wrow = W + (size_t)(n0 + rl) * (size_t)K + kl;

    for (int k0 = 0; k0 < K; k0 += 16) {
        float4 av = *(const float4*)(ap + k0);
        float4 wv = *(const float4*)(wrow + k0);
        __syncthreads();
        As[(kl+0)*68+rl] = av.x; As[(kl+1)*68+rl] = av.y;
        As[(kl+2)*68+rl] = av.z; As[(kl+3)*68+rl] = av.w;
        Bs[(kl+0)*68+rl] = wv.x; Bs[(kl+1)*68+rl] = wv.y;
        Bs[(kl+2)*68+rl] = wv.z; Bs[(kl+3)*68+rl] = wv.w;
        __syncthreads();
        #pragma unroll
        for (int kk = 0; kk < 16; ++kk) {
            const float4 a4 = *(const float4*)&As[kk*68 + ty*4];
            const float4 w4 = *(const float4*)&Bs[kk*68 + tx*4];
            acc[0][0]=fmaf(a4.x,w4.x,acc[0][0]); acc[0][1]=fmaf(a4.x,w4.y,acc[0][1]);
            acc[0][2]=fmaf(a4.x,w4.z,acc[0][2]); acc[0][3]=fmaf(a4.x,w4.w,acc[0][3]);
            acc[1][0]=fmaf(a4.y,w4.x,acc[1][0]); acc[1][1]=fmaf(a4.y,w4.y,acc[1][1]);
            acc[1][2]=fmaf(a4.y,w4.z,acc[1][2]); acc[1][3]=fmaf(a4.y,w4.w,acc[1][3]);
            acc[2][0]=fmaf(a4.z,w4.x,acc[2][0]); acc[2][1]=fmaf(a4.z,w4.y,acc[2][1]);
            acc[2][2]=fmaf(a4.z,w4.z,acc[2][2]); acc[2][3]=fmaf(a4.z,w4.w,acc[2][3]);
            acc[3][0]=fmaf(a4.w,w4.x,acc[3][0]); acc[3][1]=fmaf(a4.w,w4.y,acc[3][1]);
            acc[3][2]=fmaf(a4.w,w4.z,acc[3][2]); acc[3][3]=fmaf(a4.w,w4.w,acc[3][3]);
        }
    }
    #pragma unroll
    for (int i = 0; i < 4; ++i) {
        int m = bx * 64 + ty*4 + i;
        size_t co = (size_t)m * (size_t)N + n0 + tx*4;
        #pragma unroll
        for (int j = 0; j < 4; ++j)
            Cf[co + j] = acc[i][j] + bias[n0 + tx*4 + j];
    }
}

// =====================================================================
// bf16 MFMA GEMM (verified r6/r12) — used for gi0 and the convs.
// =====================================================================
template<int AMODE, int OMODE>
__global__ __launch_bounds__(256) void gemm_mfma(
    const float* __restrict__ A, const unsigned short* __restrict__ Wb,
    const float* __restrict__ bias,
    unsigned short* __restrict__ Cb, unsigned int* __restrict__ pool,
    int N, int K, int ldA, int rowsPerB, int tilesPerB, int nb,
    const int* __restrict__ order, const int* __restrict__ nsel, int poolOff)
{
    __shared__ __align__(16) unsigned short As[64][40];
    __shared__ __align__(16) unsigned short Bs[64][40];
    __shared__ const float* rowp[64];

    const int tid = threadIdx.x;
    const int l = tid & 63;
    const int q = tid >> 6;
    const int per = 16 * nb;
    const int id = blockIdx.x;
    const int sup = id / per, rr2 = id % per;
    const int mblk = sup * 16 + (rr2 & 15);
    const int n0 = (rr2 >> 4) * 64;

    int tileb = 0, tilet0 = 0;
    if (AMODE != 0) { tileb = mblk / tilesPerB; tilet0 = (mblk % tilesPerB) * 64; }

    if (tid < 64) {
        const float* p = nullptr;
        if (AMODE == 0) {
            p = A + ((size_t)mblk * 64 + tid) * (size_t)ldA;
        } else if (AMODE == 1) {
            int t = tilet0 + tid;
            if (t < nsel[tileb]) {
                int src = order[tileb * T_ + t];
                p = A + ((size_t)tileb * T_ + src) * (size_t)ldA;
            }
        } else {
            int t = tilet0 + tid;
            if (t < rowsPerB) p = A + ((size_t)tileb * T_ + t) * (size_t)ldA;
        }
        rowp[tid] = p;
    }
    __syncthreads();

    f32x4 acc0 = {0.f,0.f,0.f,0.f}, acc1 = {0.f,0.f,0.f,0.f};
    f32x4 acc2 = {0.f,0.f,0.f,0.f}, acc3 = {0.f,0.f,0.f,0.f};

    const int r = tid & 63, seg = tid >> 6;
    const float* ap = rowp[r];
    if (ap) ap += seg * 8;
    const unsigned short* wrow = Wb + (size_t)(n0 + r) * (size_t)K + seg * 8;

    for (int k0 = 0; k0 < K; k0 += 32) {
        float4 fa = make_float4(0,0,0,0), fb = make_float4(0,0,0,0);
        if (ap) { fa = *(const float4*)(ap + k0); fb = *(const float4*)(ap + k0 + 4); }
        const uint4 wv = *(const uint4*)(wrow + k0);
        __syncthreads();
        uint4 pk;
        pk.x = (unsigned)f2bu(fa.x) | ((unsigned)f2bu(fa.y) << 16);
        pk.y = (unsigned)f2bu(fa.z) | ((unsigned)f2bu(fa.w) << 16);
        pk.z = (unsigned)f2bu(fb.x) | ((unsigned)f2bu(fb.y) << 16);
        pk.w = (unsigned)f2bu(fb.z) | ((unsigned)f2bu(fb.w) << 16);
        *(uint4*)&As[r][seg * 8] = pk;
        *(uint4*)&Bs[r][seg * 8] = wv;
        __syncthreads();
        const bf16x8 av = *(const bf16x8*)&As[q * 16 + (l & 15)][(l >> 4) * 8];
        const bf16x8 b0 = *(const bf16x8*)&Bs[ 0 + (l & 15)][(l >> 4) * 8];
        const bf16x8 b1 = *(const bf16x8*)&Bs[16 + (l & 15)][(l >> 4) * 8];
        const bf16x8 b2 = *(const bf16x8*)&Bs[32 + (l & 15)][(l >> 4) * 8];
        const bf16x8 b3 = *(const bf16x8*)&Bs[48 + (l & 15)][(l >> 4) * 8];
        acc0 = __builtin_amdgcn_mfma_f32_16x16x32_bf16(av, b0, acc0, 0, 0, 0);
        acc1 = __builtin_amdgcn_mfma_f32_16x16x32_bf16(av, b1, acc1, 0, 0, 0);
        acc2 = __builtin_amdgcn_mfma_f32_16x16x32_bf16(av, b2, acc2, 0, 0, 0);
        acc3 = __builtin_amdgcn_mfma_f32_16x16x32_bf16(av, b3, acc3, 0, 0, 0);
    }

    f32x4 accs[4] = {acc0, acc1, acc2, acc3};
    if (OMODE == 0) {
        const int mbase = (AMODE == 0) ? mblk * 64 : tileb * T_ + tilet0;
        #pragma unroll
        for (int s = 0; s < 4; ++s) {
            const int col = n0 + s * 16 + (l & 15);
            const float bv = bias[col];
            #pragma unroll
            for (int reg = 0; reg < 4; ++reg) {
                const int m = mbase + q * 16 + (l >> 4) * 4 + reg;
                Cb[(size_t)m * (size_t)N + col] = f2bu(accs[s][reg] + bv);
            }
        }
    } else {
        #pragma unroll
        for (int s = 0; s < 4; ++s) {
            const int col = n0 + s * 16 + (l & 15);
            const float bv = bias[col];
            float mx = 0.f;
            #pragma unroll
            for (int reg = 0; reg < 4; ++reg) {
                const int t = tilet0 + q * 16 + (l >> 4) * 4 + reg;
                const float val = fmaxf(accs[s][reg] + bv, 0.f);
                if (t < rowsPerB) mx = fmaxf(mx, val);
            }
            mx = fmaxf(mx, __shfl_xor(mx, 16));
            mx = fmaxf(mx, __shfl_xor(mx, 32));
            if (l < 16)
                atomicMax(&pool[(size_t)tileb * (3*NF_) + poolOff + n0 + s*16 + l],
                          __float_as_uint(mx));
        }
    }
}

// =====================================================================
// Merged weight f32 -> bf16 prep (verified r12).
// =====================================================================
__global__ void wprep_all(
    const float* __restrict__ w0, const float* __restrict__ w1,
    const float* __restrict__ w2, const float* __restrict__ w3,
    const float* __restrict__ w4, const float* __restrict__ w5,
    const float* __restrict__ w6, unsigned short* __restrict__ o)
{
    const int i = blockIdx.x * 256 + threadIdx.x;
    if (i >= WP_N6) return;
    float v;
    if      (i < WP_N0) v = w0[i];
    else if (i < WP_N1) v = w1[i - WP_N0];
    else if (i < WP_N2) v = w2[i - WP_N1];
    else if (i < WP_N3) v = w3[i - WP_N2];
    else if (i < WP_N4) v = w4[i - WP_N3];
    else if (i < WP_N5) v = w5[i - WP_N4];
    else                v = w6[i - WP_N5];
    o[i] = f2bu(v);
}

// =====================================================================
// Selector GRU v7 (unchanged, verified r11/r12) — 128 WGs x 512 thr.
// =====================================================================
__device__ __forceinline__ void gates_abs(
    const float* __restrict__ hs, int b, int base,
    const float* __restrict__ wR, const float* __restrict__ wZ,
    const float* __restrict__ wN,
    float& aR, float& aZ, float& aN)
{
    #pragma unroll 4
    for (int kq = 0; kq < 32; ++kq) {
        const int k = base + kq * 4;
        const float hv0 = hs[(k+0)*64 + b];
        const float hv1 = hs[(k+1)*64 + b];
        const float hv2 = hs[(k+2)*64 + b];
        const float hv3 = hs[(k+3)*64 + b];
        const float4 wr = *(const float4*)(wR + k);
        const float4 wz = *(const float4*)(wZ + k);
        const float4 wn = *(const float4*)(wN + k);
        aR = fmaf(hv0, wr.x, aR); aR = fmaf(hv1, wr.y, aR);
        aR = fmaf(hv2, wr.z, aR); aR = fmaf(hv3, wr.w, aR);
        aZ = fmaf(hv0, wz.x, aZ); aZ = fmaf(hv1, wz.y, aZ);
        aZ = fmaf(hv2, wz.z, aZ); aZ = fmaf(hv3, wz.w, aZ);
        aN = fmaf(hv0, wn.x, aN); aN = fmaf(hv1, wn.y, aN);
        aN = fmaf(hv2, wn.z, aN); aN = fmaf(hv3, wn.w, aN);
    }
}

__device__ __forceinline__ void dot_abs(
    const float* __restrict__ hs, int b, int base,
    const float* __restrict__ dWl, float& dot)
{
    #pragma unroll 4
    for (int kq = 0; kq < 16; ++kq) {
        const int k = base + kq * 4;
        const float hv0 = hs[(k+0)*64 + b];
        const float hv1 = hs[(k+1)*64 + b];
        const float hv2 = hs[(k+2)*64 + b];
        const float hv3 = hs[(k+3)*64 + b];
        const float4 dv = *(const float4*)(dWl + k);
        dot = fmaf(hv0, dv.x, dot); dot = fmaf(hv1, dv.y, dot);
        dot = fmaf(hv2, dv.z, dot); dot = fmaf(hv3, dv.w, dot);
    }
}

__global__ __launch_bounds__(512) void rec_sel(
    const float* __restrict__ giF,
    const float* __restrict__ Whh, const float* __restrict__ bhh,
    const float* __restrict__ Ws, const float* __restrict__ bs,
    float* __restrict__ h0, float* __restrict__ h1,
    unsigned long long* __restrict__ selm, int* __restrict__ flags)
{
    __shared__ float Wl[12 * 512];
    __shared__ float dWl[512];
    __shared__ float hs[512 * 64];
    __shared__ float partR[4 * 64], partZ[4 * 64], partN[4 * 64];
    __shared__ float pdot[8 * 64];

    const int tid = threadIdx.x;
    const int b = tid & 63;
    const int w = __builtin_amdgcn_readfirstlane(tid >> 6);
    const int u = w >> 1, s = w & 1;
    const int bx = blockIdx.x;
    const int iu = bx * 4 + u;

    for (int idx = tid; idx < 12 * 512; idx += 512) {
        int rr = idx >> 9, k = idx & 511;
        int ul = rr / 3, gate = rr - ul * 3;
        Wl[idx] = Whh[((size_t)gate * 512 + bx * 4 + ul) * 512 + k];
    }
    dWl[tid] = Ws[512 + tid] - Ws[tid];
    __syncthreads();

    const float bR = bhh[iu], bZ = bhh[512 + iu], bN = bhh[1024 + iu];
    const float db = bs[1] - bs[0];
    const float* __restrict__ wR = Wl + (u*3 + 0) * 512;
    const float* __restrict__ wZ = Wl + (u*3 + 1) * 512;
    const float* __restrict__ wN = Wl + (u*3 + 2) * 512;

    float pgR = 0.f, pgZ = 0.f, pgN = 0.f;
    if (s == 0) {
        pgR = giF[(size_t)b * T_ * G_ + iu];
        pgZ = giF[(size_t)b * T_ * G_ + 512 + iu];
        pgN = giF[(size_t)b * T_ * G_ + 1024 + iu];
    }

    for (int t = 0; t <= T_; ++t) {
        const bool comp = (t < T_);
        const float* hcur = (t & 1) ? h1 : h0;
        float* hnxt = (t & 1) ? h0 : h1;

        if (t > 0) bar_wait128(flags, t, tid);

        const float* hc = hcur + (size_t)tid * 4;
        float* hd = hs + tid * 4;
        float4 a0,a1,a2,a3,a4,a5,a6,a7,a8,a9,aa,ab,ac,ad,ae,af;
        CLOAD4(a0, hc +  0*2048); CLOAD4(a1, hc +  1*2048);
        CLOAD4(a2, hc +  2*2048); CLOAD4(a3, hc +  3*2048);
        CLOAD4(a4, hc +  4*2048); CLOAD4(a5, hc +  5*2048);
        CLOAD4(a6, hc +  6*2048); CLOAD4(a7, hc +  7*2048);
        CLOAD4(a8, hc +  8*2048); CLOAD4(a9, hc +  9*2048);
        CLOAD4(aa, hc + 10*2048); CLOAD4(ab, hc + 11*2048);
        CLOAD4(ac, hc + 12*2048); CLOAD4(ad, hc + 13*2048);
        CLOAD4(ae, hc + 14*2048); CLOAD4(af, hc + 15*2048);
        CWAIT();
        *(float4*)(hd +  0*2048) = a0; *(float4*)(hd +  1*2048) = a1;
        *(float4*)(hd +  2*2048) = a2; *(float4*)(hd +  3*2048) = a3;
        *(float4*)(hd +  4*2048) = a4; *(float4*)(hd +  5*2048) = a5;
        *(float4*)(hd +  6*2048) = a6; *(float4*)(hd +  7*2048) = a7;
        *(float4*)(hd +  8*2048) = a8; *(float4*)(hd +  9*2048) = a9;
        *(float4*)(hd + 10*2048) = aa; *(float4*)(hd + 11*2048) = ab;
        *(float4*)(hd + 12*2048) = ac; *(float4*)(hd + 13*2048) = ad;
        *(float4*)(hd + 14*2048) = ae; *(float4*)(hd + 15*2048) = af;
        __syncthreads();

        float aR = (s == 0) ? bR : 0.f;
        float aZ = (s == 0) ? bZ : 0.f;
        float aN = (s == 0) ? bN : 0.f;
        float dot = 0.f, hp = 0.f;

        if (comp) {
            gates_abs(hs, b, s * 128,       wR, wZ, wN, aR, aZ, aN);
            gates_abs(hs, b, 256 + s * 128, wR, wZ, wN, aR, aZ, aN);
            if (s == 0) hp = hs[iu * 64 + b];
        }
        dot_abs(hs, b, (w < 4) ? w * 64 : 256 + (w - 4) * 64, dWl, dot);

        if (comp && s == 1) {
            partR[u*64 + b] = aR; partZ[u*64 + b] = aZ; partN[u*64 + b] = aN;
        }
        pdot[w*64 + b] = dot;
        __syncthreads();

        if (comp && s == 0) {
            aR += partR[u*64 + b]; aZ += partZ[u*64 + b]; aN += partN[u*64 + b];
            const float r = sigm(pgR + aR);
            const float z = sigm(pgZ + aZ);
            const float n = tanhf(pgN + r * aN);
            const float hn = (1.f - z) * n + z * hp;
            const float* hdst = hnxt + (size_t)iu * 64 + b;
            CSTORE4(hdst, hn);
        }

        if (t < T_) {
            bar_arrive(flags, t, tid, bx);
            if (s == 0 && t + 1 < T_) {
                const float* gp = giF + ((size_t)b * T_ + t + 1) * G_;
                pgR = gp[iu]; pgZ = gp[512 + iu]; pgN = gp[1024 + iu];
            }
        }
        if (w == 0 && t >= 1) {
            float p = pdot[0*64 + b];
            p += pdot[1*64 + b]; p += pdot[2*64 + b]; p += pdot[3*64 + b];
            p += pdot[4*64 + b]; p += pdot[5*64 + b]; p += pdot[6*64 + b];
            p += pdot[7*64 + b];
            unsigned long long m = __ballot((p + db) > 0.f);
            if (tid == 0 && bx == 0) selm[t - 1] = m;
        }
    }
}

// =====================================================================
// FUSED pipeline: layer0 (WG 0-31) -> gi1 step-GEMM (WG 32-55) ->
// layer1 (WG 56-87). Rings depth 4; coherent stores + flag barriers
// (same primitives verified since r8). 88 WGs, 1/CU, co-resident.
//   flagsA[32]: layer0 h(t+1)+out0(t) published
//   flagsB[24]: gi1(t) published
//   flagsC[32]: layer1 h(t+1) published
// Dependency: A(t): flagsA>=t, flagsB>=t-3 | B(t): flagsA>=t+1,
// flagsC>=t-3 | C(t): flagsB>=t+1, flagsC>=t.  Monotone -> no deadlock.
// =====================================================================
template<int ROLE>   // 0 = layer0, 1 = layer1
__device__ __forceinline__ void layer_body(
    int wg, int tid,
    const unsigned short* __restrict__ gi0,     // ROLE0: bulk gi0
    const unsigned short* __restrict__ ring1,   // ROLE1: gi1 ring
    unsigned short* __restrict__ ring0,         // ROLE0: out0 ring
    const unsigned short* __restrict__ wbf, const float* __restrict__ bhh,
    const int* __restrict__ nselp, const int* __restrict__ maxnp,
    unsigned short* __restrict__ hA, unsigned short* __restrict__ hB,
    float* __restrict__ outp,
    int* __restrict__ flagsSelf, const int* __restrict__ flagsB,
    unsigned char* ldsW, unsigned char* ldsH, float* gbuf)
{
    const int l = tid & 63;
    const int q = tid >> 6;
    const int i0 = wg * 16;
    const int b = tid & 63;

    for (int idx = tid; idx < 48 * 64; idx += 256) {
        const int r = idx >> 6, seg = idx & 63;
        const int tier = r >> 4, ul = r & 15;
        const float4 v = *(const float4*)((const char*)wbf
            + ((size_t)(tier * 512 + i0 + ul) * 512) * 2 + seg * 16);
        *(float4*)(ldsW + r * 1040 + seg * 16) = v;
    }
    const float4 bRv = *(const float4*)(bhh + i0 + 4 * q);
    const float4 bZv = *(const float4*)(bhh + 512 + i0 + 4 * q);
    const float4 bNv = *(const float4*)(bhh + 1024 + i0 + 4 * q);
    const int ns = nselp[b];
    const int TOTAL = *maxnp;

    const unsigned short* gbase = gi0 + (size_t)b * T_ * (size_t)G_ + i0 + 4 * q;
    uint2 gR, gZ, gN;
    if (ROLE == 0) {
        gR = *(const uint2*)(gbase);
        gZ = *(const uint2*)(gbase + 512);
        gN = *(const uint2*)(gbase + 1024);
    }
    __syncthreads();

    for (int t = 0; t < TOTAL; ++t) {
        const unsigned short* hcur = (t & 1) ? hB : hA;
        unsigned short* hnxt = (t & 1) ? hA : hB;

        if (t > 0) bar_wait<32>(flagsSelf, t, tid);
        if (ROLE == 0) {
            if (t >= 4) poll_ge<24>(flagsB, t - 3, tid);   // ring0 slot free
        } else {
            poll_ge<24>(flagsB, t + 1, tid);               // gi1(t) ready
            const unsigned short* gp = ring1 + ((size_t)(t & 3) * 64 + b) * G_ + i0 + 4 * q;
            CLOAD2(gR, gp); CLOAD2(gZ, gp + 512); CLOAD2(gN, gp + 1024);
        }

        {
            const char* src = (const char*)hcur + tid * 256;
            float4 s0, s1, s2, s3, s4, s5, s6, s7, s8, s9, sa, sb_, sc, sd, se, sf;
            CLOAD4(s0, src + 0 * 16);  CLOAD4(s1, src + 1 * 16);
            CLOAD4(s2, src + 2 * 16);  CLOAD4(s3, src + 3 * 16);
            CLOAD4(s4, src + 4 * 16);  CLOAD4(s5, src + 5 * 16);
            CLOAD4(s6, src + 6 * 16);  CLOAD4(s7, src + 7 * 16);
            CLOAD4(s8, src + 8 * 16);  CLOAD4(s9, src + 9 * 16);
            CLOAD4(sa, src + 10 * 16); CLOAD4(sb_, src + 11 * 16);
            CLOAD4(sc, src + 12 * 16); CLOAD4(sd, src + 13 * 16);
            CLOAD4(se, src + 14 * 16); CLOAD4(sf, src + 15 * 16);
            CWAIT();    // also lands ROLE1's gi CLOAD2s
            char* dst = (char*)ldsH + (tid >> 2) * 1040 + (tid & 3) * 256;
            *(float4*)(dst + 0 * 16) = s0;  *(float4*)(dst + 1 * 16) = s1;
            *(float4*)(dst + 2 * 16) = s2;  *(float4*)(dst + 3 * 16) = s3;
            *(float4*)(dst + 4 * 16) = s4;  *(float4*)(dst + 5 * 16) = s5;
            *(float4*)(dst + 6 * 16) = s6;  *(float4*)(dst + 7 * 16) = s7;
            *(float4*)(dst + 8 * 16) = s8;  *(float4*)(dst + 9 * 16) = s9;
            *(float4*)(dst + 10 * 16) = sa; *(float4*)(dst + 11 * 16) = sb_;
            *(float4*)(dst + 12 * 16) = sc; *(float4*)(dst + 13 * 16) = sd;
            *(float4*)(dst + 14 * 16) = se; *(float4*)(dst + 15 * 16) = sf;
        }
        __syncthreads();

        f32x4 ac0 = {0.f, 0.f, 0.f, 0.f};
        f32x4 ac1 = {0.f, 0.f, 0.f, 0.f};
        f32x4 ac2 = {0.f, 0.f, 0.f, 0.f};
        {
            const char* ab2 = (const char*)ldsH + (q * 16 + (l & 15)) * 1040 + (l >> 4) * 16;
            const char* bb = (const char*)ldsW + (l & 15) * 1040 + (l >> 4) * 16;
            #pragma unroll
            for (int ks = 0; ks < 16; ++ks) {
                const bf16x8 av = *(const bf16x8*)(ab2 + ks * 64);
                const bf16x8 w0 = *(const bf16x8*)(bb + ks * 64);
                const bf16x8 w1 = *(const bf16x8*)(bb + 16 * 1040 + ks * 64);
                const bf16x8 w2 = *(const bf16x8*)(bb + 32 * 1040 + ks * 64);
                ac0 = __builtin_amdgcn_mfma_f32_16x16x32_bf16(av, w0, ac0, 0, 0, 0);
                ac1 = __builtin_amdgcn_mfma_f32_16x16x32_bf16(av, w1, ac1, 0, 0, 0);
                ac2 = __builtin_amdgcn_mfma_f32_16x16x32_bf16(av, w2, ac2, 0, 0, 0);
            }
        }
        {
            const int gcol = q * 16 + 4 * (l >> 4);
            const int grow = l & 15;
            #pragma unroll
            for (int r = 0; r < 4; ++r) {
                gbuf[grow * 66 + gcol + r]        = ac0[r];
                gbuf[(16 + grow) * 66 + gcol + r] = ac1[r];
                gbuf[(32 + grow) * 66 + gcol + r] = ac2[r];
            }
        }
        __syncthreads();

        {
            const ushort4 hp4 = *(const ushort4*)((const char*)ldsH
                                 + b * 1040 + (i0 + 4 * q) * 2);
            const unsigned short hpb[4] = {hp4.x, hp4.y, hp4.z, hp4.w};
            const float irv[4] = {b2f(gR.x & 0xffff), b2f(gR.x >> 16),
                                  b2f(gR.y & 0xffff), b2f(gR.y >> 16)};
            const float izv[4] = {b2f(gZ.x & 0xffff), b2f(gZ.x >> 16),
                                  b2f(gZ.y & 0xffff), b2f(gZ.y >> 16)};
            const float inv[4] = {b2f(gN.x & 0xffff), b2f(gN.x >> 16),
                                  b2f(gN.y & 0xffff), b2f(gN.y >> 16)};
            float4 o;
            unsigned short ob[4];
            #pragma unroll
            for (int j = 0; j < 4; ++j) {
                const int u2 = 4 * q + j;
                const float hr = gbuf[u2 * 66 + b]        + bRv[j];
                const float hz = gbuf[(16 + u2) * 66 + b] + bZv[j];
                const float hn = gbuf[(32 + u2) * 66 + b] + bNv[j];
                const float rr = sigm(irv[j] + hr);
                const float zz = sigm(izv[j] + hz);
                const float nn = tanhf(inv[j] + rr * hn);
                const float hpf = b2f(hpb[j]);
                float hv = (1.f - zz) * nn + zz * hpf;
                if (t >= ns) hv = hpf;
                ((float*)&o)[j] = hv;
                ob[j] = f2bu(hv);
            }
            uint2 hpk;
            hpk.x = (unsigned)ob[0] | ((unsigned)ob[1] << 16);
            hpk.y = (unsigned)ob[2] | ((unsigned)ob[3] << 16);
            if (ROLE == 0) {
                const unsigned short* rdst = ring0 + ((size_t)(t & 3) * 64 + b) * 512 + i0 + 4 * q;
                CSTORE8(rdst, hpk);
            } else {
                if (t < ns)
                    *(float4*)(outp + ((size_t)b * T_ + t) * 512 + i0 + 4 * q) = o;
            }
            const unsigned short* hdst = hnxt + (size_t)b * 512 + i0 + 4 * q;
            CSTORE8(hdst, hpk);
        }

        bar_arrive(flagsSelf, t, tid, wg);   // every step (consumers need last flag)
        if (ROLE == 0 && t + 1 < TOTAL) {
            const unsigned short* gp = gbase + (size_t)(t + 1) * G_;
            gR = *(const uint2*)gp;
            gZ = *(const uint2*)(gp + 512);
            gN = *(const uint2*)(gp + 1024);
        }
    }
}

__global__ __launch_bounds__(256) void rec_fused(
    const unsigned short* __restrict__ gi0,
    const unsigned short* __restrict__ wbf0,
    const unsigned short* __restrict__ wbf1,
    const unsigned short* __restrict__ wih1b,
    const float* __restrict__ bhh0, const float* __restrict__ bhh1,
    const float* __restrict__ bih1,
    const int* __restrict__ nselp, const int* __restrict__ maxnp,
    unsigned short* __restrict__ h0A, unsigned short* __restrict__ h1A,
    unsigned short* __restrict__ h0C, unsigned short* __restrict__ h1C,
    unsigned short* __restrict__ ring0, unsigned short* __restrict__ ring1,
    float* __restrict__ outp,
    int* __restrict__ flagsA, int* __restrict__ flagsB, int* __restrict__ flagsC)
{
    __shared__ __align__(16) unsigned char ldsX[64 * 1040];
    __shared__ __align__(16) unsigned char ldsY[64 * 1040];
    __shared__ float gbuf[48 * 66];

    const int tid = threadIdx.x;
    const int bx = blockIdx.x;

    if (bx < 32) {
        layer_body<0>(bx, tid, gi0, nullptr, ring0, wbf0, bhh0, nselp, maxnp,
                      h0A, h1A, nullptr, flagsA, flagsB, ldsX, ldsY, gbuf);
    } else if (bx < 56) {
        // ---- gi1 step-GEMM: wg owns 64 n-rows of Wih1 ----
        const int wg = bx - 32;
        const int l = tid & 63;
        const int q = tid >> 6;
        const int n0 = wg * 64;

        for (int idx = tid; idx < 64 * 64; idx += 256) {
            const int r = idx >> 6, seg = idx & 63;
            const float4 v = *(const float4*)((const char*)wih1b
                + ((size_t)(n0 + r) * 512) * 2 + seg * 16);
            *(float4*)(ldsX + r * 1040 + seg * 16) = v;
        }
        float bv[4];
        #pragma unroll
        for (int s = 0; s < 4; ++s) bv[s] = bih1[n0 + s * 16 + (l & 15)];
        const int TOTAL = *maxnp;
        __syncthreads();

        for (int t = 0; t < TOTAL; ++t) {
            poll_ge<32>(flagsA, t + 1, tid);              // out0(t) ready
            if (t >= 4) poll_ge<32>(flagsC, t - 3, tid);  // ring1 slot free

            {   // stage out0(t) 64KB from ring0 slot
                const char* src = (const char*)ring0 + (size_t)(t & 3) * 65536 + tid * 256;
                float4 s0, s1, s2, s3, s4, s5, s6, s7, s8, s9, sa, sb_, sc, sd, se, sf;
                CLOAD4(s0, src + 0 * 16);  CLOAD4(s1, src + 1 * 16);
                CLOAD4(s2, src + 2 * 16);  CLOAD4(s3, src + 3 * 16);
                CLOAD4(s4, src + 4 * 16);  CLOAD4(s5, src + 5 * 16);
                CLOAD4(s6, src + 6 * 16);  CLOAD4(s7, src + 7 * 16);
                CLOAD4(s8, src + 8 * 16);  CLOAD4(s9, src + 9 * 16);
                CLOAD4(sa, src + 10 * 16); CLOAD4(sb_, src + 11 * 16);
                CLOAD4(sc, src + 12 * 16); CLOAD4(sd, src + 13 * 16);
                CLOAD4(se, src + 14 * 16); CLOAD4(sf, src + 15 * 16);
                CWAIT();
                char* dst = (char*)ldsY + (tid >> 2) * 1040 + (tid & 3) * 256;
                *(float4*)(dst + 0 * 16) = s0;  *(float4*)(dst + 1 * 16) = s1;
                *(float4*)(dst + 2 * 16) = s2;  *(float4*)(dst + 3 * 16) = s3;
                *(float4*)(dst + 4 * 16) = s4;  *(float4*)(dst + 5 * 16) = s5;
                *(float4*)(dst + 6 * 16) = s6;  *(float4*)(dst + 7 * 16) = s7;
                *(float4*)(dst + 8 * 16) = s8;  *(float4*)(dst + 9 * 16) = s9;
                *(float4*)(dst + 10 * 16) = sa; *(float4*)(dst + 11 * 16) = sb_;
                *(float4*)(dst + 12 * 16) = sc; *(float4*)(dst + 13 * 16) = sd;
                *(float4*)(dst + 14 * 16) = se; *(float4*)(dst + 15 * 16) = sf;
            }
            __syncthreads();

            f32x4 acc0 = {0.f,0.f,0.f,0.f}, acc1 = {0.f,0.f,0.f,0.f};
            f32x4 acc2 = {0.f,0.f,0.f,0.f}, acc3 = {0.f,0.f,0.f,0.f};
            {
                const char* ab2 = (const char*)ldsY + (q * 16 + (l & 15)) * 1040 + (l >> 4) * 16;
                const char* bb = (const char*)ldsX + (l & 15) * 1040 + (l >> 4) * 16;
                #pragma unroll
                for (int ks = 0; ks < 16; ++ks) {
                    const bf16x8 av = *(const bf16x8*)(ab2 + ks * 64);
                    const bf16x8 b0 = *(const bf16x8*)(bb + ks * 64);
                    const bf16x8 b1 = *(const bf16x8*)(bb + 16 * 1040 + ks * 64);
                    const bf16x8 b2 = *(const bf16x8*)(bb + 32 * 1040 + ks * 64);
                    const bf16x8 b3 = *(const bf16x8*)(bb + 48 * 1040 + ks * 64);
                    acc0 = __builtin_amdgcn_mfma_f32_16x16x32_bf16(av, b0, acc0, 0, 0, 0);
                    acc1 = __builtin_amdgcn_mfma_f32_16x16x32_bf16(av, b1, acc1, 0, 0, 0);
                    acc2 = __builtin_amdgcn_mfma_f32_16x16x32_bf16(av, b2, acc2, 0, 0, 0);
                    acc3 = __builtin_amdgcn_mfma_f32_16x16x32_bf16(av, b3, acc3, 0, 0, 0);
                }
            }
            f32x4 accs[4] = {acc0, acc1, acc2, acc3};
            #pragma unroll
            for (int s = 0; s < 4; ++s) {
                const int col = n0 + s * 16 + (l & 15);
                #pragma unroll
                for (int reg = 0; reg < 4; ++reg) {
                    const int m = q * 16 + (l >> 4) * 4 + reg;   // batch
                    const unsigned val = f2bu(accs[s][reg] + bv[s]);
                    const unsigned short* dst = ring1 + ((size_t)(t & 3) * 64 + m) * G_ + col;
                    CSTORE2(dst, val);
                }
            }
            bar_arrive(flagsB, t, tid, wg);
        }
    } else {
        layer_body<1>(bx - 56, tid, nullptr, ring1, nullptr, wbf1, bhh1, nselp, maxnp,
                      h0C, h1C, outp, flagsC, flagsB, ldsX, ldsY, gbuf);
    }
}

// =====================================================================
// Per-batch selection post-processing (unchanged, selm version).
// =====================================================================
__global__ void build_order_k(const int* __restrict__ mask,
                              const unsigned long long* __restrict__ selm,
                              int* __restrict__ order, int* __restrict__ nsel,
                              int* __restrict__ maxn)
{
    const int b = threadIdx.x;
    int lens = 0;
    for (int t = 0; t < T_; ++t) lens += (mask[b * T_ + t] != 0);
    int cnt = 0;
    for (int t = 0; t < T_; ++t) {
        int s = (int)((selm[t] >> b) & 1ull);
        if (t == 0) s = 1;
        if (t == lens - 1) s = 1;
        if (t >= lens) s = 0;
        if (s) order[b * T_ + (cnt++)] = t;
    }
    nsel[b] = cnt;
    int c2 = cnt;
    for (int t = 0; t < T_; ++t) {
        int s = (int)((selm[t] >> b) & 1ull);
        if (t == 0) s = 1;
        if (t == lens - 1) s = 1;
        if (t >= lens) s = 0;
        if (!s) order[b * T_ + (c2++)] = t;
    }
    __shared__ int red[64];
    red[b] = cnt;
    __syncthreads();
    if (b == 0) {
        int m = 0;
        for (int qq = 0; qq < 64; ++qq) m = max(m, red[qq]);
        *maxn = m;
    }
}

// =====================================================================
// Final linear (unchanged).
// =====================================================================
__global__ void final_k(const unsigned int* __restrict__ pool,
                        const float* __restrict__ Wo, const float* __restrict__ bo,
                        float* __restrict__ out)
{
    const int b = threadIdx.x;
    float s = bo[0];
    for (int f = 0; f < 3 * NF_; ++f)
        s = fmaf(__uint_as_float(pool[b * (3*NF_) + f]), Wo[f], s);
    out[b] = s;
}

// =====================================================================
extern "C" void kernel_launch(void* const* d_in, const int* in_sizes, int n_in,
                              void* d_out, int out_size, void* d_ws, size_t ws_size,
                              hipStream_t stream)
{
    (void)in_sizes; (void)n_in; (void)out_size;
    const float* emb   = (const float*)d_in[0];
    const int*   mask  = (const int*)d_in[1];
    const float* Wih_c = (const float*)d_in[2];
    const float* Whh_c = (const float*)d_in[3];
    const float* bih_c = (const float*)d_in[4];
    const float* bhh_c = (const float*)d_in[5];
    const float* Ws    = (const float*)d_in[6];
    const float* bs    = (const float*)d_in[7];
    const float* Wih0  = (const float*)d_in[8];
    const float* Whh0  = (const float*)d_in[9];
    const float* bih0  = (const float*)d_in[10];
    const float* bhh0  = (const float*)d_in[11];
    const float* Wih1  = (const float*)d_in[12];
    const float* Whh1  = (const float*)d_in[13];
    const float* bih1  = (const float*)d_in[14];
    const float* bhh1  = (const float*)d_in[15];
    const float* Wc3   = (const float*)d_in[16];
    const float* bc3   = (const float*)d_in[17];
    const float* Wc4   = (const float*)d_in[18];
    const float* bc4   = (const float*)d_in[19];
    const float* Wc5   = (const float*)d_in[20];
    const float* bc5   = (const float*)d_in[21];
    const float* Wo    = (const float*)d_in[22];
    const float* bo    = (const float*)d_in[23];

    if (ws_size < WS_NEED) return;
    char* ws = (char*)d_ws;
    float*          giC    = (float*)(ws + OFF_GI);
    unsigned short* giB    = (unsigned short*)(ws + OFF_GI);
    float*          outbuf = (float*)(ws + OFF_OUT);
    unsigned short* wpack  = (unsigned short*)(ws + OFF_WBF0);
    unsigned short* wbf0   = (unsigned short*)(ws + OFF_WBF0);
    unsigned short* wbf1   = (unsigned short*)(ws + OFF_WBF1);
    unsigned short* wih0b  = (unsigned short*)(ws + OFF_WIH0);
    unsigned short* wih1b  = (unsigned short*)(ws + OFF_WIH1);
    unsigned short* wc3b   = (unsigned short*)(ws + OFF_WC3);
    unsigned short* wc4b   = (unsigned short*)(ws + OFF_WC4);
    unsigned short* wc5b   = (unsigned short*)(ws + OFF_WC5);
    float*          h0f    = (float*)(ws + OFF_H0);
    float*          h1f    = (float*)(ws + OFF_H1);
    unsigned short* h0A    = (unsigned short*)(ws + OFF_H0);
    unsigned short* h1A    = (unsigned short*)(ws + OFF_H0 + 65536);
    unsigned short* h0C    = (unsigned short*)(ws + OFF_H0 + 131072);
    unsigned short* h1C    = (unsigned short*)(ws + OFF_H0 + 196608);
    unsigned long long* selm = (unsigned long long*)(ws + OFF_SEL);
    int*            order  = (int*)(ws + OFF_ORD);
    int*            nsel   = (int*)(ws + OFF_NSEL);
    int*            maxn   = (int*)(ws + OFF_MAXN);
    int*            flagsA = (int*)(ws + OFF_FLG);
    int*            flagsB = (int*)(ws + OFF_FLG + 128);
    int*            flagsC = (int*)(ws + OFF_FLG + 256);
    unsigned int*   pool   = (unsigned int*)(ws + OFF_POOL);
    unsigned short* ring0  = (unsigned short*)(ws + OFF_RING0);
    unsigned short* ring1  = (unsigned short*)(ws + OFF_RING1);

    // 1. gi_c = emb @ Wih_c^T + bih_c  (fp32 — argmax precision)
    gemm_f32<<<dim3(12288), 256, 0, stream>>>(emb, Wih_c, bih_c, giC, G_, E_, E_);
    // 2. selector recurrence -> selm
    hipMemsetAsync(flagsA, 0, 512, stream);
    hipMemsetAsync(h0f, 0, (size_t)B_ * H_ * 4, stream);
    rec_sel<<<128, 512, 0, stream>>>(giC, Whh_c, bhh_c, Ws, bs, h0f, h1f, selm, flagsA);
    // 3. forcing + stable partition
    build_order_k<<<1, 64, 0, stream>>>(mask, selm, order, nsel, maxn);
    // 3b. merged bf16 weight prep (after rec_sel; aliases gi_c tail)
    wprep_all<<<(WP_N6 + 255) / 256, 256, 0, stream>>>(Whh0, Whh1, Wih0, Wih1,
                                                       Wc3, Wc4, Wc5, wpack);
    // 4. gi0 = new_emb @ Wih0^T + bih0 (gathered rows, bf16 MFMA, supertile)
    gemm_mfma<1,0><<<dim3(512 * 24), 256, 0, stream>>>(emb, wih0b, bih0, giB, nullptr,
                                                       G_, E_, E_, T_, 8, 24, order, nsel, 0);
    // 5. FUSED layer0 -> gi1 -> layer1 pipeline
    hipMemsetAsync(flagsA, 0, 512, stream);                       // A/B/C flags
    hipMemsetAsync(h0A, 0, 65536, stream);
    hipMemsetAsync(h0C, 0, 65536, stream);
    hipMemsetAsync(outbuf, 0, (size_t)B_ * T_ * H_ * 4, stream);  // out1 zero (conv tail rows)
    rec_fused<<<88, 256, 0, stream>>>(giB, wbf0, wbf1, wih1b, bhh0, bhh1, bih1,
                                      nsel, maxn, h0A, h1A, h0C, h1C,
                                      ring0, ring1, outbuf, flagsA, flagsB, flagsC);
    // 8. convs (bf16 MFMA sliding-window, supertile) + relu + time-max pooling
    hipMemsetAsync(pool, 0, (size_t)B_ * 3 * NF_ * 4, stream);
    gemm_mfma<2,1><<<dim3(512 * 4), 256, 0, stream>>>(outbuf, wc3b, bc3, nullptr, pool,
                                                      NF_, 3*H_, H_, 510, 8, 4, nullptr, nullptr, 0);
    gemm_mfma<2,1><<<dim3(512 * 4), 256, 0, stream>>>(outbuf, wc4b, bc4, nullptr, pool,
                                                      NF_, 4*H_, H_, 509, 8, 4, nullptr, nullptr, 256);
    gemm_mfma<2,1><<<dim3(512 * 4), 256, 0, stream>>>(outbuf, wc5b, bc5, nullptr, pool,
                                                      NF_, 5*H_, H_, 508, 8, 4, nullptr, nullptr, 512);
    // 9. final linear -> d_out (64 f32)
    final_k<<<1, 64, 0, stream>>>(pool, Wo, bo, (float*)d_out);
}

// Round 15
// 9735.371 us; speedup vs baseline: 3.2876x; 1.0877x over previous
//
#include <hip/hip_runtime.h>
#include <hip/hip_bf16.h>
#include <cstddef>

// ---------------- problem constants ----------------
constexpr int B_ = 64, T_ = 512, E_ = 768, H_ = 512, G_ = 1536, NF_ = 256;

typedef float f32x4 __attribute__((ext_vector_type(4)));
typedef __bf16 bf16x8 __attribute__((ext_vector_type(8)));

// ---------------- workspace layout (bytes) ----------------
constexpr size_t SZ_GIC   = (size_t)B_ * T_ * G_ * 4;       // 192 MiB
constexpr size_t OFF_GI   = 0;                              // f32 gi_c / later bf16 gi
constexpr size_t OFF_OUT  = (size_t)B_ * T_ * G_ * 2;       // 96MiB: out1 f32 (64MiB)
// bf16 weight copies alias gi_c's tail -> wprep must run AFTER sel_fused.
constexpr size_t OFF_WBF0 = 170u * 1024 * 1024;
constexpr size_t OFF_WBF1 = OFF_WBF0 + (size_t)G_ * H_ * 2;
constexpr size_t OFF_WIH0 = OFF_WBF1 + (size_t)G_ * H_ * 2;
constexpr size_t OFF_WIH1 = OFF_WIH0 + (size_t)G_ * E_ * 2;
constexpr size_t OFF_WC3  = OFF_WIH1 + (size_t)G_ * H_ * 2;
constexpr size_t OFF_WC4  = OFF_WC3 + (size_t)NF_ * 3 * H_ * 2;
constexpr size_t OFF_WC5  = OFF_WC4 + (size_t)NF_ * 4 * H_ * 2;
constexpr size_t OFF_MISC = SZ_GIC;
constexpr size_t OFF_H0   = OFF_MISC;                       // 256KB
constexpr size_t OFF_H1   = OFF_H0 + (size_t)B_ * H_ * 4;
constexpr size_t OFF_SEL  = OFF_H1 + (size_t)B_ * H_ * 4;   // uint64 selm[T_]
constexpr size_t OFF_ORD  = OFF_SEL + (size_t)B_ * T_ * 4;
constexpr size_t OFF_NSEL = OFF_ORD + (size_t)B_ * T_ * 4;
constexpr size_t OFF_MAXN = OFF_NSEL + 256;
constexpr size_t OFF_FLG  = OFF_MAXN + 256;   // sel flags[128] / fused A,B,C
constexpr size_t OFF_JOBS = OFF_FLG + 512;    // jobs_done[8]
constexpr size_t OFF_POOL = OFF_FLG + 1024;
constexpr size_t OFF_RING0 = OFF_POOL + (size_t)B_ * 3 * NF_ * 4;   // out0 ring [4][64][512] bf16
constexpr size_t OFF_RING1 = OFF_RING0 + 4ull * 64 * 512 * 2;       // gi1 ring [4][64][1536] bf16
constexpr size_t WS_NEED  = OFF_RING1 + 4ull * 64 * 1536 * 2;

// merged weight-prep region sizes (elements)
constexpr int WP_N0 = G_ * H_;
constexpr int WP_N1 = WP_N0 + G_ * H_;
constexpr int WP_N2 = WP_N1 + G_ * E_;
constexpr int WP_N3 = WP_N2 + G_ * H_;
constexpr int WP_N4 = WP_N3 + NF_ * 3 * H_;
constexpr int WP_N5 = WP_N4 + NF_ * 4 * H_;
constexpr int WP_N6 = WP_N5 + NF_ * 5 * H_;

// coherent (fabric-level, L1/L2-bypass) access helpers
#define CLOAD4(dst, ptr) \
    asm volatile("global_load_dwordx4 %0, %1, off sc0 sc1" : "=v"(dst) : "v"(ptr))
#define CLOAD2(dst, ptr) \
    asm volatile("global_load_dwordx2 %0, %1, off sc0 sc1" : "=v"(dst) : "v"(ptr))
#define CWAIT() do { \
    asm volatile("s_waitcnt vmcnt(0)" ::: "memory"); \
    __builtin_amdgcn_sched_barrier(0); } while (0)
#define CSTORE4(ptr, val) \
    asm volatile("global_store_dword %0, %1, off sc0 sc1" :: "v"(ptr), "v"(val) : "memory")
#define CSTORE8(ptr, val) \
    asm volatile("global_store_dwordx2 %0, %1, off sc0 sc1" :: "v"(ptr), "v"(val) : "memory")
#define CSTORE2(ptr, val) \
    asm volatile("global_store_short %0, %1, off sc0 sc1" :: "v"(ptr), "v"(val) : "memory")
// r15 FIX: 128-bit asm store input must be an ext_vector_type (f32x4), not
// the struct-based float4 (LLVM: "indirect register inputs" error).
#define CSTOREX4(ptr, val) \
    asm volatile("global_store_dwordx4 %0, %1, off sc0 sc1" :: "v"(ptr), "v"(val) : "memory")

__device__ __forceinline__ float sigm(float x) { return 1.f / (1.f + expf(-x)); }
__device__ __forceinline__ float b2f(unsigned short u) {
    return __uint_as_float(((unsigned int)u) << 16);
}
__device__ __forceinline__ unsigned short f2bu(float x) {
    __hip_bfloat16 h = __float2bfloat16(x);
    return *(unsigned short*)&h;
}

template<int NWG>
__device__ __forceinline__ void bar_wait(const int* flags, int t, int tid) {
    if (tid < 64) {
        int v;
        for (;;) {
            asm volatile("global_load_dword %0, %1, off sc0 sc1\n\t"
                         "s_waitcnt vmcnt(0)"
                         : "=v"(v) : "v"(flags + (tid & (NWG - 1))) : "memory");
            if (__all(v >= t)) break;
            __builtin_amdgcn_s_sleep(1);
        }
    }
    __syncthreads();
}

// poll first N flags until all >= thresh
template<int N>
__device__ __forceinline__ void poll_ge(const int* flags, int thresh, int tid) {
    if (tid < 64) {
        const int idx = (tid < N) ? tid : 0;
        int v;
        for (;;) {
            asm volatile("global_load_dword %0, %1, off sc0 sc1\n\t"
                         "s_waitcnt vmcnt(0)"
                         : "=v"(v) : "v"(flags + idx) : "memory");
            if (__all(v >= thresh)) break;
            __builtin_amdgcn_s_sleep(1);
        }
    }
    __syncthreads();
}

// per-wave spin on a single counter (all lanes same address)
__device__ __forceinline__ void poll_cnt(const int* p, int thr) {
    int v;
    for (;;) {
        asm volatile("global_load_dword %0, %1, off sc0 sc1\n\t"
                     "s_waitcnt vmcnt(0)"
                     : "=v"(v) : "v"(p) : "memory");
        if (__all(v >= thr)) break;
        __builtin_amdgcn_s_sleep(1);
    }
}

// 128-WG variant for rec_sel
__device__ __forceinline__ void bar_wait128(const int* flags, int t, int tid) {
    if (tid < 64) {
        int v1, v2;
        for (;;) {
            asm volatile("global_load_dword %0, %2, off sc0 sc1\n\t"
                         "global_load_dword %1, %3, off sc0 sc1\n\t"
                         "s_waitcnt vmcnt(0)"
                         : "=&v"(v1), "=&v"(v2)
                         : "v"(flags + tid), "v"(flags + tid + 64) : "memory");
            if (__all((v1 >= t) && (v2 >= t))) break;
            __builtin_amdgcn_s_sleep(1);
        }
    }
    __syncthreads();
}

__device__ __forceinline__ void bar_arrive(int* flags, int t, int tid, int idx) {
    asm volatile("s_waitcnt vmcnt(0)" ::: "memory");
    __syncthreads();
    if (tid == 0) { int pv = t + 1; CSTORE4(flags + idx, pv); }
}

// =====================================================================
// bf16 MFMA GEMM (verified r6/r12) — used for gi0 and the convs.
// =====================================================================
template<int AMODE, int OMODE>
__global__ __launch_bounds__(256) void gemm_mfma(
    const float* __restrict__ A, const unsigned short* __restrict__ Wb,
    const float* __restrict__ bias,
    unsigned short* __restrict__ Cb, unsigned int* __restrict__ pool,
    int N, int K, int ldA, int rowsPerB, int tilesPerB, int nb,
    const int* __restrict__ order, const int* __restrict__ nsel, int poolOff)
{
    __shared__ __align__(16) unsigned short As[64][40];
    __shared__ __align__(16) unsigned short Bs[64][40];
    __shared__ const float* rowp[64];

    const int tid = threadIdx.x;
    const int l = tid & 63;
    const int q = tid >> 6;
    const int per = 16 * nb;
    const int id = blockIdx.x;
    const int sup = id / per, rr2 = id % per;
    const int mblk = sup * 16 + (rr2 & 15);
    const int n0 = (rr2 >> 4) * 64;

    int tileb = 0, tilet0 = 0;
    if (AMODE != 0) { tileb = mblk / tilesPerB; tilet0 = (mblk % tilesPerB) * 64; }

    if (tid < 64) {
        const float* p = nullptr;
        if (AMODE == 0) {
            p = A + ((size_t)mblk * 64 + tid) * (size_t)ldA;
        } else if (AMODE == 1) {
            int t = tilet0 + tid;
            if (t < nsel[tileb]) {
                int src = order[tileb * T_ + t];
                p = A + ((size_t)tileb * T_ + src) * (size_t)ldA;
            }
        } else {
            int t = tilet0 + tid;
            if (t < rowsPerB) p = A + ((size_t)tileb * T_ + t) * (size_t)ldA;
        }
        rowp[tid] = p;
    }
    __syncthreads();

    f32x4 acc0 = {0.f,0.f,0.f,0.f}, acc1 = {0.f,0.f,0.f,0.f};
    f32x4 acc2 = {0.f,0.f,0.f,0.f}, acc3 = {0.f,0.f,0.f,0.f};

    const int r = tid & 63, seg = tid >> 6;
    const float* ap = rowp[r];
    if (ap) ap += seg * 8;
    const unsigned short* wrow = Wb + (size_t)(n0 + r) * (size_t)K + seg * 8;

    for (int k0 = 0; k0 < K; k0 += 32) {
        float4 fa = make_float4(0,0,0,0), fb = make_float4(0,0,0,0);
        if (ap) { fa = *(const float4*)(ap + k0); fb = *(const float4*)(ap + k0 + 4); }
        const uint4 wv = *(const uint4*)(wrow + k0);
        __syncthreads();
        uint4 pk;
        pk.x = (unsigned)f2bu(fa.x) | ((unsigned)f2bu(fa.y) << 16);
        pk.y = (unsigned)f2bu(fa.z) | ((unsigned)f2bu(fa.w) << 16);
        pk.z = (unsigned)f2bu(fb.x) | ((unsigned)f2bu(fb.y) << 16);
        pk.w = (unsigned)f2bu(fb.z) | ((unsigned)f2bu(fb.w) << 16);
        *(uint4*)&As[r][seg * 8] = pk;
        *(uint4*)&Bs[r][seg * 8] = wv;
        __syncthreads();
        const bf16x8 av = *(const bf16x8*)&As[q * 16 + (l & 15)][(l >> 4) * 8];
        const bf16x8 b0 = *(const bf16x8*)&Bs[ 0 + (l & 15)][(l >> 4) * 8];
        const bf16x8 b1 = *(const bf16x8*)&Bs[16 + (l & 15)][(l >> 4) * 8];
        const bf16x8 b2 = *(const bf16x8*)&Bs[32 + (l & 15)][(l >> 4) * 8];
        const bf16x8 b3 = *(const bf16x8*)&Bs[48 + (l & 15)][(l >> 4) * 8];
        acc0 = __builtin_amdgcn_mfma_f32_16x16x32_bf16(av, b0, acc0, 0, 0, 0);
        acc1 = __builtin_amdgcn_mfma_f32_16x16x32_bf16(av, b1, acc1, 0, 0, 0);
        acc2 = __builtin_amdgcn_mfma_f32_16x16x32_bf16(av, b2, acc2, 0, 0, 0);
        acc3 = __builtin_amdgcn_mfma_f32_16x16x32_bf16(av, b3, acc3, 0, 0, 0);
    }

    f32x4 accs[4] = {acc0, acc1, acc2, acc3};
    if (OMODE == 0) {
        const int mbase = (AMODE == 0) ? mblk * 64 : tileb * T_ + tilet0;
        #pragma unroll
        for (int s = 0; s < 4; ++s) {
            const int col = n0 + s * 16 + (l & 15);
            const float bv = bias[col];
            #pragma unroll
            for (int reg = 0; reg < 4; ++reg) {
                const int m = mbase + q * 16 + (l >> 4) * 4 + reg;
                Cb[(size_t)m * (size_t)N + col] = f2bu(accs[s][reg] + bv);
            }
        }
    } else {
        #pragma unroll
        for (int s = 0; s < 4; ++s) {
            const int col = n0 + s * 16 + (l & 15);
            const float bv = bias[col];
            float mx = 0.f;
            #pragma unroll
            for (int reg = 0; reg < 4; ++reg) {
                const int t = tilet0 + q * 16 + (l >> 4) * 4 + reg;
                const float val = fmaxf(accs[s][reg] + bv, 0.f);
                if (t < rowsPerB) mx = fmaxf(mx, val);
            }
            mx = fmaxf(mx, __shfl_xor(mx, 16));
            mx = fmaxf(mx, __shfl_xor(mx, 32));
            if (l < 16)
                atomicMax(&pool[(size_t)tileb * (3*NF_) + poolOff + n0 + s*16 + l],
                          __float_as_uint(mx));
        }
    }
}

// =====================================================================
// Merged weight f32 -> bf16 prep (verified r12).
// =====================================================================
__global__ void wprep_all(
    const float* __restrict__ w0, const float* __restrict__ w1,
    const float* __restrict__ w2, const float* __restrict__ w3,
    const float* __restrict__ w4, const float* __restrict__ w5,
    const float* __restrict__ w6, unsigned short* __restrict__ o)
{
    const int i = blockIdx.x * 256 + threadIdx.x;
    if (i >= WP_N6) return;
    float v;
    if      (i < WP_N0) v = w0[i];
    else if (i < WP_N1) v = w1[i - WP_N0];
    else if (i < WP_N2) v = w2[i - WP_N1];
    else if (i < WP_N3) v = w3[i - WP_N2];
    else if (i < WP_N4) v = w4[i - WP_N3];
    else if (i < WP_N5) v = w5[i - WP_N4];
    else                v = w6[i - WP_N5];
    o[i] = f2bu(v);
}

// =====================================================================
// Fused gi_c producer + selector GRU consumer. 256 WGs x 512 thr.
// WGs 0-127: rec_sel v7 (verified r11-r13), gi reads coherent, gated by
//   jobs_done[chunk] (chunk = t/64); 8 polls per recurrence.
// WGs 128-255: fp32 gi_c GEMM producers, chunk-ordered jobs
//   (job = 64x64 tile; per-output k-ascending fma chains + bias-at-store
//   bit-identical to the old gemm_f32). Coherent stores + drain +
//   device-scope atomicAdd(jobs_done[c]). Producers never wait; all
//   256 WGs co-resident (1/CU) -> deadlock-free.
// =====================================================================
__device__ __forceinline__ void gates_abs(
    const float* __restrict__ hs, int b, int base,
    const float* __restrict__ wR, const float* __restrict__ wZ,
    const float* __restrict__ wN,
    float& aR, float& aZ, float& aN)
{
    #pragma unroll 4
    for (int kq = 0; kq < 32; ++kq) {
        const int k = base + kq * 4;
        const float hv0 = hs[(k+0)*64 + b];
        const float hv1 = hs[(k+1)*64 + b];
        const float hv2 = hs[(k+2)*64 + b];
        const float hv3 = hs[(k+3)*64 + b];
        const float4 wr = *(const float4*)(wR + k);
        const float4 wz = *(const float4*)(wZ + k);
        const float4 wn = *(const float4*)(wN + k);
        aR = fmaf(hv0, wr.x, aR); aR = fmaf(hv1, wr.y, aR);
        aR = fmaf(hv2, wr.z, aR); aR = fmaf(hv3, wr.w, aR);
        aZ = fmaf(hv0, wz.x, aZ); aZ = fmaf(hv1, wz.y, aZ);
        aZ = fmaf(hv2, wz.z, aZ); aZ = fmaf(hv3, wz.w, aZ);
        aN = fmaf(hv0, wn.x, aN); aN = fmaf(hv1, wn.y, aN);
        aN = fmaf(hv2, wn.z, aN); aN = fmaf(hv3, wn.w, aN);
    }
}

__device__ __forceinline__ void dot_abs(
    const float* __restrict__ hs, int b, int base,
    const float* __restrict__ dWl, float& dot)
{
    #pragma unroll 4
    for (int kq = 0; kq < 16; ++kq) {
        const int k = base + kq * 4;
        const float hv0 = hs[(k+0)*64 + b];
        const float hv1 = hs[(k+1)*64 + b];
        const float hv2 = hs[(k+2)*64 + b];
        const float hv3 = hs[(k+3)*64 + b];
        const float4 dv = *(const float4*)(dWl + k);
        dot = fmaf(hv0, dv.x, dot); dot = fmaf(hv1, dv.y, dot);
        dot = fmaf(hv2, dv.z, dot); dot = fmaf(hv3, dv.w, dot);
    }
}

__global__ __launch_bounds__(512) void sel_fused(
    const float* __restrict__ emb, const float* __restrict__ Wih_c,
    const float* __restrict__ bih_c, float* __restrict__ giC,
    const float* __restrict__ Whh, const float* __restrict__ bhh,
    const float* __restrict__ Ws, const float* __restrict__ bs,
    float* __restrict__ h0, float* __restrict__ h1,
    unsigned long long* __restrict__ selm, int* __restrict__ flags,
    int* __restrict__ jobs)
{
    __shared__ __align__(16) char smem[162816];   // union: consumer 159KB / producer 8.7KB
    const int tid = threadIdx.x;
    const int bx = blockIdx.x;

    if (bx >= 128) {
        // ------------------- PRODUCER: gi_c GEMM, chunk-ordered -------------------
        const int p = bx - 128;
        float* As = (float*)smem;            // [16][68]
        float* Bs = As + 16 * 68;
        const int half = tid >> 8;           // 0 = A stager, 1 = B stager
        const int t2 = tid & 255;
        const int srl = t2 >> 2, skl = (t2 & 3) * 4;
        const int ty = tid >> 4;             // 0..31 (2 rows)
        const int tx = tid & 15;             // 0..15 (4 cols)

        for (int c = 0; c < 8; ++c) {
            for (int j = p; j < 1536; j += 128) {
                const int b = j / 24, n = j % 24;
                const int mblk = b * 8 + c;
                const int n0 = n * 64;
                const float* src = (half == 0)
                    ? emb + ((size_t)mblk * 64 + srl) * (size_t)E_ + skl
                    : Wih_c + ((size_t)(n0 + srl)) * (size_t)E_ + skl;
                float* dl = (half == 0) ? As : Bs;

                float acc[2][4] = {};
                for (int k0 = 0; k0 < E_; k0 += 16) {
                    const float4 v = *(const float4*)(src + k0);
                    __syncthreads();
                    dl[(skl+0)*68 + srl] = v.x; dl[(skl+1)*68 + srl] = v.y;
                    dl[(skl+2)*68 + srl] = v.z; dl[(skl+3)*68 + srl] = v.w;
                    __syncthreads();
                    #pragma unroll
                    for (int kk = 0; kk < 16; ++kk) {
                        const float a0 = As[kk*68 + ty*2 + 0];
                        const float a1 = As[kk*68 + ty*2 + 1];
                        const float4 w4 = *(const float4*)&Bs[kk*68 + tx*4];
                        acc[0][0]=fmaf(a0,w4.x,acc[0][0]); acc[0][1]=fmaf(a0,w4.y,acc[0][1]);
                        acc[0][2]=fmaf(a0,w4.z,acc[0][2]); acc[0][3]=fmaf(a0,w4.w,acc[0][3]);
                        acc[1][0]=fmaf(a1,w4.x,acc[1][0]); acc[1][1]=fmaf(a1,w4.y,acc[1][1]);
                        acc[1][2]=fmaf(a1,w4.z,acc[1][2]); acc[1][3]=fmaf(a1,w4.w,acc[1][3]);
                    }
                }
                const float4 bv = *(const float4*)(bih_c + n0 + tx*4);
                f32x4 o0, o1;   // ext_vector_type for asm store (r15 fix)
                o0[0] = acc[0][0]+bv.x; o0[1] = acc[0][1]+bv.y;
                o0[2] = acc[0][2]+bv.z; o0[3] = acc[0][3]+bv.w;
                o1[0] = acc[1][0]+bv.x; o1[1] = acc[1][1]+bv.y;
                o1[2] = acc[1][2]+bv.z; o1[3] = acc[1][3]+bv.w;
                const float* d0 = giC + (size_t)(mblk * 64 + ty*2) * (size_t)G_ + n0 + tx*4;
                CSTOREX4(d0, o0);
                CSTOREX4(d0 + G_, o1);
                asm volatile("s_waitcnt vmcnt(0)" ::: "memory");
                __syncthreads();
                if (tid == 0)
                    __hip_atomic_fetch_add(jobs + c, 1, __ATOMIC_RELAXED,
                                           __HIP_MEMORY_SCOPE_AGENT);
                __syncthreads();
            }
        }
        return;
    }

    // ------------------- CONSUMER: rec_sel v7 -------------------
    float* Wl    = (float*)smem;           // 6144
    float* dWl   = Wl + 6144;              // 512
    float* hs    = dWl + 512;              // 32768
    float* partR = hs + 32768;             // 256
    float* partZ = partR + 256;            // 256
    float* partN = partZ + 256;            // 256
    float* pdot  = partN + 256;            // 512

    const int b = tid & 63;
    const int w = __builtin_amdgcn_readfirstlane(tid >> 6);
    const int u = w >> 1, s = w & 1;
    const int iu = bx * 4 + u;

    for (int idx = tid; idx < 12 * 512; idx += 512) {
        int rr = idx >> 9, k = idx & 511;
        int ul = rr / 3, gate = rr - ul * 3;
        Wl[idx] = Whh[((size_t)gate * 512 + bx * 4 + ul) * 512 + k];
    }
    dWl[tid] = Ws[512 + tid] - Ws[tid];
    __syncthreads();

    const float bR = bhh[iu], bZ = bhh[512 + iu], bN = bhh[1024 + iu];
    const float db = bs[1] - bs[0];
    const float* __restrict__ wR = Wl + (u*3 + 0) * 512;
    const float* __restrict__ wZ = Wl + (u*3 + 1) * 512;
    const float* __restrict__ wN = Wl + (u*3 + 2) * 512;

    // gi(t=0) prefetch — gated on chunk 0, coherent
    float pgR = 0.f, pgZ = 0.f, pgN = 0.f;
    int ready_chunk = 0;
    if (s == 0) {
        poll_cnt(jobs + 0, 1536);
        ready_chunk = 1;
        const float* gp = giC + (size_t)b * T_ * G_;
        asm volatile("global_load_dword %0, %3, off sc0 sc1\n\t"
                     "global_load_dword %1, %4, off sc0 sc1\n\t"
                     "global_load_dword %2, %5, off sc0 sc1\n\t"
                     "s_waitcnt vmcnt(0)"
                     : "=&v"(pgR), "=&v"(pgZ), "=&v"(pgN)
                     : "v"(gp + iu), "v"(gp + 512 + iu), "v"(gp + 1024 + iu)
                     : "memory");
    }

    for (int t = 0; t <= T_; ++t) {
        const bool comp = (t < T_);
        const float* hcur = (t & 1) ? h1 : h0;
        float* hnxt = (t & 1) ? h0 : h1;

        if (t > 0) bar_wait128(flags, t, tid);

        // ---- single-shot stage of full h(t): 16 CLOAD4/thread ----
        const float* hc = hcur + (size_t)tid * 4;
        float* hd = hs + tid * 4;
        float4 a0,a1,a2,a3,a4,a5,a6,a7,a8,a9,aa,ab,ac,ad,ae,af;
        CLOAD4(a0, hc +  0*2048); CLOAD4(a1, hc +  1*2048);
        CLOAD4(a2, hc +  2*2048); CLOAD4(a3, hc +  3*2048);
        CLOAD4(a4, hc +  4*2048); CLOAD4(a5, hc +  5*2048);
        CLOAD4(a6, hc +  6*2048); CLOAD4(a7, hc +  7*2048);
        CLOAD4(a8, hc +  8*2048); CLOAD4(a9, hc +  9*2048);
        CLOAD4(aa, hc + 10*2048); CLOAD4(ab, hc + 11*2048);
        CLOAD4(ac, hc + 12*2048); CLOAD4(ad, hc + 13*2048);
        CLOAD4(ae, hc + 14*2048); CLOAD4(af, hc + 15*2048);
        CWAIT();
        *(float4*)(hd +  0*2048) = a0; *(float4*)(hd +  1*2048) = a1;
        *(float4*)(hd +  2*2048) = a2; *(float4*)(hd +  3*2048) = a3;
        *(float4*)(hd +  4*2048) = a4; *(float4*)(hd +  5*2048) = a5;
        *(float4*)(hd +  6*2048) = a6; *(float4*)(hd +  7*2048) = a7;
        *(float4*)(hd +  8*2048) = a8; *(float4*)(hd +  9*2048) = a9;
        *(float4*)(hd + 10*2048) = aa; *(float4*)(hd + 11*2048) = ab;
        *(float4*)(hd + 12*2048) = ac; *(float4*)(hd + 13*2048) = ad;
        *(float4*)(hd + 14*2048) = ae; *(float4*)(hd + 15*2048) = af;
        __syncthreads();

        float aR = (s == 0) ? bR : 0.f;
        float aZ = (s == 0) ? bZ : 0.f;
        float aN = (s == 0) ? bN : 0.f;
        float dot = 0.f, hp = 0.f;

        if (comp) {
            gates_abs(hs, b, s * 128,       wR, wZ, wN, aR, aZ, aN);
            gates_abs(hs, b, 256 + s * 128, wR, wZ, wN, aR, aZ, aN);
            if (s == 0) hp = hs[iu * 64 + b];
        }
        dot_abs(hs, b, (w < 4) ? w * 64 : 256 + (w - 4) * 64, dWl, dot);

        if (comp && s == 1) {
            partR[u*64 + b] = aR; partZ[u*64 + b] = aZ; partN[u*64 + b] = aN;
        }
        pdot[w*64 + b] = dot;
        __syncthreads();

        if (comp && s == 0) {
            aR += partR[u*64 + b]; aZ += partZ[u*64 + b]; aN += partN[u*64 + b];
            const float r = sigm(pgR + aR);
            const float z = sigm(pgZ + aZ);
            const float n = tanhf(pgN + r * aN);
            const float hn = (1.f - z) * n + z * hp;
            const float* hdst = hnxt + (size_t)iu * 64 + b;
            CSTORE4(hdst, hn);
        }

        if (t < T_) {
            bar_arrive(flags, t, tid, bx);
            // gi(t+1) prefetch after flag store; gated on producer chunk
            if (s == 0 && t + 1 < T_) {
                const int nc = (t + 1) >> 6;
                if (nc >= ready_chunk) { poll_cnt(jobs + nc, 1536); ready_chunk = nc + 1; }
                const float* gp = giC + ((size_t)b * T_ + t + 1) * G_;
                asm volatile("global_load_dword %0, %3, off sc0 sc1\n\t"
                             "global_load_dword %1, %4, off sc0 sc1\n\t"
                             "global_load_dword %2, %5, off sc0 sc1\n\t"
                             "s_waitcnt vmcnt(0)"
                             : "=&v"(pgR), "=&v"(pgZ), "=&v"(pgN)
                             : "v"(gp + iu), "v"(gp + 512 + iu), "v"(gp + 1024 + iu)
                             : "memory");
            }
        }
        if (w == 0 && t >= 1) {
            float p2 = pdot[0*64 + b];
            p2 += pdot[1*64 + b]; p2 += pdot[2*64 + b]; p2 += pdot[3*64 + b];
            p2 += pdot[4*64 + b]; p2 += pdot[5*64 + b]; p2 += pdot[6*64 + b];
            p2 += pdot[7*64 + b];
            unsigned long long m = __ballot((p2 + db) > 0.f);
            if (tid == 0 && bx == 0) selm[t - 1] = m;
        }
    }
}

// =====================================================================
// FUSED layer0 -> gi1 -> layer1 pipeline (verified r13, unchanged).
// =====================================================================
template<int ROLE>
__device__ __forceinline__ void layer_body(
    int wg, int tid,
    const unsigned short* __restrict__ gi0,
    const unsigned short* __restrict__ ring1,
    unsigned short* __restrict__ ring0,
    const unsigned short* __restrict__ wbf, const float* __restrict__ bhh,
    const int* __restrict__ nselp, const int* __restrict__ maxnp,
    unsigned short* __restrict__ hA, unsigned short* __restrict__ hB,
    float* __restrict__ outp,
    int* __restrict__ flagsSelf, const int* __restrict__ flagsB,
    unsigned char* ldsW, unsigned char* ldsH, float* gbuf)
{
    const int l = tid & 63;
    const int q = tid >> 6;
    const int i0 = wg * 16;
    const int b = tid & 63;

    for (int idx = tid; idx < 48 * 64; idx += 256) {
        const int r = idx >> 6, seg = idx & 63;
        const int tier = r >> 4, ul = r & 15;
        const float4 v = *(const float4*)((const char*)wbf
            + ((size_t)(tier * 512 + i0 + ul) * 512) * 2 + seg * 16);
        *(float4*)(ldsW + r * 1040 + seg * 16) = v;
    }
    const float4 bRv = *(const float4*)(bhh + i0 + 4 * q);
    const float4 bZv = *(const float4*)(bhh + 512 + i0 + 4 * q);
    const float4 bNv = *(const float4*)(bhh + 1024 + i0 + 4 * q);
    const int ns = nselp[b];
    const int TOTAL = *maxnp;

    const unsigned short* gbase = gi0 + (size_t)b * T_ * (size_t)G_ + i0 + 4 * q;
    uint2 gR, gZ, gN;
    if (ROLE == 0) {
        gR = *(const uint2*)(gbase);
        gZ = *(const uint2*)(gbase + 512);
        gN = *(const uint2*)(gbase + 1024);
    }
    __syncthreads();

    for (int t = 0; t < TOTAL; ++t) {
        const unsigned short* hcur = (t & 1) ? hB : hA;
        unsigned short* hnxt = (t & 1) ? hA : hB;

        if (t > 0) bar_wait<32>(flagsSelf, t, tid);
        if (ROLE == 0) {
            if (t >= 4) poll_ge<24>(flagsB, t - 3, tid);
        } else {
            poll_ge<24>(flagsB, t + 1, tid);
            const unsigned short* gp = ring1 + ((size_t)(t & 3) * 64 + b) * G_ + i0 + 4 * q;
            CLOAD2(gR, gp); CLOAD2(gZ, gp + 512); CLOAD2(gN, gp + 1024);
        }

        {
            const char* src = (const char*)hcur + tid * 256;
            float4 s0, s1, s2, s3, s4, s5, s6, s7, s8, s9, sa, sb_, sc, sd, se, sf;
            CLOAD4(s0, src + 0 * 16);  CLOAD4(s1, src + 1 * 16);
            CLOAD4(s2, src + 2 * 16);  CLOAD4(s3, src + 3 * 16);
            CLOAD4(s4, src + 4 * 16);  CLOAD4(s5, src + 5 * 16);
            CLOAD4(s6, src + 6 * 16);  CLOAD4(s7, src + 7 * 16);
            CLOAD4(s8, src + 8 * 16);  CLOAD4(s9, src + 9 * 16);
            CLOAD4(sa, src + 10 * 16); CLOAD4(sb_, src + 11 * 16);
            CLOAD4(sc, src + 12 * 16); CLOAD4(sd, src + 13 * 16);
            CLOAD4(se, src + 14 * 16); CLOAD4(sf, src + 15 * 16);
            CWAIT();
            char* dst = (char*)ldsH + (tid >> 2) * 1040 + (tid & 3) * 256;
            *(float4*)(dst + 0 * 16) = s0;  *(float4*)(dst + 1 * 16) = s1;
            *(float4*)(dst + 2 * 16) = s2;  *(float4*)(dst + 3 * 16) = s3;
            *(float4*)(dst + 4 * 16) = s4;  *(float4*)(dst + 5 * 16) = s5;
            *(float4*)(dst + 6 * 16) = s6;  *(float4*)(dst + 7 * 16) = s7;
            *(float4*)(dst + 8 * 16) = s8;  *(float4*)(dst + 9 * 16) = s9;
            *(float4*)(dst + 10 * 16) = sa; *(float4*)(dst + 11 * 16) = sb_;
            *(float4*)(dst + 12 * 16) = sc; *(float4*)(dst + 13 * 16) = sd;
            *(float4*)(dst + 14 * 16) = se; *(float4*)(dst + 15 * 16) = sf;
        }
        __syncthreads();

        f32x4 ac0 = {0.f, 0.f, 0.f, 0.f};
        f32x4 ac1 = {0.f, 0.f, 0.f, 0.f};
        f32x4 ac2 = {0.f, 0.f, 0.f, 0.f};
        {
            const char* ab2 = (const char*)ldsH + (q * 16 + (l & 15)) * 1040 + (l >> 4) * 16;
            const char* bb = (const char*)ldsW + (l & 15) * 1040 + (l >> 4) * 16;
            #pragma unroll
            for (int ks = 0; ks < 16; ++ks) {
                const bf16x8 av = *(const bf16x8*)(ab2 + ks * 64);
                const bf16x8 w0 = *(const bf16x8*)(bb + ks * 64);
                const bf16x8 w1 = *(const bf16x8*)(bb + 16 * 1040 + ks * 64);
                const bf16x8 w2 = *(const bf16x8*)(bb + 32 * 1040 + ks * 64);
                ac0 = __builtin_amdgcn_mfma_f32_16x16x32_bf16(av, w0, ac0, 0, 0, 0);
                ac1 = __builtin_amdgcn_mfma_f32_16x16x32_bf16(av, w1, ac1, 0, 0, 0);
                ac2 = __builtin_amdgcn_mfma_f32_16x16x32_bf16(av, w2, ac2, 0, 0, 0);
            }
        }
        {
            const int gcol = q * 16 + 4 * (l >> 4);
            const int grow = l & 15;
            #pragma unroll
            for (int r = 0; r < 4; ++r) {
                gbuf[grow * 66 + gcol + r]        = ac0[r];
                gbuf[(16 + grow) * 66 + gcol + r] = ac1[r];
                gbuf[(32 + grow) * 66 + gcol + r] = ac2[r];
            }
        }
        __syncthreads();

        {
            const ushort4 hp4 = *(const ushort4*)((const char*)ldsH
                                 + b * 1040 + (i0 + 4 * q) * 2);
            const unsigned short hpb[4] = {hp4.x, hp4.y, hp4.z, hp4.w};
            const float irv[4] = {b2f(gR.x & 0xffff), b2f(gR.x >> 16),
                                  b2f(gR.y & 0xffff), b2f(gR.y >> 16)};
            const float izv[4] = {b2f(gZ.x & 0xffff), b2f(gZ.x >> 16),
                                  b2f(gZ.y & 0xffff), b2f(gZ.y >> 16)};
            const float inv[4] = {b2f(gN.x & 0xffff), b2f(gN.x >> 16),
                                  b2f(gN.y & 0xffff), b2f(gN.y >> 16)};
            float4 o;
            unsigned short ob[4];
            #pragma unroll
            for (int j = 0; j < 4; ++j) {
                const int u2 = 4 * q + j;
                const float hr = gbuf[u2 * 66 + b]        + bRv[j];
                const float hz = gbuf[(16 + u2) * 66 + b] + bZv[j];
                const float hn = gbuf[(32 + u2) * 66 + b] + bNv[j];
                const float rr = sigm(irv[j] + hr);
                const float zz = sigm(izv[j] + hz);
                const float nn = tanhf(inv[j] + rr * hn);
                const float hpf = b2f(hpb[j]);
                float hv = (1.f - zz) * nn + zz * hpf;
                if (t >= ns) hv = hpf;
                ((float*)&o)[j] = hv;
                ob[j] = f2bu(hv);
            }
            uint2 hpk;
            hpk.x = (unsigned)ob[0] | ((unsigned)ob[1] << 16);
            hpk.y = (unsigned)ob[2] | ((unsigned)ob[3] << 16);
            if (ROLE == 0) {
                const unsigned short* rdst = ring0 + ((size_t)(t & 3) * 64 + b) * 512 + i0 + 4 * q;
                CSTORE8(rdst, hpk);
            } else {
                if (t < ns)
                    *(float4*)(outp + ((size_t)b * T_ + t) * 512 + i0 + 4 * q) = o;
            }
            const unsigned short* hdst = hnxt + (size_t)b * 512 + i0 + 4 * q;
            CSTORE8(hdst, hpk);
        }

        bar_arrive(flagsSelf, t, tid, wg);
        if (ROLE == 0 && t + 1 < TOTAL) {
            const unsigned short* gp = gbase + (size_t)(t + 1) * G_;
            gR = *(const uint2*)gp;
            gZ = *(const uint2*)(gp + 512);
            gN = *(const uint2*)(gp + 1024);
        }
    }
}

__global__ __launch_bounds__(256) void rec_fused(
    const unsigned short* __restrict__ gi0,
    const unsigned short* __restrict__ wbf0,
    const unsigned short* __restrict__ wbf1,
    const unsigned short* __restrict__ wih1b,
    const float* __restrict__ bhh0, const float* __restrict__ bhh1,
    const float* __restrict__ bih1,
    const int* __restrict__ nselp, const int* __restrict__ maxnp,
    unsigned short* __restrict__ h0A, unsigned short* __restrict__ h1A,
    unsigned short* __restrict__ h0C, unsigned short* __restrict__ h1C,
    unsigned short* __restrict__ ring0, unsigned short* __restrict__ ring1,
    float* __restrict__ outp,
    int* __restrict__ flagsA, int* __restrict__ flagsB, int* __restrict__ flagsC)
{
    __shared__ __align__(16) unsigned char ldsX[64 * 1040];
    __shared__ __align__(16) unsigned char ldsY[64 * 1040];
    __shared__ float gbuf[48 * 66];

    const int tid = threadIdx.x;
    const int bx = blockIdx.x;

    if (bx < 32) {
        layer_body<0>(bx, tid, gi0, nullptr, ring0, wbf0, bhh0, nselp, maxnp,
                      h0A, h1A, nullptr, flagsA, flagsB, ldsX, ldsY, gbuf);
    } else if (bx < 56) {
        const int wg = bx - 32;
        const int l = tid & 63;
        const int q = tid >> 6;
        const int n0 = wg * 64;

        for (int idx = tid; idx < 64 * 64; idx += 256) {
            const int r = idx >> 6, seg = idx & 63;
            const float4 v = *(const float4*)((const char*)wih1b
                + ((size_t)(n0 + r) * 512) * 2 + seg * 16);
            *(float4*)(ldsX + r * 1040 + seg * 16) = v;
        }
        float bv[4];
        #pragma unroll
        for (int s = 0; s < 4; ++s) bv[s] = bih1[n0 + s * 16 + (l & 15)];
        const int TOTAL = *maxnp;
        __syncthreads();

        for (int t = 0; t < TOTAL; ++t) {
            poll_ge<32>(flagsA, t + 1, tid);
            if (t >= 4) poll_ge<32>(flagsC, t - 3, tid);

            {
                const char* src = (const char*)ring0 + (size_t)(t & 3) * 65536 + tid * 256;
                float4 s0, s1, s2, s3, s4, s5, s6, s7, s8, s9, sa, sb_, sc, sd, se, sf;
                CLOAD4(s0, src + 0 * 16);  CLOAD4(s1, src + 1 * 16);
                CLOAD4(s2, src + 2 * 16);  CLOAD4(s3, src + 3 * 16);
                CLOAD4(s4, src + 4 * 16);  CLOAD4(s5, src + 5 * 16);
                CLOAD4(s6, src + 6 * 16);  CLOAD4(s7, src + 7 * 16);
                CLOAD4(s8, src + 8 * 16);  CLOAD4(s9, src + 9 * 16);
                CLOAD4(sa, src + 10 * 16); CLOAD4(sb_, src + 11 * 16);
                CLOAD4(sc, src + 12 * 16); CLOAD4(sd, src + 13 * 16);
                CLOAD4(se, src + 14 * 16); CLOAD4(sf, src + 15 * 16);
                CWAIT();
                char* dst = (char*)ldsY + (tid >> 2) * 1040 + (tid & 3) * 256;
                *(float4*)(dst + 0 * 16) = s0;  *(float4*)(dst + 1 * 16) = s1;
                *(float4*)(dst + 2 * 16) = s2;  *(float4*)(dst + 3 * 16) = s3;
                *(float4*)(dst + 4 * 16) = s4;  *(float4*)(dst + 5 * 16) = s5;
                *(float4*)(dst + 6 * 16) = s6;  *(float4*)(dst + 7 * 16) = s7;
                *(float4*)(dst + 8 * 16) = s8;  *(float4*)(dst + 9 * 16) = s9;
                *(float4*)(dst + 10 * 16) = sa; *(float4*)(dst + 11 * 16) = sb_;
                *(float4*)(dst + 12 * 16) = sc; *(float4*)(dst + 13 * 16) = sd;
                *(float4*)(dst + 14 * 16) = se; *(float4*)(dst + 15 * 16) = sf;
            }
            __syncthreads();

            f32x4 acc0 = {0.f,0.f,0.f,0.f}, acc1 = {0.f,0.f,0.f,0.f};
            f32x4 acc2 = {0.f,0.f,0.f,0.f}, acc3 = {0.f,0.f,0.f,0.f};
            {
                const char* ab2 = (const char*)ldsY + (q * 16 + (l & 15)) * 1040 + (l >> 4) * 16;
                const char* bb = (const char*)ldsX + (l & 15) * 1040 + (l >> 4) * 16;
                #pragma unroll
                for (int ks = 0; ks < 16; ++ks) {
                    const bf16x8 av = *(const bf16x8*)(ab2 + ks * 64);
                    const bf16x8 b0 = *(const bf16x8*)(bb + ks * 64);
                    const bf16x8 b1 = *(const bf16x8*)(bb + 16 * 1040 + ks * 64);
                    const bf16x8 b2 = *(const bf16x8*)(bb + 32 * 1040 + ks * 64);
                    const bf16x8 b3 = *(const bf16x8*)(bb + 48 * 1040 + ks * 64);
                    acc0 = __builtin_amdgcn_mfma_f32_16x16x32_bf16(av, b0, acc0, 0, 0, 0);
                    acc1 = __builtin_amdgcn_mfma_f32_16x16x32_bf16(av, b1, acc1, 0, 0, 0);
                    acc2 = __builtin_amdgcn_mfma_f32_16x16x32_bf16(av, b2, acc2, 0, 0, 0);
                    acc3 = __builtin_amdgcn_mfma_f32_16x16x32_bf16(av, b3, acc3, 0, 0, 0);
                }
            }
            f32x4 accs[4] = {acc0, acc1, acc2, acc3};
            #pragma unroll
            for (int s = 0; s < 4; ++s) {
                const int col = n0 + s * 16 + (l & 15);
                #pragma unroll
                for (int reg = 0; reg < 4; ++reg) {
                    const int m = q * 16 + (l >> 4) * 4 + reg;
                    const unsigned val = f2bu(accs[s][reg] + bv[s]);
                    const unsigned short* dst = ring1 + ((size_t)(t & 3) * 64 + m) * G_ + col;
                    CSTORE2(dst, val);
                }
            }
            bar_arrive(flagsB, t, tid, wg);
        }
    } else {
        layer_body<1>(bx - 56, tid, nullptr, ring1, nullptr, wbf1, bhh1, nselp, maxnp,
                      h0C, h1C, outp, flagsC, flagsB, ldsX, ldsY, gbuf);
    }
}

// =====================================================================
// Per-batch selection post-processing (unchanged, selm version).
// =====================================================================
__global__ void build_order_k(const int* __restrict__ mask,
                              const unsigned long long* __restrict__ selm,
                              int* __restrict__ order, int* __restrict__ nsel,
                              int* __restrict__ maxn)
{
    const int b = threadIdx.x;
    int lens = 0;
    for (int t = 0; t < T_; ++t) lens += (mask[b * T_ + t] != 0);
    int cnt = 0;
    for (int t = 0; t < T_; ++t) {
        int s = (int)((selm[t] >> b) & 1ull);
        if (t == 0) s = 1;
        if (t == lens - 1) s = 1;
        if (t >= lens) s = 0;
        if (s) order[b * T_ + (cnt++)] = t;
    }
    nsel[b] = cnt;
    int c2 = cnt;
    for (int t = 0; t < T_; ++t) {
        int s = (int)((selm[t] >> b) & 1ull);
        if (t == 0) s = 1;
        if (t == lens - 1) s = 1;
        if (t >= lens) s = 0;
        if (!s) order[b * T_ + (c2++)] = t;
    }
    __shared__ int red[64];
    red[b] = cnt;
    __syncthreads();
    if (b == 0) {
        int m = 0;
        for (int qq = 0; qq < 64; ++qq) m = max(m, red[qq]);
        *maxn = m;
    }
}

// =====================================================================
// Final linear (unchanged).
// =====================================================================
__global__ void final_k(const unsigned int* __restrict__ pool,
                        const float* __restrict__ Wo, const float* __restrict__ bo,
                        float* __restrict__ out)
{
    const int b = threadIdx.x;
    float s = bo[0];
    for (int f = 0; f < 3 * NF_; ++f)
        s = fmaf(__uint_as_float(pool[b * (3*NF_) + f]), Wo[f], s);
    out[b] = s;
}

// =====================================================================
extern "C" void kernel_launch(void* const* d_in, const int* in_sizes, int n_in,
                              void* d_out, int out_size, void* d_ws, size_t ws_size,
                              hipStream_t stream)
{
    (void)in_sizes; (void)n_in; (void)out_size;
    const float* emb   = (const float*)d_in[0];
    const int*   mask  = (const int*)d_in[1];
    const float* Wih_c = (const float*)d_in[2];
    const float* Whh_c = (const float*)d_in[3];
    const float* bih_c = (const float*)d_in[4];
    const float* bhh_c = (const float*)d_in[5];
    const float* Ws    = (const float*)d_in[6];
    const float* bs    = (const float*)d_in[7];
    const float* Wih0  = (const float*)d_in[8];
    const float* Whh0  = (const float*)d_in[9];
    const float* bih0  = (const float*)d_in[10];
    const float* bhh0  = (const float*)d_in[11];
    const float* Wih1  = (const float*)d_in[12];
    const float* Whh1  = (const float*)d_in[13];
    const float* bih1  = (const float*)d_in[14];
    const float* bhh1  = (const float*)d_in[15];
    const float* Wc3   = (const float*)d_in[16];
    const float* bc3   = (const float*)d_in[17];
    const float* Wc4   = (const float*)d_in[18];
    const float* bc4   = (const float*)d_in[19];
    const float* Wc5   = (const float*)d_in[20];
    const float* bc5   = (const float*)d_in[21];
    const float* Wo    = (const float*)d_in[22];
    const float* bo    = (const float*)d_in[23];

    if (ws_size < WS_NEED) return;
    char* ws = (char*)d_ws;
    float*          giC    = (float*)(ws + OFF_GI);
    unsigned short* giB    = (unsigned short*)(ws + OFF_GI);
    float*          outbuf = (float*)(ws + OFF_OUT);
    unsigned short* wpack  = (unsigned short*)(ws + OFF_WBF0);
    unsigned short* wbf0   = (unsigned short*)(ws + OFF_WBF0);
    unsigned short* wbf1   = (unsigned short*)(ws + OFF_WBF1);
    unsigned short* wih0b  = (unsigned short*)(ws + OFF_WIH0);
    unsigned short* wih1b  = (unsigned short*)(ws + OFF_WIH1);
    unsigned short* wc3b   = (unsigned short*)(ws + OFF_WC3);
    unsigned short* wc4b   = (unsigned short*)(ws + OFF_WC4);
    unsigned short* wc5b   = (unsigned short*)(ws + OFF_WC5);
    float*          h0f    = (float*)(ws + OFF_H0);
    float*          h1f    = (float*)(ws + OFF_H1);
    unsigned short* h0A    = (unsigned short*)(ws + OFF_H0);
    unsigned short* h1A    = (unsigned short*)(ws + OFF_H0 + 65536);
    unsigned short* h0C    = (unsigned short*)(ws + OFF_H0 + 131072);
    unsigned short* h1C    = (unsigned short*)(ws + OFF_H0 + 196608);
    unsigned long long* selm = (unsigned long long*)(ws + OFF_SEL);
    int*            order  = (int*)(ws + OFF_ORD);
    int*            nsel   = (int*)(ws + OFF_NSEL);
    int*            maxn   = (int*)(ws + OFF_MAXN);
    int*            flagsA = (int*)(ws + OFF_FLG);
    int*            flagsB = (int*)(ws + OFF_FLG + 128);
    int*            flagsC = (int*)(ws + OFF_FLG + 256);
    int*            jobs   = (int*)(ws + OFF_JOBS);
    unsigned int*   pool   = (unsigned int*)(ws + OFF_POOL);
    unsigned short* ring0  = (unsigned short*)(ws + OFF_RING0);
    unsigned short* ring1  = (unsigned short*)(ws + OFF_RING1);

    // 1+2. fused gi_c producers + selector recurrence -> selm
    hipMemsetAsync(flagsA, 0, 1024, stream);   // sel flags + jobs counters
    hipMemsetAsync(h0f, 0, (size_t)B_ * H_ * 4, stream);
    sel_fused<<<256, 512, 0, stream>>>(emb, Wih_c, bih_c, giC, Whh_c, bhh_c,
                                       Ws, bs, h0f, h1f, selm, flagsA, jobs);
    // 3. forcing + stable partition
    build_order_k<<<1, 64, 0, stream>>>(mask, selm, order, nsel, maxn);
    // 3b. merged bf16 weight prep (after sel_fused; aliases gi_c tail)
    wprep_all<<<(WP_N6 + 255) / 256, 256, 0, stream>>>(Whh0, Whh1, Wih0, Wih1,
                                                       Wc3, Wc4, Wc5, wpack);
    // 4. gi0 = new_emb @ Wih0^T + bih0 (gathered rows, bf16 MFMA, supertile)
    gemm_mfma<1,0><<<dim3(512 * 24), 256, 0, stream>>>(emb, wih0b, bih0, giB, nullptr,
                                                       G_, E_, E_, T_, 8, 24, order, nsel, 0);
    // 5. FUSED layer0 -> gi1 -> layer1 pipeline (verified r13)
    hipMemsetAsync(flagsA, 0, 512, stream);
    hipMemsetAsync(h0A, 0, 65536, stream);
    hipMemsetAsync(h0C, 0, 65536, stream);
    hipMemsetAsync(outbuf, 0, (size_t)B_ * T_ * H_ * 4, stream);
    rec_fused<<<88, 256, 0, stream>>>(giB, wbf0, wbf1, wih1b, bhh0, bhh1, bih1,
                                      nsel, maxn, h0A, h1A, h0C, h1C,
                                      ring0, ring1, outbuf, flagsA, flagsB, flagsC);
    // 8. convs (bf16 MFMA sliding-window, supertile) + relu + time-max pooling
    hipMemsetAsync(pool, 0, (size_t)B_ * 3 * NF_ * 4, stream);
    gemm_mfma<2,1><<<dim3(512 * 4), 256, 0, stream>>>(outbuf, wc3b, bc3, nullptr, pool,
                                                      NF_, 3*H_, H_, 510, 8, 4, nullptr, nullptr, 0);
    gemm_mfma<2,1><<<dim3(512 * 4), 256, 0, stream>>>(outbuf, wc4b, bc4, nullptr, pool,
                                                      NF_, 4*H_, H_, 509, 8, 4, nullptr, nullptr, 256);
    gemm_mfma<2,1><<<dim3(512 * 4), 256, 0, stream>>>(outbuf, wc5b, bc5, nullptr, pool,
                                                      NF_, 5*H_, H_, 508, 8, 4, nullptr, nullptr, 512);
    // 9. final linear -> d_out (64 f32)
    final_k<<<1, 64, 0, stream>>>(pool, Wo, bo, (float*)d_out);
}